// Round 1
// baseline (4100.164 us; speedup 1.0000x reference)
//
#include <hip/hip_runtime.h>
#include <hip/hip_bf16.h>

#define NPTS 100000
#define KNBR 16
#define CCH  64
#define GRP  8
#define BN_EPS 1e-5f

// ---- workspace layout (float offsets) ----
#define O_QLIN 0
#define O_KLIN (NPTS * CCH)
#define O_VLIN (2 * NPTS * CCH)
#define O_STAT (3 * NPTS * CCH)          // 400 floats of stats
#define O_AFF  (O_STAT + 400)            // 400 floats of affines
// stat layout: qsum[64] qsq[64] ksum[64] ksq[64] psum[64] psq[64] wsum[8] wsq[8]
// aff  layout: qa[64] qb[64] ka[64] kb[64] pa[64] pb[64] wa[8] wb[8]

__device__ __forceinline__ int clip_idx(int r) {
    int i = r < 0 ? 0 : r;
    return i >= NPTS ? NPTS - 1 : i;
}

__global__ __launch_bounds__(512) void k_init(float* __restrict__ stat) {
    int t = threadIdx.x;
    if (t < 400) stat[t] = 0.f;
}

// ---- pass 1: Q/K/V linear + Q/K BN stats ----
__global__ __launch_bounds__(256) void k_qkv(
    const float* __restrict__ feat,
    const float* __restrict__ wq, const float* __restrict__ bq,
    const float* __restrict__ wk, const float* __restrict__ bk,
    const float* __restrict__ wv, const float* __restrict__ bv,
    float* __restrict__ Qlin, float* __restrict__ Klin, float* __restrict__ Vlin,
    float* __restrict__ stat)
{
    const int lane = threadIdx.x & 63;
    const int gw = (blockIdx.x * blockDim.x + threadIdx.x) >> 6;
    const int nw = (gridDim.x * blockDim.x) >> 6;
    const float bql = bq[lane], bkl = bk[lane], bvl = bv[lane];
    float qs = 0.f, qs2 = 0.f, ks = 0.f, ks2 = 0.f;
    for (int n = gw; n < NPTS; n += nw) {
        const float* frow = feat + n * CCH;
        float qa = bql, ka = bkl, va = bvl;
        #pragma unroll 8
        for (int j = 0; j < CCH; ++j) {
            float fj = frow[j];
            qa = fmaf(fj, wq[j * CCH + lane], qa);
            ka = fmaf(fj, wk[j * CCH + lane], ka);
            va = fmaf(fj, wv[j * CCH + lane], va);
        }
        Qlin[n * CCH + lane] = qa;
        Klin[n * CCH + lane] = ka;
        Vlin[n * CCH + lane] = va;
        qs += qa; qs2 += qa * qa; ks += ka; ks2 += ka * ka;
    }
    __shared__ float s_acc[256];
    s_acc[threadIdx.x] = 0.f;
    __syncthreads();
    atomicAdd(&s_acc[lane], qs);
    atomicAdd(&s_acc[64 + lane], qs2);
    atomicAdd(&s_acc[128 + lane], ks);
    atomicAdd(&s_acc[192 + lane], ks2);
    __syncthreads();
    atomicAdd(&stat[threadIdx.x], s_acc[threadIdx.x]);
}

// ---- pass 2: P-branch BN stats (recompute pos@wp1 on the fly) ----
__global__ __launch_bounds__(256) void k_pstats(
    const float* __restrict__ coord, const int* __restrict__ ref,
    const float* __restrict__ wp1, const float* __restrict__ bp1,
    float* __restrict__ stat)
{
    const int lane = threadIdx.x & 63;
    const int gw = (blockIdx.x * blockDim.x + threadIdx.x) >> 6;
    const int nw = (gridDim.x * blockDim.x) >> 6;
    const float w0 = wp1[lane], w1 = wp1[CCH + lane], w2 = wp1[2 * CCH + lane];
    const float b = bp1[lane];
    float ps = 0.f, ps2 = 0.f;
    const int R = NPTS * KNBR;
    for (int row = gw; row < R; row += nw) {
        int n = row >> 4;
        int idx = clip_idx(ref[row]);
        float px = coord[idx * 3 + 0] - coord[n * 3 + 0];
        float py = coord[idx * 3 + 1] - coord[n * 3 + 1];
        float pz = coord[idx * 3 + 2] - coord[n * 3 + 2];
        float p = fmaf(px, w0, fmaf(py, w1, fmaf(pz, w2, b)));
        ps += p; ps2 += p * p;
    }
    __shared__ float s_acc[128];
    if (threadIdx.x < 128) s_acc[threadIdx.x] = 0.f;
    __syncthreads();
    atomicAdd(&s_acc[lane], ps);
    atomicAdd(&s_acc[64 + lane], ps2);
    __syncthreads();
    if (threadIdx.x < 128) atomicAdd(&stat[256 + threadIdx.x], s_acc[threadIdx.x]);
}

// ---- finalize q/k/p BN affines ----
__global__ __launch_bounds__(192) void k_finA(
    const float* __restrict__ gq, const float* __restrict__ betaq,
    const float* __restrict__ gk, const float* __restrict__ betak,
    const float* __restrict__ gp, const float* __restrict__ betap,
    const float* __restrict__ stat, float* __restrict__ aff)
{
    int t = threadIdx.x;
    if (t < 64) {
        float m = stat[t] / (float)NPTS;
        float v = stat[64 + t] / (float)NPTS - m * m;
        float rstd = rsqrtf(v + BN_EPS);
        float a = gq[t] * rstd;
        aff[t] = a;
        aff[64 + t] = betaq[t] - m * a;
    } else if (t < 128) {
        int c = t - 64;
        float m = stat[128 + c] / (float)NPTS;
        float v = stat[192 + c] / (float)NPTS - m * m;
        float rstd = rsqrtf(v + BN_EPS);
        float a = gk[c] * rstd;
        aff[128 + c] = a;
        aff[192 + c] = betak[c] - m * a;
    } else {
        int c = t - 128;
        const float M = (float)(NPTS * KNBR);
        float m = stat[256 + c] / M;
        float v = stat[320 + c] / M - m * m;
        float rstd = rsqrtf(v + BN_EPS);
        float a = gp[c] * rstd;
        aff[256 + c] = a;
        aff[320 + c] = betap[c] - m * a;
    }
}

// ---- pass 3: W-branch BN stats (full recompute of peb + relation) ----
__global__ __launch_bounds__(256) void k_wstats(
    const float* __restrict__ coord, const int* __restrict__ ref,
    const float* __restrict__ wp1, const float* __restrict__ bp1,
    const float* __restrict__ wp2, const float* __restrict__ bp2,
    const float* __restrict__ ww1, const float* __restrict__ bw1,
    const float* __restrict__ Qlin, const float* __restrict__ Klin,
    const float* __restrict__ aff, float* __restrict__ stat)
{
    const int lane = threadIdx.x & 63;
    const int gw = (blockIdx.x * blockDim.x + threadIdx.x) >> 6;
    const int nw = (gridDim.x * blockDim.x) >> 6;
    const float w0 = wp1[lane], w1 = wp1[CCH + lane], w2c = wp1[2 * CCH + lane];
    const float bpl = bp1[lane];
    const float qa = aff[lane], qb = aff[64 + lane];
    const float ka = aff[128 + lane], kb = aff[192 + lane];
    const float pa = aff[256 + lane], pb = aff[320 + lane];
    const float bp2l = bp2[lane];
    float w1r[8], bw1r[8];
    #pragma unroll
    for (int g = 0; g < 8; ++g) { w1r[g] = ww1[lane * 8 + g]; bw1r[g] = bw1[g]; }
    float accs[8], accq[8];
    #pragma unroll
    for (int g = 0; g < 8; ++g) { accs[g] = 0.f; accq[g] = 0.f; }

    const int R = NPTS * KNBR;
    for (int row = gw; row < R; row += nw) {
        int n = row >> 4;
        int idx = clip_idx(ref[row]);
        float px = coord[idx * 3 + 0] - coord[n * 3 + 0];
        float py = coord[idx * 3 + 1] - coord[n * 3 + 1];
        float pz = coord[idx * 3 + 2] - coord[n * 3 + 2];
        float p1 = fmaf(px, w0, fmaf(py, w1, fmaf(pz, w2c, bpl)));
        p1 = fmaxf(fmaf(p1, pa, pb), 0.f);          // bn + relu
        float peb = bp2l;
        #pragma unroll 16
        for (int j = 0; j < CCH; ++j)
            peb = fmaf(__shfl(p1, j, 64), wp2[j * CCH + lane], peb);
        float qv = fmaxf(fmaf(Qlin[n * CCH + lane], qa, qb), 0.f);
        float kv = fmaxf(fmaf(Klin[idx * CCH + lane], ka, kb), 0.f);
        float rel = kv - qv + peb;
        float pg[8];
        #pragma unroll
        for (int g = 0; g < 8; ++g) pg[g] = rel * w1r[g];
        #pragma unroll
        for (int off = 32; off >= 1; off >>= 1) {
            #pragma unroll
            for (int g = 0; g < 8; ++g) pg[g] += __shfl_xor(pg[g], off, 64);
        }
        if (lane == 0) {
            #pragma unroll
            for (int g = 0; g < 8; ++g) {
                float W = pg[g] + bw1r[g];
                accs[g] += W; accq[g] += W * W;
            }
        }
    }
    __shared__ float s_acc[16];
    if (threadIdx.x < 16) s_acc[threadIdx.x] = 0.f;
    __syncthreads();
    if (lane == 0) {
        #pragma unroll
        for (int g = 0; g < 8; ++g) {
            atomicAdd(&s_acc[g], accs[g]);
            atomicAdd(&s_acc[8 + g], accq[g]);
        }
    }
    __syncthreads();
    if (threadIdx.x < 16) atomicAdd(&stat[384 + threadIdx.x], s_acc[threadIdx.x]);
}

__global__ __launch_bounds__(64) void k_finB(
    const float* __restrict__ gw_, const float* __restrict__ betaw,
    const float* __restrict__ stat, float* __restrict__ aff)
{
    int t = threadIdx.x;
    if (t < 8) {
        const float M = (float)(NPTS * KNBR);
        float m = stat[384 + t] / M;
        float v = stat[392 + t] / M - m * m;
        float rstd = rsqrtf(v + BN_EPS);
        float a = gw_[t] * rstd;
        aff[384 + t] = a;
        aff[392 + t] = betaw[t] - m * a;
    }
}

// ---- pass 4: final — w2, masked grouped softmax, einsum ----
__global__ __launch_bounds__(256) void k_final(
    const float* __restrict__ coord, const int* __restrict__ ref,
    const float* __restrict__ wp1, const float* __restrict__ bp1,
    const float* __restrict__ wp2, const float* __restrict__ bp2,
    const float* __restrict__ ww1, const float* __restrict__ bw1,
    const float* __restrict__ ww2, const float* __restrict__ bw2,
    const float* __restrict__ Qlin, const float* __restrict__ Klin,
    const float* __restrict__ Vlin,
    const float* __restrict__ aff, float* __restrict__ out)
{
    const int n = blockIdx.x;
    const int lane = threadIdx.x & 63;
    const int wv = threadIdx.x >> 6;

    __shared__ float s_val[KNBR][CCH];
    __shared__ float s_w[KNBR][GRP];
    __shared__ float s_mask[KNBR];

    const float w0 = wp1[lane], w1 = wp1[CCH + lane], w2c = wp1[2 * CCH + lane];
    const float bpl = bp1[lane];
    const float qa = aff[lane], qb = aff[64 + lane];
    const float ka = aff[128 + lane], kb = aff[192 + lane];
    const float pa = aff[256 + lane], pb = aff[320 + lane];
    const float bp2l = bp2[lane];
    float w1r[8], bw1r[8], wa[8], wb[8];
    #pragma unroll
    for (int g = 0; g < 8; ++g) {
        w1r[g] = ww1[lane * 8 + g];
        bw1r[g] = bw1[g];
        wa[g] = aff[384 + g];
        wb[g] = aff[392 + g];
    }
    const float cx = coord[n * 3 + 0], cy = coord[n * 3 + 1], cz = coord[n * 3 + 2];
    const float qv = fmaxf(fmaf(Qlin[n * CCH + lane], qa, qb), 0.f);

    #pragma unroll
    for (int i = 0; i < 4; ++i) {
        const int kk = wv * 4 + i;
        int r = ref[n * KNBR + kk];
        int idx = clip_idx(r);
        if (lane == 0) s_mask[kk] = (r >= 0) ? 1.f : 0.f;
        float px = coord[idx * 3 + 0] - cx;
        float py = coord[idx * 3 + 1] - cy;
        float pz = coord[idx * 3 + 2] - cz;
        float p1 = fmaf(px, w0, fmaf(py, w1, fmaf(pz, w2c, bpl)));
        p1 = fmaxf(fmaf(p1, pa, pb), 0.f);
        float peb = bp2l;
        #pragma unroll 16
        for (int j = 0; j < CCH; ++j)
            peb = fmaf(__shfl(p1, j, 64), wp2[j * CCH + lane], peb);
        float kv = fmaxf(fmaf(Klin[idx * CCH + lane], ka, kb), 0.f);
        float rel = kv - qv + peb;
        float pg[8];
        #pragma unroll
        for (int g = 0; g < 8; ++g) pg[g] = rel * w1r[g];
        #pragma unroll
        for (int off = 32; off >= 1; off >>= 1) {
            #pragma unroll
            for (int g = 0; g < 8; ++g) pg[g] += __shfl_xor(pg[g], off, 64);
        }
        // bn + relu on W1 (identical in every lane)
        float h[8];
        #pragma unroll
        for (int g = 0; g < 8; ++g)
            h[g] = fmaxf(fmaf(pg[g] + bw1r[g], wa[g], wb[g]), 0.f);
        if (lane < 8) {
            float acc = bw2[lane];
            #pragma unroll
            for (int g = 0; g < 8; ++g)
                acc = fmaf(h[g], ww2[g * 8 + lane], acc);
            s_w[kk][lane] = acc;
        }
        s_val[kk][lane] = Vlin[idx * CCH + lane] + peb;
    }
    __syncthreads();
    if (threadIdx.x < 8) {
        const int g = threadIdx.x;
        float m = -1e30f;
        #pragma unroll
        for (int k = 0; k < KNBR; ++k) m = fmaxf(m, s_w[k][g]);
        float s = 0.f;
        #pragma unroll
        for (int k = 0; k < KNBR; ++k) {
            float e = __expf(s_w[k][g] - m);
            s_w[k][g] = e;
            s += e;
        }
        float inv = 1.f / s;
        #pragma unroll
        for (int k = 0; k < KNBR; ++k) s_w[k][g] *= inv * s_mask[k];
    }
    __syncthreads();
    if (threadIdx.x < 64) {
        const int c = threadIdx.x;
        const int g = c >> 3;
        float acc = 0.f;
        #pragma unroll
        for (int k = 0; k < KNBR; ++k) acc = fmaf(s_val[k][c], s_w[k][g], acc);
        out[n * CCH + c] = acc;
    }
}

extern "C" void kernel_launch(void* const* d_in, const int* in_sizes, int n_in,
                              void* d_out, int out_size, void* d_ws, size_t ws_size,
                              hipStream_t stream)
{
    const float* feat  = (const float*)d_in[0];
    const float* coord = (const float*)d_in[1];
    const int*   ref   = (const int*)d_in[2];
    const float* wq    = (const float*)d_in[3];
    const float* bq    = (const float*)d_in[4];
    const float* gq    = (const float*)d_in[5];
    const float* betaq = (const float*)d_in[6];
    const float* wk    = (const float*)d_in[7];
    const float* bk    = (const float*)d_in[8];
    const float* gk    = (const float*)d_in[9];
    const float* betak = (const float*)d_in[10];
    const float* wv    = (const float*)d_in[11];
    const float* bv    = (const float*)d_in[12];
    const float* wp1   = (const float*)d_in[13];
    const float* bp1   = (const float*)d_in[14];
    const float* gp    = (const float*)d_in[15];
    const float* betap = (const float*)d_in[16];
    const float* wp2   = (const float*)d_in[17];
    const float* bp2   = (const float*)d_in[18];
    const float* ww1   = (const float*)d_in[19];
    const float* bw1   = (const float*)d_in[20];
    const float* gw_   = (const float*)d_in[21];
    const float* betaw = (const float*)d_in[22];
    const float* ww2   = (const float*)d_in[23];
    const float* bw2   = (const float*)d_in[24];

    float* ws   = (float*)d_ws;
    float* Qlin = ws + O_QLIN;
    float* Klin = ws + O_KLIN;
    float* Vlin = ws + O_VLIN;
    float* stat = ws + O_STAT;
    float* aff  = ws + O_AFF;
    float* out  = (float*)d_out;

    hipLaunchKernelGGL(k_init, dim3(1), dim3(512), 0, stream, stat);
    hipLaunchKernelGGL(k_qkv, dim3(2048), dim3(256), 0, stream,
                       feat, wq, bq, wk, bk, wv, bv, Qlin, Klin, Vlin, stat);
    hipLaunchKernelGGL(k_pstats, dim3(2048), dim3(256), 0, stream,
                       coord, ref, wp1, bp1, stat);
    hipLaunchKernelGGL(k_finA, dim3(1), dim3(192), 0, stream,
                       gq, betaq, gk, betak, gp, betap, stat, aff);
    hipLaunchKernelGGL(k_wstats, dim3(4096), dim3(256), 0, stream,
                       coord, ref, wp1, bp1, wp2, bp2, ww1, bw1, Qlin, Klin, aff, stat);
    hipLaunchKernelGGL(k_finB, dim3(1), dim3(64), 0, stream,
                       gw_, betaw, stat, aff);
    hipLaunchKernelGGL(k_final, dim3(NPTS), dim3(256), 0, stream,
                       coord, ref, wp1, bp1, wp2, bp2, ww1, bw1, ww2, bw2,
                       Qlin, Klin, Vlin, aff, out);
}

// Round 2
// 1895.297 us; speedup vs baseline: 2.1633x; 2.1633x over previous
//
#include <hip/hip_runtime.h>
#include <hip/hip_bf16.h>

#define NPTS 100000
#define KNBR 16
#define CCH  64
#define GRP  8
#define BN_EPS 1e-5f
#define NROW (NPTS * KNBR)        // 1,600,000
#define NBATCH (NROW / 64)        // 25,000 batches of 64 rows (4 points)

// ---- workspace layout (float offsets) ----
#define O_QLIN 0
#define O_KLIN (NPTS * CCH)
#define O_VLIN (2 * NPTS * CCH)
#define O_STAT (3 * NPTS * CCH)   // 416 floats of stats
#define O_AFF  (O_STAT + 416)     // 416 floats of affines
// stat: qsum[0..64) qsq[64..128) ksum[128..192) ksq[192..256)
//       pmom[256..265) = {Sx,Sy,Sz,Sxx,Syy,Szz,Sxy,Sxz,Syz}
//       wsum[384..392) wsq[392..400)
// aff:  qa[0..64) qb[64..128) ka[128..192) kb[192..256)
//       pa[256..320) pb[320..384) wa[384..392) wb[392..400)

__device__ __forceinline__ int clip_idx(int r) {
    int i = r < 0 ? 0 : r;
    return i >= NPTS ? NPTS - 1 : i;
}

__global__ __launch_bounds__(512) void k_init(float* __restrict__ stat) {
    int t = threadIdx.x;
    if (t < 416) stat[t] = 0.f;
}

// ---- pass 1: Q/K/V linear + Q/K BN stats (weights staged in LDS) ----
__global__ __launch_bounds__(256) void k_qkv(
    const float* __restrict__ feat,
    const float* __restrict__ wq, const float* __restrict__ bq,
    const float* __restrict__ wk, const float* __restrict__ bk,
    const float* __restrict__ wv, const float* __restrict__ bv,
    float* __restrict__ Qlin, float* __restrict__ Klin, float* __restrict__ Vlin,
    float* __restrict__ stat)
{
    __shared__ float s_w[3 * 4096];
    __shared__ float s_red[256];
    const int tid = threadIdx.x;
    for (int i = tid; i < 4096; i += 256) {
        s_w[i] = wq[i];
        s_w[4096 + i] = wk[i];
        s_w[8192 + i] = wv[i];
    }
    s_red[tid] = 0.f;
    __syncthreads();

    const int lane = tid & 63;
    const int wid = (blockIdx.x * 256 + tid) >> 6;
    const int nw = (gridDim.x * 256) >> 6;
    const float bql = bq[lane], bkl = bk[lane], bvl = bv[lane];
    float qs = 0.f, qs2 = 0.f, ks = 0.f, ks2 = 0.f;
    for (int n = wid; n < NPTS; n += nw) {
        const int nu = __builtin_amdgcn_readfirstlane(n);
        const float* frow = feat + nu * CCH;
        float qa = bql, ka = bkl, va = bvl;
        #pragma unroll 16
        for (int j = 0; j < CCH; ++j) {
            float fj = frow[j];
            qa = fmaf(fj, s_w[j * 64 + lane], qa);
            ka = fmaf(fj, s_w[4096 + j * 64 + lane], ka);
            va = fmaf(fj, s_w[8192 + j * 64 + lane], va);
        }
        Qlin[n * CCH + lane] = qa;
        Klin[n * CCH + lane] = ka;
        Vlin[n * CCH + lane] = va;
        qs += qa; qs2 += qa * qa; ks += ka; ks2 += ka * ka;
    }
    atomicAdd(&s_red[lane], qs);
    atomicAdd(&s_red[64 + lane], qs2);
    atomicAdd(&s_red[128 + lane], ks);
    atomicAdd(&s_red[192 + lane], ks2);
    __syncthreads();
    atomicAdd(&stat[tid], s_red[tid]);
}

// ---- pass 2: pos second moments (9 scalars) -> analytic P-branch BN stats ----
__global__ __launch_bounds__(256) void k_pmom(
    const float* __restrict__ coord, const int* __restrict__ ref,
    float* __restrict__ stat)
{
    float m[9];
    #pragma unroll
    for (int i = 0; i < 9; ++i) m[i] = 0.f;
    const int gid = blockIdx.x * 256 + threadIdx.x;
    const int stride = gridDim.x * 256;
    for (int row = gid; row < NROW; row += stride) {
        int n = row >> 4;
        int idx = clip_idx(ref[row]);
        float px = coord[idx * 3 + 0] - coord[n * 3 + 0];
        float py = coord[idx * 3 + 1] - coord[n * 3 + 1];
        float pz = coord[idx * 3 + 2] - coord[n * 3 + 2];
        m[0] += px; m[1] += py; m[2] += pz;
        m[3] = fmaf(px, px, m[3]); m[4] = fmaf(py, py, m[4]); m[5] = fmaf(pz, pz, m[5]);
        m[6] = fmaf(px, py, m[6]); m[7] = fmaf(px, pz, m[7]); m[8] = fmaf(py, pz, m[8]);
    }
    __shared__ float s9[9];
    if (threadIdx.x < 9) s9[threadIdx.x] = 0.f;
    __syncthreads();
    #pragma unroll
    for (int off = 32; off >= 1; off >>= 1) {
        #pragma unroll
        for (int i = 0; i < 9; ++i) m[i] += __shfl_xor(m[i], off, 64);
    }
    if ((threadIdx.x & 63) == 0) {
        #pragma unroll
        for (int i = 0; i < 9; ++i) atomicAdd(&s9[i], m[i]);
    }
    __syncthreads();
    if (threadIdx.x < 9) atomicAdd(&stat[256 + threadIdx.x], s9[threadIdx.x]);
}

// ---- finalize q/k/p BN affines ----
__global__ __launch_bounds__(192) void k_finA(
    const float* __restrict__ gq, const float* __restrict__ betaq,
    const float* __restrict__ gk, const float* __restrict__ betak,
    const float* __restrict__ gp, const float* __restrict__ betap,
    const float* __restrict__ wp1, const float* __restrict__ bp1,
    const float* __restrict__ stat, float* __restrict__ aff)
{
    int t = threadIdx.x;
    if (t < 64) {
        float m = stat[t] / (float)NPTS;
        float v = stat[64 + t] / (float)NPTS - m * m;
        float a = gq[t] * rsqrtf(v + BN_EPS);
        aff[t] = a;
        aff[64 + t] = betaq[t] - m * a;
    } else if (t < 128) {
        int c = t - 64;
        float m = stat[128 + c] / (float)NPTS;
        float v = stat[192 + c] / (float)NPTS - m * m;
        float a = gk[c] * rsqrtf(v + BN_EPS);
        aff[128 + c] = a;
        aff[192 + c] = betak[c] - m * a;
    } else {
        int c = t - 128;
        const float R = (float)NROW;
        float Ex = stat[256] / R, Ey = stat[257] / R, Ez = stat[258] / R;
        float Exx = stat[259] / R, Eyy = stat[260] / R, Ezz = stat[261] / R;
        float Exy = stat[262] / R, Exz = stat[263] / R, Eyz = stat[264] / R;
        float Cxx = Exx - Ex * Ex, Cyy = Eyy - Ey * Ey, Czz = Ezz - Ez * Ez;
        float Cxy = Exy - Ex * Ey, Cxz = Exz - Ex * Ez, Cyz = Eyz - Ey * Ez;
        float a0 = wp1[c], a1 = wp1[64 + c], a2 = wp1[128 + c];
        float mean = a0 * Ex + a1 * Ey + a2 * Ez + bp1[c];
        float var = a0 * a0 * Cxx + a1 * a1 * Cyy + a2 * a2 * Czz
                  + 2.f * (a0 * a1 * Cxy + a0 * a2 * Cxz + a1 * a2 * Cyz);
        float a = gp[c] * rsqrtf(var + BN_EPS);
        aff[256 + c] = a;
        aff[320 + c] = betap[c] - mean * a;
    }
}

// ---- pass 3: W-branch BN stats (LDS-transpose restructure) ----
__global__ __launch_bounds__(128) void k_wstats(
    const float* __restrict__ coord, const int* __restrict__ ref,
    const float* __restrict__ wp1, const float* __restrict__ bp1,
    const float* __restrict__ wp2, const float* __restrict__ bp2,
    const float* __restrict__ ww1, const float* __restrict__ bw1,
    const float* __restrict__ Qlin, const float* __restrict__ Klin,
    const float* __restrict__ aff, float* __restrict__ stat)
{
    __shared__ float s_wp2T[4096];
    __shared__ float s_rq[2][4096];
    __shared__ float s_red[16];
    const int tid = threadIdx.x, lane = tid & 63, w = tid >> 6;
    for (int i = tid; i < 4096; i += 128)
        s_wp2T[i] = wp2[(i & 63) * 64 + (i >> 6)];   // wp2T[c][j] = wp2[j][c]
    if (tid < 16) s_red[tid] = 0.f;
    __syncthreads();
    float* rq = s_rq[w];

    const float qa = aff[lane], qb = aff[64 + lane];
    const float ka = aff[128 + lane], kb = aff[192 + lane];
    float acc_s[8], acc_q[8];
    #pragma unroll
    for (int g = 0; g < 8; ++g) { acc_s[g] = 0.f; acc_q[g] = 0.f; }

    const int wid = blockIdx.x * 2 + w;
    const int nwv = gridDim.x * 2;
    for (int b = wid; b < NBATCH; b += nwv) {
        const int rbase = b * 64;
        const int p0 = rbase >> 4;
        // ---- phase A: lane = channel, coalesced gather + stage rel_qk ----
        #pragma unroll
        for (int p = 0; p < 4; ++p) {
            float qv = fmaxf(fmaf(Qlin[(p0 + p) * CCH + lane], qa, qb), 0.f);
            #pragma unroll 4
            for (int k = 0; k < 16; ++k) {
                int r = p * 16 + k;
                int idx = clip_idx(ref[rbase + r]);
                float kv = fmaxf(fmaf(Klin[idx * CCH + lane], ka, kb), 0.f);
                rq[r * 64 + (lane ^ (r & 31))] = kv - qv;
            }
        }
        // ---- phase B: lane = row ----
        int rr = ref[rbase + lane];
        int idx = clip_idx(rr);
        int n = (rbase + lane) >> 4;
        float px = coord[idx * 3 + 0] - coord[n * 3 + 0];
        float py = coord[idx * 3 + 1] - coord[n * 3 + 1];
        float pz = coord[idx * 3 + 2] - coord[n * 3 + 2];
        float p1[64];
        #pragma unroll
        for (int j = 0; j < 64; ++j) {
            float v = fmaf(px, wp1[j], fmaf(py, wp1[64 + j], fmaf(pz, wp1[128 + j], bp1[j])));
            p1[j] = fmaxf(fmaf(v, aff[256 + j], aff[320 + j]), 0.f);
        }
        float w1a[8];
        #pragma unroll
        for (int g = 0; g < 8; ++g) w1a[g] = 0.f;
        for (int c = 0; c < 64; ++c) {
            const float4* wrow = (const float4*)&s_wp2T[c * 64];
            float a0 = 0.f, a1 = 0.f, a2 = 0.f, a3 = 0.f;
            #pragma unroll
            for (int j4 = 0; j4 < 16; ++j4) {
                float4 wv4 = wrow[j4];
                a0 = fmaf(p1[4 * j4 + 0], wv4.x, a0);
                a1 = fmaf(p1[4 * j4 + 1], wv4.y, a1);
                a2 = fmaf(p1[4 * j4 + 2], wv4.z, a2);
                a3 = fmaf(p1[4 * j4 + 3], wv4.w, a3);
            }
            float peb = (a0 + a1) + (a2 + a3) + bp2[c];
            float rel = rq[lane * 64 + (c ^ (lane & 31))] + peb;
            #pragma unroll
            for (int g = 0; g < 8; ++g) w1a[g] = fmaf(rel, ww1[c * 8 + g], w1a[g]);
        }
        #pragma unroll
        for (int g = 0; g < 8; ++g) {
            float W = w1a[g] + bw1[g];
            acc_s[g] += W;
            acc_q[g] = fmaf(W, W, acc_q[g]);
        }
    }
    #pragma unroll
    for (int off = 32; off >= 1; off >>= 1) {
        #pragma unroll
        for (int g = 0; g < 8; ++g) {
            acc_s[g] += __shfl_xor(acc_s[g], off, 64);
            acc_q[g] += __shfl_xor(acc_q[g], off, 64);
        }
    }
    if (lane == 0) {
        #pragma unroll
        for (int g = 0; g < 8; ++g) {
            atomicAdd(&s_red[g], acc_s[g]);
            atomicAdd(&s_red[8 + g], acc_q[g]);
        }
    }
    __syncthreads();
    if (tid < 16) atomicAdd(&stat[384 + tid], s_red[tid]);
}

__global__ __launch_bounds__(64) void k_finB(
    const float* __restrict__ gw_, const float* __restrict__ betaw,
    const float* __restrict__ stat, float* __restrict__ aff)
{
    int t = threadIdx.x;
    if (t < 8) {
        const float M = (float)NROW;
        float m = stat[384 + t] / M;
        float v = stat[392 + t] / M - m * m;
        float a = gw_[t] * rsqrtf(v + BN_EPS);
        aff[384 + t] = a;
        aff[392 + t] = betaw[t] - m * a;
    }
}

// ---- pass 4: final — recompute, w2, grouped masked softmax, einsum ----
__global__ __launch_bounds__(128) void k_final(
    const float* __restrict__ coord, const int* __restrict__ ref,
    const float* __restrict__ wp1, const float* __restrict__ bp1,
    const float* __restrict__ wp2, const float* __restrict__ bp2,
    const float* __restrict__ ww1, const float* __restrict__ bw1,
    const float* __restrict__ ww2, const float* __restrict__ bw2,
    const float* __restrict__ Qlin, const float* __restrict__ Klin,
    const float* __restrict__ Vlin,
    const float* __restrict__ aff, float* __restrict__ out)
{
    __shared__ float s_wp2T[4096];
    __shared__ float s_rq[2][4096];
    __shared__ float s_wgt[2][64 * 9];
    const int tid = threadIdx.x, lane = tid & 63, w = tid >> 6;
    for (int i = tid; i < 4096; i += 128)
        s_wp2T[i] = wp2[(i & 63) * 64 + (i >> 6)];
    __syncthreads();
    float* rq = s_rq[w];
    float* swg = s_wgt[w];

    const int b = blockIdx.x * 2 + w;   // exactly 25000 waves
    const int rbase = b * 64;
    const int p0 = rbase >> 4;
    const float qa = aff[lane], qb = aff[64 + lane];
    const float kaf = aff[128 + lane], kbf = aff[192 + lane];

    // ---- phase A ----
    #pragma unroll
    for (int p = 0; p < 4; ++p) {
        float qv = fmaxf(fmaf(Qlin[(p0 + p) * CCH + lane], qa, qb), 0.f);
        #pragma unroll 4
        for (int k = 0; k < 16; ++k) {
            int r = p * 16 + k;
            int idx = clip_idx(ref[rbase + r]);
            float kv = fmaxf(fmaf(Klin[idx * CCH + lane], kaf, kbf), 0.f);
            rq[r * 64 + (lane ^ (r & 31))] = kv - qv;
        }
    }
    // ---- phase B: lane = row ----
    int rr = ref[rbase + lane];
    float mask = (rr >= 0) ? 1.f : 0.f;
    int idx = clip_idx(rr);
    int n = (rbase + lane) >> 4;
    float px = coord[idx * 3 + 0] - coord[n * 3 + 0];
    float py = coord[idx * 3 + 1] - coord[n * 3 + 1];
    float pz = coord[idx * 3 + 2] - coord[n * 3 + 2];
    float p1[64];
    #pragma unroll
    for (int j = 0; j < 64; ++j) {
        float v = fmaf(px, wp1[j], fmaf(py, wp1[64 + j], fmaf(pz, wp1[128 + j], bp1[j])));
        p1[j] = fmaxf(fmaf(v, aff[256 + j], aff[320 + j]), 0.f);
    }
    float w1a[8];
    #pragma unroll
    for (int g = 0; g < 8; ++g) w1a[g] = 0.f;
    for (int c = 0; c < 64; ++c) {
        const float4* wrow = (const float4*)&s_wp2T[c * 64];
        float a0 = 0.f, a1 = 0.f, a2 = 0.f, a3 = 0.f;
        #pragma unroll
        for (int j4 = 0; j4 < 16; ++j4) {
            float4 wv4 = wrow[j4];
            a0 = fmaf(p1[4 * j4 + 0], wv4.x, a0);
            a1 = fmaf(p1[4 * j4 + 1], wv4.y, a1);
            a2 = fmaf(p1[4 * j4 + 2], wv4.z, a2);
            a3 = fmaf(p1[4 * j4 + 3], wv4.w, a3);
        }
        float peb = (a0 + a1) + (a2 + a3) + bp2[c];
        int ra = lane * 64 + (c ^ (lane & 31));
        float rel = rq[ra] + peb;
        rq[ra] = peb;                      // keep peb for phase C
        #pragma unroll
        for (int g = 0; g < 8; ++g) w1a[g] = fmaf(rel, ww1[c * 8 + g], w1a[g]);
    }
    // ---- w2 + grouped masked softmax (within 16-lane point groups) ----
    float h[8];
    #pragma unroll
    for (int g = 0; g < 8; ++g) {
        float W = w1a[g] + bw1[g];
        h[g] = fmaxf(fmaf(W, aff[384 + g], aff[392 + g]), 0.f);
    }
    #pragma unroll
    for (int o = 0; o < 8; ++o) {
        float acc = bw2[o];
        #pragma unroll
        for (int g = 0; g < 8; ++g) acc = fmaf(h[g], ww2[g * 8 + o], acc);
        float m = acc;
        m = fmaxf(m, __shfl_xor(m, 1, 64));
        m = fmaxf(m, __shfl_xor(m, 2, 64));
        m = fmaxf(m, __shfl_xor(m, 4, 64));
        m = fmaxf(m, __shfl_xor(m, 8, 64));
        float e = __expf(acc - m);
        float s = e;
        s += __shfl_xor(s, 1, 64);
        s += __shfl_xor(s, 2, 64);
        s += __shfl_xor(s, 4, 64);
        s += __shfl_xor(s, 8, 64);
        swg[lane * 9 + o] = e / s * mask;
    }
    // ---- phase C: lane = channel, einsum ----
    const int g = lane >> 3;
    #pragma unroll
    for (int p = 0; p < 4; ++p) {
        float acc = 0.f;
        #pragma unroll 4
        for (int k = 0; k < 16; ++k) {
            int r = p * 16 + k;
            int idxr = clip_idx(ref[rbase + r]);
            float val = Vlin[idxr * CCH + lane] + rq[r * 64 + (lane ^ (r & 31))];
            acc = fmaf(val, swg[r * 9 + g], acc);
        }
        out[(p0 + p) * CCH + lane] = acc;
    }
}

extern "C" void kernel_launch(void* const* d_in, const int* in_sizes, int n_in,
                              void* d_out, int out_size, void* d_ws, size_t ws_size,
                              hipStream_t stream)
{
    const float* feat  = (const float*)d_in[0];
    const float* coord = (const float*)d_in[1];
    const int*   ref   = (const int*)d_in[2];
    const float* wq    = (const float*)d_in[3];
    const float* bq    = (const float*)d_in[4];
    const float* gq    = (const float*)d_in[5];
    const float* betaq = (const float*)d_in[6];
    const float* wk    = (const float*)d_in[7];
    const float* bk    = (const float*)d_in[8];
    const float* gk    = (const float*)d_in[9];
    const float* betak = (const float*)d_in[10];
    const float* wv    = (const float*)d_in[11];
    const float* bv    = (const float*)d_in[12];
    const float* wp1   = (const float*)d_in[13];
    const float* bp1   = (const float*)d_in[14];
    const float* gp    = (const float*)d_in[15];
    const float* betap = (const float*)d_in[16];
    const float* wp2   = (const float*)d_in[17];
    const float* bp2   = (const float*)d_in[18];
    const float* ww1   = (const float*)d_in[19];
    const float* bw1   = (const float*)d_in[20];
    const float* gw_   = (const float*)d_in[21];
    const float* betaw = (const float*)d_in[22];
    const float* ww2   = (const float*)d_in[23];
    const float* bw2   = (const float*)d_in[24];

    float* ws   = (float*)d_ws;
    float* Qlin = ws + O_QLIN;
    float* Klin = ws + O_KLIN;
    float* Vlin = ws + O_VLIN;
    float* stat = ws + O_STAT;
    float* aff  = ws + O_AFF;
    float* out  = (float*)d_out;

    hipLaunchKernelGGL(k_init, dim3(1), dim3(512), 0, stream, stat);
    hipLaunchKernelGGL(k_qkv, dim3(512), dim3(256), 0, stream,
                       feat, wq, bq, wk, bk, wv, bv, Qlin, Klin, Vlin, stat);
    hipLaunchKernelGGL(k_pmom, dim3(512), dim3(256), 0, stream, coord, ref, stat);
    hipLaunchKernelGGL(k_finA, dim3(1), dim3(192), 0, stream,
                       gq, betaq, gk, betak, gp, betap, wp1, bp1, stat, aff);
    hipLaunchKernelGGL(k_wstats, dim3(1024), dim3(128), 0, stream,
                       coord, ref, wp1, bp1, wp2, bp2, ww1, bw1, Qlin, Klin, aff, stat);
    hipLaunchKernelGGL(k_finB, dim3(1), dim3(64), 0, stream, gw_, betaw, stat, aff);
    hipLaunchKernelGGL(k_final, dim3(12500), dim3(128), 0, stream,
                       coord, ref, wp1, bp1, wp2, bp2, ww1, bw1, ww2, bw2,
                       Qlin, Klin, Vlin, aff, out);
}

// Round 3
// 587.156 us; speedup vs baseline: 6.9831x; 3.2279x over previous
//
#include <hip/hip_runtime.h>
#include <hip/hip_bf16.h>

#define NPTS 100000
#define KNBR 16
#define CCH  64
#define GRP  8
#define BN_EPS 1e-5f
#define NROW (NPTS * KNBR)        // 1,600,000
#define NBATCH (NROW / 64)        // 25,000 batches of 64 rows (4 points)

// ---- workspace layout (float offsets) ----
#define O_QLIN 0
#define O_KLIN (NPTS * CCH)
#define O_VLIN (2 * NPTS * CCH)
#define O_STAT (3 * NPTS * CCH)   // 416 floats of stats
#define O_AFF  (O_STAT + 416)     // 416 floats of affines
#define O_W2W1 (O_AFF + 416)      // 512 floats: wp2@ww1 [64][8]
// stat: qsum[0..64) qsq[64..128) ksum[128..192) ksq[192..256)
//       pmom[256..265), wsum[384..392) wsq[392..400)
// aff:  qa qb ka kb pa pb (64 each), wa[384..392) wb[392..400)

typedef __attribute__((ext_vector_type(8))) short short8;
typedef __attribute__((ext_vector_type(4))) float f32x4;
#define MFMA16(a, b, c) __builtin_amdgcn_mfma_f32_16x16x32_bf16(a, b, c, 0, 0, 0)

__device__ __forceinline__ int clip_idx(int r) {
    int i = r < 0 ? 0 : r;
    return i >= NPTS ? NPTS - 1 : i;
}
__device__ __forceinline__ unsigned short f2bf(float x) {
    union { float f; unsigned u; } v; v.f = x;
    unsigned r = v.u + 0x7fffu + ((v.u >> 16) & 1u);
    return (unsigned short)(r >> 16);
}
__device__ __forceinline__ float bf2f(unsigned short h) {
    union { unsigned u; float f; } v; v.u = ((unsigned)h) << 16;
    return v.f;
}
// slot s (0..127 along K) -> physical short offset within a row (pre-swizzle).
// Groups the 8 elements one lane-quarter needs per K=32 block contiguously.
__device__ __forceinline__ int physK(int s) {
    return (s >> 5) * 32 + ((s >> 2) & 3) * 8 + ((s >> 4) & 1) * 4 + (s & 3);
}
// short index into a [64][128]-short A-buffer with 16B-chunk XOR swizzle
__device__ __forceinline__ int aOff(int r, int p) {
    return r * 128 + ((((p >> 3)) ^ (r & 7)) << 3) + (p & 7);
}

__global__ __launch_bounds__(512) void k_init(float* __restrict__ stat) {
    int t = threadIdx.x;
    if (t < 416) stat[t] = 0.f;
}

// ---- Q/K/V linear + Q/K BN stats ----
__global__ __launch_bounds__(256) void k_qkv(
    const float* __restrict__ feat,
    const float* __restrict__ wq, const float* __restrict__ bq,
    const float* __restrict__ wk, const float* __restrict__ bk,
    const float* __restrict__ wv, const float* __restrict__ bv,
    float* __restrict__ Qlin, float* __restrict__ Klin, float* __restrict__ Vlin,
    float* __restrict__ stat)
{
    __shared__ float s_w[3 * 4096];
    __shared__ float s_red[256];
    const int tid = threadIdx.x;
    for (int i = tid; i < 4096; i += 256) {
        s_w[i] = wq[i];
        s_w[4096 + i] = wk[i];
        s_w[8192 + i] = wv[i];
    }
    s_red[tid] = 0.f;
    __syncthreads();

    const int lane = tid & 63;
    const int wid = (blockIdx.x * 256 + tid) >> 6;
    const int nw = (gridDim.x * 256) >> 6;
    const float bql = bq[lane], bkl = bk[lane], bvl = bv[lane];
    float qs = 0.f, qs2 = 0.f, ks = 0.f, ks2 = 0.f;
    for (int n = wid; n < NPTS; n += nw) {
        const int nu = __builtin_amdgcn_readfirstlane(n);
        const float* frow = feat + nu * CCH;
        float qa = bql, ka = bkl, va = bvl;
        #pragma unroll 16
        for (int j = 0; j < CCH; ++j) {
            float fj = frow[j];
            qa = fmaf(fj, s_w[j * 64 + lane], qa);
            ka = fmaf(fj, s_w[4096 + j * 64 + lane], ka);
            va = fmaf(fj, s_w[8192 + j * 64 + lane], va);
        }
        Qlin[n * CCH + lane] = qa;
        Klin[n * CCH + lane] = ka;
        Vlin[n * CCH + lane] = va;
        qs += qa; qs2 += qa * qa; ks += ka; ks2 += ka * ka;
    }
    atomicAdd(&s_red[lane], qs);
    atomicAdd(&s_red[64 + lane], qs2);
    atomicAdd(&s_red[128 + lane], ks);
    atomicAdd(&s_red[192 + lane], ks2);
    __syncthreads();
    atomicAdd(&stat[tid], s_red[tid]);
}

// ---- pos second moments (9 scalars) ----
__global__ __launch_bounds__(256) void k_pmom(
    const float* __restrict__ coord, const int* __restrict__ ref,
    float* __restrict__ stat)
{
    float m[9];
    #pragma unroll
    for (int i = 0; i < 9; ++i) m[i] = 0.f;
    const int gid = blockIdx.x * 256 + threadIdx.x;
    const int stride = gridDim.x * 256;
    for (int row = gid; row < NROW; row += stride) {
        int n = row >> 4;
        int idx = clip_idx(ref[row]);
        float px = coord[idx * 3 + 0] - coord[n * 3 + 0];
        float py = coord[idx * 3 + 1] - coord[n * 3 + 1];
        float pz = coord[idx * 3 + 2] - coord[n * 3 + 2];
        m[0] += px; m[1] += py; m[2] += pz;
        m[3] = fmaf(px, px, m[3]); m[4] = fmaf(py, py, m[4]); m[5] = fmaf(pz, pz, m[5]);
        m[6] = fmaf(px, py, m[6]); m[7] = fmaf(px, pz, m[7]); m[8] = fmaf(py, pz, m[8]);
    }
    __shared__ float s9[9];
    if (threadIdx.x < 9) s9[threadIdx.x] = 0.f;
    __syncthreads();
    #pragma unroll
    for (int off = 32; off >= 1; off >>= 1) {
        #pragma unroll
        for (int i = 0; i < 9; ++i) m[i] += __shfl_xor(m[i], off, 64);
    }
    if ((threadIdx.x & 63) == 0) {
        #pragma unroll
        for (int i = 0; i < 9; ++i) atomicAdd(&s9[i], m[i]);
    }
    __syncthreads();
    if (threadIdx.x < 9) atomicAdd(&stat[256 + threadIdx.x], s9[threadIdx.x]);
}

// ---- w2w1 = wp2 @ ww1  [64][8] ----
__global__ __launch_bounds__(512) void k_w2w1(
    const float* __restrict__ wp2, const float* __restrict__ ww1,
    float* __restrict__ w2w1)
{
    int t = threadIdx.x;           // 512 threads: j = t>>3, g = t&7
    int j = t >> 3, g = t & 7;
    float acc = 0.f;
    #pragma unroll 16
    for (int c = 0; c < 64; ++c) acc = fmaf(wp2[j * 64 + c], ww1[c * 8 + g], acc);
    w2w1[t] = acc;
}

// ---- finalize q/k/p BN affines ----
__global__ __launch_bounds__(192) void k_finA(
    const float* __restrict__ gq, const float* __restrict__ betaq,
    const float* __restrict__ gk, const float* __restrict__ betak,
    const float* __restrict__ gp, const float* __restrict__ betap,
    const float* __restrict__ wp1, const float* __restrict__ bp1,
    const float* __restrict__ stat, float* __restrict__ aff)
{
    int t = threadIdx.x;
    if (t < 64) {
        float m = stat[t] / (float)NPTS;
        float v = stat[64 + t] / (float)NPTS - m * m;
        float a = gq[t] * rsqrtf(v + BN_EPS);
        aff[t] = a;
        aff[64 + t] = betaq[t] - m * a;
    } else if (t < 128) {
        int c = t - 64;
        float m = stat[128 + c] / (float)NPTS;
        float v = stat[192 + c] / (float)NPTS - m * m;
        float a = gk[c] * rsqrtf(v + BN_EPS);
        aff[128 + c] = a;
        aff[192 + c] = betak[c] - m * a;
    } else {
        int c = t - 128;
        const float R = (float)NROW;
        float Ex = stat[256] / R, Ey = stat[257] / R, Ez = stat[258] / R;
        float Exx = stat[259] / R, Eyy = stat[260] / R, Ezz = stat[261] / R;
        float Exy = stat[262] / R, Exz = stat[263] / R, Eyz = stat[264] / R;
        float Cxx = Exx - Ex * Ex, Cyy = Eyy - Ey * Ey, Czz = Ezz - Ez * Ez;
        float Cxy = Exy - Ex * Ey, Cxz = Exz - Ex * Ez, Cyz = Eyz - Ey * Ez;
        float a0 = wp1[c], a1 = wp1[64 + c], a2 = wp1[128 + c];
        float mean = a0 * Ex + a1 * Ey + a2 * Ez + bp1[c];
        float var = a0 * a0 * Cxx + a1 * a1 * Cyy + a2 * a2 * Czz
                  + 2.f * (a0 * a1 * Cxy + a0 * a2 * Cxz + a1 * a2 * Cyz);
        float a = gp[c] * rsqrtf(var + BN_EPS);
        aff[256 + c] = a;
        aff[320 + c] = betap[c] - mean * a;
    }
}

// ---- W-branch BN stats: W1 = RQ@ww1 + P1@w2w1 via MFMA ----
__global__ __launch_bounds__(128) void k_wstats(
    const float* __restrict__ coord, const int* __restrict__ ref,
    const float* __restrict__ wp1, const float* __restrict__ bp1,
    const float* __restrict__ ww1, const float* __restrict__ bw1,
    const float* __restrict__ w2w1,
    const float* __restrict__ Qlin, const float* __restrict__ Klin,
    const float* __restrict__ aff, float* __restrict__ stat)
{
    __shared__ short sA[2][64 * 128];
    __shared__ float sPos[2][64 * 4];
    __shared__ int   sIdx[2][64];
    __shared__ short sB2[4 * 64 * 8];
    __shared__ float sRed[16];
    const int tid = threadIdx.x, lane = tid & 63, w = tid >> 6;

    // build B2 image: K=128 concat [ww1 ; w2w1], cols 0..7 valid, frag-linear
    for (int t = tid; t < 2048; t += 128) {
        int i = t & 7, l = (t >> 3) & 63, kt = t >> 9;
        int q = l >> 4;
        int kib = (i < 4) ? (4 * q + i) : (16 + 4 * q + (i - 4));
        int s = kt * 32 + kib;
        int col = l & 15;
        float v = 0.f;
        if (col < 8) v = (s < 64) ? ww1[s * 8 + col] : w2w1[(s - 64) * 8 + col];
        sB2[t] = (short)f2bf(v);
    }
    if (tid < 16) sRed[tid] = 0.f;
    __syncthreads();

    // per-lane constants
    const float qa = aff[lane], qb = aff[64 + lane];
    const float ka = aff[128 + lane], kb = aff[192 + lane];
    const float pa = aff[256 + lane];
    const float A0 = pa * wp1[lane], A1 = pa * wp1[64 + lane], A2 = pa * wp1[128 + lane];
    const float B0 = fmaf(pa, bp1[lane], aff[320 + lane]);
    const float bw1g = ((lane & 15) < 8) ? bw1[lane & 15] : 0.f;
    const int prq = physK(lane), pp1 = physK(64 + lane);

    short8 b2[4];
    #pragma unroll
    for (int kt = 0; kt < 4; ++kt)
        b2[kt] = *(const short8*)(sB2 + (kt * 64 + lane) * 8);

    short* A = sA[w];
    float* pos = sPos[w];
    int* idxs = sIdx[w];
    float accS = 0.f, accQ = 0.f;

    const int wid = blockIdx.x * 2 + w;
    for (int b = wid; b < NBATCH; b += 2500) {
        const int rbase = b * 64;
        const int p0 = rbase >> 4;
        // phase 0: lane = row
        {
            int r = ref[rbase + lane];
            int idx = clip_idx(r);
            idxs[lane] = idx;
            int n = p0 + (lane >> 4);
            pos[lane * 4 + 0] = coord[idx * 3 + 0] - coord[n * 3 + 0];
            pos[lane * 4 + 1] = coord[idx * 3 + 1] - coord[n * 3 + 1];
            pos[lane * 4 + 2] = coord[idx * 3 + 2] - coord[n * 3 + 2];
        }
        // phase A: lane = channel; stage RQ (slots 0..63) and P1 (64..127)
        #pragma unroll
        for (int p = 0; p < 4; ++p) {
            float qv = fmaxf(fmaf(Qlin[(p0 + p) * CCH + lane], qa, qb), 0.f);
            #pragma unroll 8
            for (int k = 0; k < 16; ++k) {
                int r = p * 16 + k;
                int idx = idxs[r];
                float kv = fmaxf(fmaf(Klin[idx * CCH + lane], ka, kb), 0.f);
                float px = pos[r * 4 + 0], py = pos[r * 4 + 1], pz = pos[r * 4 + 2];
                float p1v = fmaxf(fmaf(px, A0, fmaf(py, A1, fmaf(pz, A2, B0))), 0.f);
                A[aOff(r, prq)] = (short)f2bf(kv - qv);
                A[aOff(r, pp1)] = (short)f2bf(p1v);
            }
        }
        // GEMM2: W1 = [RQ|P1] @ B2   (4 M-tiles x K=128)
        f32x4 acc2[4];
        #pragma unroll
        for (int mt = 0; mt < 4; ++mt) acc2[mt] = (f32x4){0.f, 0.f, 0.f, 0.f};
        #pragma unroll
        for (int mt = 0; mt < 4; ++mt) {
            #pragma unroll
            for (int kt = 0; kt < 4; ++kt) {
                int r = mt * 16 + (lane & 15);
                int chunk = kt * 4 + (lane >> 4);
                short8 a = *(const short8*)(A + r * 128 + ((chunk ^ (r & 7)) << 3));
                acc2[mt] = MFMA16(a, b2[kt], acc2[mt]);
            }
        }
        // stats: cols 8..15 are exact zeros (B padded) -> harmless
        #pragma unroll
        for (int mt = 0; mt < 4; ++mt) {
            #pragma unroll
            for (int rg = 0; rg < 4; ++rg) {
                float W = acc2[mt][rg] + bw1g;
                accS += W;
                accQ = fmaf(W, W, accQ);
            }
        }
    }
    // reduce across quarter-lanes sharing the same col
    accS += __shfl_xor(accS, 16, 64); accS += __shfl_xor(accS, 32, 64);
    accQ += __shfl_xor(accQ, 16, 64); accQ += __shfl_xor(accQ, 32, 64);
    if (lane < 8) {
        atomicAdd(&sRed[lane], accS);
        atomicAdd(&sRed[8 + lane], accQ);
    }
    __syncthreads();
    if (tid < 16) atomicAdd(&stat[384 + tid], sRed[tid]);
}

__global__ __launch_bounds__(64) void k_finB(
    const float* __restrict__ gw_, const float* __restrict__ betaw,
    const float* __restrict__ stat, float* __restrict__ aff)
{
    int t = threadIdx.x;
    if (t < 8) {
        const float M = (float)NROW;
        float m = stat[384 + t] / M;
        float v = stat[392 + t] / M - m * m;
        float a = gw_[t] * rsqrtf(v + BN_EPS);
        aff[384 + t] = a;
        aff[392 + t] = betaw[t] - m * a;
    }
}

// ---- final: W1 (MFMA) -> bn/relu -> w2 -> softmax; PEB (MFMA); einsum ----
__global__ __launch_bounds__(128) void k_final(
    const float* __restrict__ coord, const int* __restrict__ ref,
    const float* __restrict__ wp1, const float* __restrict__ bp1,
    const float* __restrict__ wp2, const float* __restrict__ bp2,
    const float* __restrict__ ww1, const float* __restrict__ bw1,
    const float* __restrict__ ww2, const float* __restrict__ bw2,
    const float* __restrict__ w2w1,
    const float* __restrict__ Qlin, const float* __restrict__ Klin,
    const float* __restrict__ Vlin,
    const float* __restrict__ aff, float* __restrict__ out)
{
    __shared__ short sA[2][64 * 128];
    __shared__ float sPos[2][64 * 4];
    __shared__ int   sIdx[2][64];
    __shared__ short sB2[4 * 64 * 8];
    __shared__ short sB1[8 * 64 * 8];
    __shared__ float sWn[2][64 * 9];
    const int tid = threadIdx.x, lane = tid & 63, w = tid >> 6;

    for (int t = tid; t < 2048; t += 128) {
        int i = t & 7, l = (t >> 3) & 63, kt = t >> 9;
        int q = l >> 4;
        int kib = (i < 4) ? (4 * q + i) : (16 + 4 * q + (i - 4));
        int s = kt * 32 + kib;
        int col = l & 15;
        float v = 0.f;
        if (col < 8) v = (s < 64) ? ww1[s * 8 + col] : w2w1[(s - 64) * 8 + col];
        sB2[t] = (short)f2bf(v);
    }
    for (int t = tid; t < 4096; t += 128) {
        int i = t & 7, l = (t >> 3) & 63, kt = (t >> 9) & 1, nt = t >> 10;
        int q = l >> 4;
        int kib = (i < 4) ? (4 * q + i) : (16 + 4 * q + (i - 4));
        int kk = kt * 32 + kib;                 // 0..63 (= j index of wp2)
        int c = nt * 16 + (l & 15);
        sB1[t] = (short)f2bf(wp2[kk * 64 + c]);
    }
    __syncthreads();

    const float qa = aff[lane], qb = aff[64 + lane];
    const float ka = aff[128 + lane], kb = aff[192 + lane];
    const float pa = aff[256 + lane];
    const float A0 = pa * wp1[lane], A1 = pa * wp1[64 + lane], A2 = pa * wp1[128 + lane];
    const float B0 = fmaf(pa, bp1[lane], aff[320 + lane]);
    const float bp2l = bp2[lane];
    const int g15 = lane & 15;
    const float bw1g = (g15 < 8) ? bw1[g15] : 0.f;
    const float wag = aff[384 + (g15 & 7)], wbg = aff[392 + (g15 & 7)];
    const int prq = physK(lane), pp1 = physK(64 + lane);

    short8 b2[4];
    #pragma unroll
    for (int kt = 0; kt < 4; ++kt)
        b2[kt] = *(const short8*)(sB2 + (kt * 64 + lane) * 8);

    short* A = sA[w];
    float* pos = sPos[w];
    int* idxs = sIdx[w];
    float* wn = sWn[w];

    const int wid = blockIdx.x * 2 + w;
    for (int b = wid; b < NBATCH; b += 2500) {
        const int rbase = b * 64;
        const int p0 = rbase >> 4;
        // phase 0
        {
            int r = ref[rbase + lane];
            int idx = clip_idx(r);
            idxs[lane] = idx;
            int n = p0 + (lane >> 4);
            pos[lane * 4 + 0] = coord[idx * 3 + 0] - coord[n * 3 + 0];
            pos[lane * 4 + 1] = coord[idx * 3 + 1] - coord[n * 3 + 1];
            pos[lane * 4 + 2] = coord[idx * 3 + 2] - coord[n * 3 + 2];
            pos[lane * 4 + 3] = (r >= 0) ? 1.f : 0.f;
        }
        // phase A
        #pragma unroll
        for (int p = 0; p < 4; ++p) {
            float qv = fmaxf(fmaf(Qlin[(p0 + p) * CCH + lane], qa, qb), 0.f);
            #pragma unroll 8
            for (int k = 0; k < 16; ++k) {
                int r = p * 16 + k;
                int idx = idxs[r];
                float kv = fmaxf(fmaf(Klin[idx * CCH + lane], ka, kb), 0.f);
                float px = pos[r * 4 + 0], py = pos[r * 4 + 1], pz = pos[r * 4 + 2];
                float p1v = fmaxf(fmaf(px, A0, fmaf(py, A1, fmaf(pz, A2, B0))), 0.f);
                A[aOff(r, prq)] = (short)f2bf(kv - qv);
                A[aOff(r, pp1)] = (short)f2bf(p1v);
            }
        }
        // GEMM2: raw W1
        f32x4 acc2[4];
        #pragma unroll
        for (int mt = 0; mt < 4; ++mt) acc2[mt] = (f32x4){0.f, 0.f, 0.f, 0.f};
        #pragma unroll
        for (int mt = 0; mt < 4; ++mt) {
            #pragma unroll
            for (int kt = 0; kt < 4; ++kt) {
                int r = mt * 16 + (lane & 15);
                int chunk = kt * 4 + (lane >> 4);
                short8 a = *(const short8*)(A + r * 128 + ((chunk ^ (r & 7)) << 3));
                acc2[mt] = MFMA16(a, b2[kt], acc2[mt]);
            }
        }
        // BN + relu -> wn[row][g]
        #pragma unroll
        for (int mt = 0; mt < 4; ++mt) {
            #pragma unroll
            for (int rg = 0; rg < 4; ++rg) {
                if (g15 < 8) {
                    int row = mt * 16 + 4 * (lane >> 4) + rg;
                    wn[row * 9 + g15] = fmaxf(fmaf(wag, acc2[mt][rg] + bw1g, wbg), 0.f);
                }
            }
        }
        // lane = row: w2 + grouped masked softmax (16-lane point groups)
        {
            float h[8];
            #pragma unroll
            for (int g = 0; g < 8; ++g) h[g] = wn[lane * 9 + g];
            float mask = pos[lane * 4 + 3];
            #pragma unroll
            for (int o = 0; o < 8; ++o) {
                float acc = bw2[o];
                #pragma unroll
                for (int g = 0; g < 8; ++g) acc = fmaf(h[g], ww2[g * 8 + o], acc);
                float m = acc;
                m = fmaxf(m, __shfl_xor(m, 1, 64));
                m = fmaxf(m, __shfl_xor(m, 2, 64));
                m = fmaxf(m, __shfl_xor(m, 4, 64));
                m = fmaxf(m, __shfl_xor(m, 8, 64));
                float e = __expf(acc - m);
                float s = e;
                s += __shfl_xor(s, 1, 64);
                s += __shfl_xor(s, 2, 64);
                s += __shfl_xor(s, 4, 64);
                s += __shfl_xor(s, 8, 64);
                wn[lane * 9 + o] = e / s * mask;
            }
        }
        // GEMM1: PEB = P1 @ wp2 (kt 2,3 of A), then bf16 writeback over RQ region
        {
            short8 b1[8];
            #pragma unroll
            for (int t = 0; t < 8; ++t)
                b1[t] = *(const short8*)(sB1 + (t * 64 + lane) * 8);
            #pragma unroll
            for (int mt = 0; mt < 4; ++mt) {
                int r = mt * 16 + (lane & 15);
                int c2 = (2 * 4 + (lane >> 4)) ^ (r & 7);
                int c3 = (3 * 4 + (lane >> 4)) ^ (r & 7);
                short8 a2 = *(const short8*)(A + r * 128 + (c2 << 3));
                short8 a3 = *(const short8*)(A + r * 128 + (c3 << 3));
                #pragma unroll
                for (int nt = 0; nt < 4; ++nt) {
                    f32x4 acc = (f32x4){0.f, 0.f, 0.f, 0.f};
                    acc = MFMA16(a2, b1[nt * 2 + 0], acc);
                    acc = MFMA16(a3, b1[nt * 2 + 1], acc);
                    // writeback: row = mt*16+4q+rg, col = nt*16+(lane&15)
                    int col = nt * 16 + (lane & 15);
                    int pc = physK(col);
                    #pragma unroll
                    for (int rg = 0; rg < 4; ++rg) {
                        int row = mt * 16 + 4 * (lane >> 4) + rg;
                        A[aOff(row, pc)] = (short)f2bf(acc[rg]);
                    }
                }
            }
        }
        // phase C: lane = channel; out = sum_k (V + peb + bp2) * w
        const int pl = physK(lane);
        #pragma unroll
        for (int p = 0; p < 4; ++p) {
            float accO = 0.f;
            #pragma unroll 8
            for (int k = 0; k < 16; ++k) {
                int r = p * 16 + k;
                int idx = idxs[r];
                float val = Vlin[idx * CCH + lane] + bf2f((unsigned short)A[aOff(r, pl)]) + bp2l;
                accO = fmaf(val, wn[r * 9 + (lane >> 3)], accO);
            }
            out[(p0 + p) * CCH + lane] = accO;
        }
    }
}

extern "C" void kernel_launch(void* const* d_in, const int* in_sizes, int n_in,
                              void* d_out, int out_size, void* d_ws, size_t ws_size,
                              hipStream_t stream)
{
    const float* feat  = (const float*)d_in[0];
    const float* coord = (const float*)d_in[1];
    const int*   ref   = (const int*)d_in[2];
    const float* wq    = (const float*)d_in[3];
    const float* bq    = (const float*)d_in[4];
    const float* gq    = (const float*)d_in[5];
    const float* betaq = (const float*)d_in[6];
    const float* wk    = (const float*)d_in[7];
    const float* bk    = (const float*)d_in[8];
    const float* gk    = (const float*)d_in[9];
    const float* betak = (const float*)d_in[10];
    const float* wv    = (const float*)d_in[11];
    const float* bv    = (const float*)d_in[12];
    const float* wp1   = (const float*)d_in[13];
    const float* bp1   = (const float*)d_in[14];
    const float* gp    = (const float*)d_in[15];
    const float* betap = (const float*)d_in[16];
    const float* wp2   = (const float*)d_in[17];
    const float* bp2   = (const float*)d_in[18];
    const float* ww1   = (const float*)d_in[19];
    const float* bw1   = (const float*)d_in[20];
    const float* gw_   = (const float*)d_in[21];
    const float* betaw = (const float*)d_in[22];
    const float* ww2   = (const float*)d_in[23];
    const float* bw2   = (const float*)d_in[24];

    float* ws   = (float*)d_ws;
    float* Qlin = ws + O_QLIN;
    float* Klin = ws + O_KLIN;
    float* Vlin = ws + O_VLIN;
    float* stat = ws + O_STAT;
    float* aff  = ws + O_AFF;
    float* w2w1 = ws + O_W2W1;
    float* out  = (float*)d_out;

    hipLaunchKernelGGL(k_init, dim3(1), dim3(512), 0, stream, stat);
    hipLaunchKernelGGL(k_w2w1, dim3(1), dim3(512), 0, stream, wp2, ww1, w2w1);
    hipLaunchKernelGGL(k_qkv, dim3(512), dim3(256), 0, stream,
                       feat, wq, bq, wk, bk, wv, bv, Qlin, Klin, Vlin, stat);
    hipLaunchKernelGGL(k_pmom, dim3(512), dim3(256), 0, stream, coord, ref, stat);
    hipLaunchKernelGGL(k_finA, dim3(1), dim3(192), 0, stream,
                       gq, betaq, gk, betak, gp, betap, wp1, bp1, stat, aff);
    hipLaunchKernelGGL(k_wstats, dim3(1250), dim3(128), 0, stream,
                       coord, ref, wp1, bp1, ww1, bw1, w2w1, Qlin, Klin, aff, stat);
    hipLaunchKernelGGL(k_finB, dim3(1), dim3(64), 0, stream, gw_, betaw, stat, aff);
    hipLaunchKernelGGL(k_final, dim3(1250), dim3(128), 0, stream,
                       coord, ref, wp1, bp1, wp2, bp2, ww1, bw1, ww2, bw2, w2w1,
                       Qlin, Klin, Vlin, aff, out);
}

// Round 4
// 421.835 us; speedup vs baseline: 9.7198x; 1.3919x over previous
//
#include <hip/hip_runtime.h>
#include <hip/hip_bf16.h>

#define NPTS 100000
#define KNBR 16
#define CCH  64
#define GRP  8
#define BN_EPS 1e-5f
#define NROW (NPTS * KNBR)        // 1,600,000
#define NBATCH (NROW / 64)        // 25,000 batches of 64 rows (4 points)
#define NPB   ((NPTS + 63) / 64)  // 1563 point-batches for k_qkw

// ---- workspace layout (float offsets) ----
#define O_QLIN 0
#define O_KLIN (NPTS * CCH)
#define O_VLIN (2 * NPTS * CCH)
#define O_STAT (3 * NPTS * CCH)   // 416 floats of stats
#define O_AFF  (O_STAT + 416)     // 416 floats of affines
#define O_W2W1 (O_AFF + 416)      // 512 floats: wp2@ww1 [64][8]
#define O_QW1  (O_W2W1 + 512)     // NPTS*8: relu_bn(Q)@ww1
#define O_KW1  (O_QW1 + NPTS * 8) // NPTS*8: relu_bn(K)@ww1
// stat: qsum[0..64) qsq[64..128) ksum[128..192) ksq[192..256)
//       pmom[256..265), wsum[384..392) wsq[392..400)
// aff:  qa qb ka kb pa pb (64 each), wa[384..392) wb[392..400)

typedef __attribute__((ext_vector_type(8))) short short8;
typedef __attribute__((ext_vector_type(4))) float f32x4;
#define MFMA16(a, b, c) __builtin_amdgcn_mfma_f32_16x16x32_bf16(a, b, c, 0, 0, 0)

__device__ __forceinline__ int clip_idx(int r) {
    int i = r < 0 ? 0 : r;
    return i >= NPTS ? NPTS - 1 : i;
}
__device__ __forceinline__ unsigned short f2bf(float x) {
    union { float f; unsigned u; } v; v.f = x;
    unsigned r = v.u + 0x7fffu + ((v.u >> 16) & 1u);
    return (unsigned short)(r >> 16);
}
__device__ __forceinline__ float bf2f(unsigned short h) {
    union { unsigned u; float f; } v; v.u = ((unsigned)h) << 16;
    return v.f;
}
// K-slot s -> physical short offset within a row (A-fragment-linear order)
__device__ __forceinline__ int physK(int s) {
    return (s >> 5) * 32 + ((s >> 2) & 3) * 8 + ((s >> 4) & 1) * 4 + (s & 3);
}
// short index into a [64 rows][64 K-slots] A-buffer with 16B-chunk XOR swizzle
__device__ __forceinline__ int aOff(int r, int p) {
    return r * 64 + (((p >> 3) ^ (r & 7)) << 3) + (p & 7);
}

// ---- prep: zero stats + w2w1 = wp2@ww1 ----
__global__ __launch_bounds__(512) void k_prep(
    const float* __restrict__ wp2, const float* __restrict__ ww1,
    float* __restrict__ stat, float* __restrict__ w2w1)
{
    int t = threadIdx.x;
    if (t < 416) stat[t] = 0.f;
    int j = t >> 3, g = t & 7;
    float acc = 0.f;
    #pragma unroll 16
    for (int c = 0; c < 64; ++c) acc = fmaf(wp2[j * 64 + c], ww1[c * 8 + g], acc);
    w2w1[t] = acc;
}

// ---- Q/K/V linear + Q/K BN stats, fused with pos second moments ----
#define QKV_BLOCKS 512
__global__ __launch_bounds__(256) void k_qkv(
    const float* __restrict__ feat,
    const float* __restrict__ wq, const float* __restrict__ bq,
    const float* __restrict__ wk, const float* __restrict__ bk,
    const float* __restrict__ wv, const float* __restrict__ bv,
    const float* __restrict__ coord, const int* __restrict__ ref,
    float* __restrict__ Qlin, float* __restrict__ Klin, float* __restrict__ Vlin,
    float* __restrict__ stat)
{
    __shared__ float s_w[3 * 4096];
    __shared__ float s_red[256];
    const int tid = threadIdx.x;
    if (blockIdx.x >= QKV_BLOCKS) {
        // ---- pmom body ----
        float m[9];
        #pragma unroll
        for (int i = 0; i < 9; ++i) m[i] = 0.f;
        const int gid = (blockIdx.x - QKV_BLOCKS) * 256 + tid;
        const int stride = 128 * 256;
        for (int row = gid; row < NROW; row += stride) {
            int n = row >> 4;
            int idx = clip_idx(ref[row]);
            float px = coord[idx * 3 + 0] - coord[n * 3 + 0];
            float py = coord[idx * 3 + 1] - coord[n * 3 + 1];
            float pz = coord[idx * 3 + 2] - coord[n * 3 + 2];
            m[0] += px; m[1] += py; m[2] += pz;
            m[3] = fmaf(px, px, m[3]); m[4] = fmaf(py, py, m[4]); m[5] = fmaf(pz, pz, m[5]);
            m[6] = fmaf(px, py, m[6]); m[7] = fmaf(px, pz, m[7]); m[8] = fmaf(py, pz, m[8]);
        }
        if (tid < 9) s_red[tid] = 0.f;
        __syncthreads();
        #pragma unroll
        for (int off = 32; off >= 1; off >>= 1) {
            #pragma unroll
            for (int i = 0; i < 9; ++i) m[i] += __shfl_xor(m[i], off, 64);
        }
        if ((tid & 63) == 0) {
            #pragma unroll
            for (int i = 0; i < 9; ++i) atomicAdd(&s_red[i], m[i]);
        }
        __syncthreads();
        if (tid < 9) atomicAdd(&stat[256 + tid], s_red[tid]);
        return;
    }
    // ---- qkv body ----
    for (int i = tid; i < 4096; i += 256) {
        s_w[i] = wq[i];
        s_w[4096 + i] = wk[i];
        s_w[8192 + i] = wv[i];
    }
    s_red[tid] = 0.f;
    __syncthreads();

    const int lane = tid & 63;
    const int wid = (blockIdx.x * 256 + tid) >> 6;
    const int nw = (QKV_BLOCKS * 256) >> 6;
    const float bql = bq[lane], bkl = bk[lane], bvl = bv[lane];
    float qs = 0.f, qs2 = 0.f, ks = 0.f, ks2 = 0.f;
    for (int n = wid; n < NPTS; n += nw) {
        const int nu = __builtin_amdgcn_readfirstlane(n);
        const float* frow = feat + nu * CCH;
        float qa = bql, ka = bkl, va = bvl;
        #pragma unroll 16
        for (int j = 0; j < CCH; ++j) {
            float fj = frow[j];
            qa = fmaf(fj, s_w[j * 64 + lane], qa);
            ka = fmaf(fj, s_w[4096 + j * 64 + lane], ka);
            va = fmaf(fj, s_w[8192 + j * 64 + lane], va);
        }
        Qlin[n * CCH + lane] = qa;
        Klin[n * CCH + lane] = ka;
        Vlin[n * CCH + lane] = va;
        qs += qa; qs2 += qa * qa; ks += ka; ks2 += ka * ka;
    }
    atomicAdd(&s_red[lane], qs);
    atomicAdd(&s_red[64 + lane], qs2);
    atomicAdd(&s_red[128 + lane], ks);
    atomicAdd(&s_red[192 + lane], ks2);
    __syncthreads();
    atomicAdd(&stat[tid], s_red[tid]);
}

// ---- finalize q/k/p BN affines ----
__global__ __launch_bounds__(192) void k_finA(
    const float* __restrict__ gq, const float* __restrict__ betaq,
    const float* __restrict__ gk, const float* __restrict__ betak,
    const float* __restrict__ gp, const float* __restrict__ betap,
    const float* __restrict__ wp1, const float* __restrict__ bp1,
    const float* __restrict__ stat, float* __restrict__ aff)
{
    int t = threadIdx.x;
    if (t < 64) {
        float m = stat[t] / (float)NPTS;
        float v = stat[64 + t] / (float)NPTS - m * m;
        float a = gq[t] * rsqrtf(v + BN_EPS);
        aff[t] = a;
        aff[64 + t] = betaq[t] - m * a;
    } else if (t < 128) {
        int c = t - 64;
        float m = stat[128 + c] / (float)NPTS;
        float v = stat[192 + c] / (float)NPTS - m * m;
        float a = gk[c] * rsqrtf(v + BN_EPS);
        aff[128 + c] = a;
        aff[192 + c] = betak[c] - m * a;
    } else {
        int c = t - 128;
        const float R = (float)NROW;
        float Ex = stat[256] / R, Ey = stat[257] / R, Ez = stat[258] / R;
        float Exx = stat[259] / R, Eyy = stat[260] / R, Ezz = stat[261] / R;
        float Exy = stat[262] / R, Exz = stat[263] / R, Eyz = stat[264] / R;
        float Cxx = Exx - Ex * Ex, Cyy = Eyy - Ey * Ey, Czz = Ezz - Ez * Ez;
        float Cxy = Exy - Ex * Ey, Cxz = Exz - Ex * Ez, Cyz = Eyz - Ey * Ez;
        float a0 = wp1[c], a1 = wp1[64 + c], a2 = wp1[128 + c];
        float mean = a0 * Ex + a1 * Ey + a2 * Ez + bp1[c];
        float var = a0 * a0 * Cxx + a1 * a1 * Cyy + a2 * a2 * Czz
                  + 2.f * (a0 * a1 * Cxy + a0 * a2 * Cxz + a1 * a2 * Cyz);
        float a = gp[c] * rsqrtf(var + BN_EPS);
        aff[256 + c] = a;
        aff[320 + c] = betap[c] - mean * a;
    }
}

// ---- per-point QW1/KW1 = relu_bn(Q/K) @ ww1 via MFMA ----
__global__ __launch_bounds__(128) void k_qkw(
    const float* __restrict__ Qlin, const float* __restrict__ Klin,
    const float* __restrict__ ww1, const float* __restrict__ aff,
    float* __restrict__ QW1, float* __restrict__ KW1)
{
    __shared__ short sA[2][8192];   // per wave: AQ[64*64] + AK[64*64]
    __shared__ short sB[1024];      // ww1 image, K=64, N=16 (cols 0..7 valid)
    const int tid = threadIdx.x, lane = tid & 63, w = tid >> 6;
    for (int t = tid; t < 1024; t += 128) {
        int i = t & 7, l = (t >> 3) & 63, kt = t >> 9;
        int q = l >> 4;
        int kib = (i < 4) ? (4 * q + i) : (16 + 4 * q + (i - 4));
        int s = kt * 32 + kib;
        int col = l & 15;
        sB[t] = (short)f2bf(col < 8 ? ww1[s * 8 + col] : 0.f);
    }
    __syncthreads();
    short8 bimg[2];
    #pragma unroll
    for (int kt = 0; kt < 2; ++kt)
        bimg[kt] = *(const short8*)(sB + (kt * 64 + lane) * 8);

    const float qa = aff[lane], qb = aff[64 + lane];
    const float ka = aff[128 + lane], kb = aff[192 + lane];
    short* AQ = sA[w];
    short* AK = sA[w] + 4096;
    const int pk = physK(lane);
    const int g = lane & 15;

    for (int b = blockIdx.x * 2 + w; b < NPB; b += gridDim.x * 2) {
        const int pbase = b * 64;
        #pragma unroll 8
        for (int p = 0; p < 64; ++p) {
            int n = pbase + p;
            float qv = 0.f, kv = 0.f;
            if (n < NPTS) {
                qv = fmaxf(fmaf(Qlin[n * CCH + lane], qa, qb), 0.f);
                kv = fmaxf(fmaf(Klin[n * CCH + lane], ka, kb), 0.f);
            }
            AQ[aOff(p, pk)] = (short)f2bf(qv);
            AK[aOff(p, pk)] = (short)f2bf(kv);
        }
        #pragma unroll
        for (int mt = 0; mt < 4; ++mt) {
            f32x4 aq = (f32x4){0.f, 0.f, 0.f, 0.f};
            f32x4 ak = (f32x4){0.f, 0.f, 0.f, 0.f};
            int r = mt * 16 + (lane & 15);
            #pragma unroll
            for (int kt = 0; kt < 2; ++kt) {
                int chunk = (kt * 4 + (lane >> 4)) ^ (r & 7);
                aq = MFMA16(*(const short8*)(AQ + r * 64 + (chunk << 3)), bimg[kt], aq);
                ak = MFMA16(*(const short8*)(AK + r * 64 + (chunk << 3)), bimg[kt], ak);
            }
            if (g < 8) {
                #pragma unroll
                for (int rg = 0; rg < 4; ++rg) {
                    int p = mt * 16 + 4 * (lane >> 4) + rg;
                    int n = pbase + p;
                    if (n < NPTS) {
                        QW1[n * 8 + g] = aq[rg];
                        KW1[n * 8 + g] = ak[rg];
                    }
                }
            }
        }
    }
}

// ---- W-branch BN stats: W1 = P1@w2w1 (MFMA) + KW1[idx] - QW1[n] + bw1 ----
__global__ __launch_bounds__(128) void k_wstats(
    const float* __restrict__ coord, const int* __restrict__ ref,
    const float* __restrict__ wp1, const float* __restrict__ bp1,
    const float* __restrict__ bw1, const float* __restrict__ w2w1,
    const float* __restrict__ QW1, const float* __restrict__ KW1,
    const float* __restrict__ aff, float* __restrict__ stat)
{
    __shared__ short sP[2][4096];
    __shared__ float sPos[2][256];
    __shared__ int   sIdx[2][64];
    __shared__ short sBw[1024];
    __shared__ float sRed[16];
    const int tid = threadIdx.x, lane = tid & 63, w = tid >> 6;
    for (int t = tid; t < 1024; t += 128) {
        int i = t & 7, l = (t >> 3) & 63, kt = t >> 9;
        int q = l >> 4;
        int kib = (i < 4) ? (4 * q + i) : (16 + 4 * q + (i - 4));
        int s = kt * 32 + kib;
        int col = l & 15;
        sBw[t] = (short)f2bf(col < 8 ? w2w1[s * 8 + col] : 0.f);
    }
    if (tid < 16) sRed[tid] = 0.f;
    __syncthreads();
    short8 bimg[2];
    #pragma unroll
    for (int kt = 0; kt < 2; ++kt)
        bimg[kt] = *(const short8*)(sBw + (kt * 64 + lane) * 8);

    const float pa = aff[256 + lane];
    const float A0 = pa * wp1[lane], A1 = pa * wp1[64 + lane], A2 = pa * wp1[128 + lane];
    const float B0 = fmaf(pa, bp1[lane], aff[320 + lane]);
    const int g = lane & 15;
    const float bwg = (g < 8) ? bw1[g] : 0.f;
    const int pk = physK(lane);

    short* P = sP[w];
    float* pos = sPos[w];
    int* idxs = sIdx[w];
    float accS = 0.f, accQ = 0.f;

    for (int b = blockIdx.x * 2 + w; b < NBATCH; b += gridDim.x * 2) {
        const int rbase = b * 64;
        const int p0 = b * 4;
        {
            int r = ref[rbase + lane];
            int idx = clip_idx(r);
            idxs[lane] = idx;
            int n = p0 + (lane >> 4);
            pos[lane * 4 + 0] = coord[idx * 3 + 0] - coord[n * 3 + 0];
            pos[lane * 4 + 1] = coord[idx * 3 + 1] - coord[n * 3 + 1];
            pos[lane * 4 + 2] = coord[idx * 3 + 2] - coord[n * 3 + 2];
        }
        #pragma unroll 8
        for (int rr = 0; rr < 64; ++rr) {
            f32x4 pp = *(const f32x4*)(pos + rr * 4);
            float p1v = fmaxf(fmaf(pp.x, A0, fmaf(pp.y, A1, fmaf(pp.z, A2, B0))), 0.f);
            P[aOff(rr, pk)] = (short)f2bf(p1v);
        }
        #pragma unroll
        for (int mt = 0; mt < 4; ++mt) {
            f32x4 acc = (f32x4){0.f, 0.f, 0.f, 0.f};
            int r = mt * 16 + (lane & 15);
            #pragma unroll
            for (int kt = 0; kt < 2; ++kt) {
                int chunk = (kt * 4 + (lane >> 4)) ^ (r & 7);
                acc = MFMA16(*(const short8*)(P + r * 64 + (chunk << 3)), bimg[kt], acc);
            }
            if (g < 8) {
                #pragma unroll
                for (int rg = 0; rg < 4; ++rg) {
                    int row = mt * 16 + 4 * (lane >> 4) + rg;
                    float W = acc[rg] + KW1[idxs[row] * 8 + g]
                            - QW1[(p0 + (row >> 4)) * 8 + g] + bwg;
                    accS += W;
                    accQ = fmaf(W, W, accQ);
                }
            }
        }
    }
    accS += __shfl_xor(accS, 16, 64); accS += __shfl_xor(accS, 32, 64);
    accQ += __shfl_xor(accQ, 16, 64); accQ += __shfl_xor(accQ, 32, 64);
    if (lane < 8) {
        atomicAdd(&sRed[lane], accS);
        atomicAdd(&sRed[8 + lane], accQ);
    }
    __syncthreads();
    if (tid < 16) atomicAdd(&stat[384 + tid], sRed[tid]);
}

__global__ __launch_bounds__(64) void k_finB(
    const float* __restrict__ gw_, const float* __restrict__ betaw,
    const float* __restrict__ stat, float* __restrict__ aff)
{
    int t = threadIdx.x;
    if (t < 8) {
        const float M = (float)NROW;
        float m = stat[384 + t] / M;
        float v = stat[392 + t] / M - m * m;
        float a = gw_[t] * rsqrtf(v + BN_EPS);
        aff[384 + t] = a;
        aff[392 + t] = betaw[t] - m * a;
    }
}

// ---- final: W1 -> bn/relu -> w2 -> softmax; PEB (MFMA); einsum ----
__global__ __launch_bounds__(128) void k_final(
    const float* __restrict__ coord, const int* __restrict__ ref,
    const float* __restrict__ wp1, const float* __restrict__ bp1,
    const float* __restrict__ wp2, const float* __restrict__ bp2,
    const float* __restrict__ bw1, const float* __restrict__ w2w1,
    const float* __restrict__ ww2, const float* __restrict__ bw2,
    const float* __restrict__ QW1, const float* __restrict__ KW1,
    const float* __restrict__ Vlin,
    const float* __restrict__ aff, float* __restrict__ out)
{
    __shared__ short sP[2][4096];      // P1, overwritten by PEB per mt-tile
    __shared__ float sPos[2][256];
    __shared__ int   sIdx[2][64];
    __shared__ short sB1[4096];        // wp2 image: K=64, N=64
    __shared__ short sBw[1024];        // w2w1 image: K=64, N=16
    __shared__ float sWn[2][576];
    const int tid = threadIdx.x, lane = tid & 63, w = tid >> 6;
    for (int t = tid; t < 1024; t += 128) {
        int i = t & 7, l = (t >> 3) & 63, kt = t >> 9;
        int q = l >> 4;
        int kib = (i < 4) ? (4 * q + i) : (16 + 4 * q + (i - 4));
        int s = kt * 32 + kib;
        int col = l & 15;
        sBw[t] = (short)f2bf(col < 8 ? w2w1[s * 8 + col] : 0.f);
    }
    for (int t = tid; t < 4096; t += 128) {
        int i = t & 7, l = (t >> 3) & 63, kt = (t >> 9) & 1, nt = t >> 10;
        int q = l >> 4;
        int kib = (i < 4) ? (4 * q + i) : (16 + 4 * q + (i - 4));
        int kk = kt * 32 + kib;
        int c = nt * 16 + (l & 15);
        sB1[t] = (short)f2bf(wp2[kk * 64 + c]);
    }
    __syncthreads();
    short8 bw_img[2];
    #pragma unroll
    for (int kt = 0; kt < 2; ++kt)
        bw_img[kt] = *(const short8*)(sBw + (kt * 64 + lane) * 8);
    short8 b1[8];
    #pragma unroll
    for (int t = 0; t < 8; ++t)
        b1[t] = *(const short8*)(sB1 + (t * 64 + lane) * 8);

    const float pa = aff[256 + lane];
    const float A0 = pa * wp1[lane], A1 = pa * wp1[64 + lane], A2 = pa * wp1[128 + lane];
    const float B0 = fmaf(pa, bp1[lane], aff[320 + lane]);
    const float bp2l = bp2[lane];
    const int g15 = lane & 15;
    const float bwg = (g15 < 8) ? bw1[g15] : 0.f;
    const float wag = aff[384 + (g15 & 7)], wbg = aff[392 + (g15 & 7)];
    const int pk = physK(lane);

    short* P = sP[w];
    float* pos = sPos[w];
    int* idxs = sIdx[w];
    float* wn = sWn[w];

    for (int b = blockIdx.x * 2 + w; b < NBATCH; b += gridDim.x * 2) {
        const int rbase = b * 64;
        const int p0 = b * 4;
        {
            int r = ref[rbase + lane];
            int idx = clip_idx(r);
            idxs[lane] = idx;
            int n = p0 + (lane >> 4);
            pos[lane * 4 + 0] = coord[idx * 3 + 0] - coord[n * 3 + 0];
            pos[lane * 4 + 1] = coord[idx * 3 + 1] - coord[n * 3 + 1];
            pos[lane * 4 + 2] = coord[idx * 3 + 2] - coord[n * 3 + 2];
            pos[lane * 4 + 3] = (r >= 0) ? 1.f : 0.f;
        }
        // stage P1
        #pragma unroll 8
        for (int rr = 0; rr < 64; ++rr) {
            f32x4 pp = *(const f32x4*)(pos + rr * 4);
            float p1v = fmaxf(fmaf(pp.x, A0, fmaf(pp.y, A1, fmaf(pp.z, A2, B0))), 0.f);
            P[aOff(rr, pk)] = (short)f2bf(p1v);
        }
        // GEMM2: P1@w2w1, + per-point terms -> bn/relu -> wn
        #pragma unroll
        for (int mt = 0; mt < 4; ++mt) {
            f32x4 acc = (f32x4){0.f, 0.f, 0.f, 0.f};
            int r = mt * 16 + (lane & 15);
            #pragma unroll
            for (int kt = 0; kt < 2; ++kt) {
                int chunk = (kt * 4 + (lane >> 4)) ^ (r & 7);
                acc = MFMA16(*(const short8*)(P + r * 64 + (chunk << 3)), bw_img[kt], acc);
            }
            if (g15 < 8) {
                #pragma unroll
                for (int rg = 0; rg < 4; ++rg) {
                    int row = mt * 16 + 4 * (lane >> 4) + rg;
                    float W = acc[rg] + KW1[idxs[row] * 8 + g15]
                            - QW1[(p0 + (row >> 4)) * 8 + g15] + bwg;
                    wn[row * 9 + g15] = fmaxf(fmaf(wag, W, wbg), 0.f);
                }
            }
        }
        // lane = row: w2 + grouped masked softmax (16-lane point groups)
        {
            float h[8];
            #pragma unroll
            for (int g = 0; g < 8; ++g) h[g] = wn[lane * 9 + g];
            float mask = pos[lane * 4 + 3];
            #pragma unroll
            for (int o = 0; o < 8; ++o) {
                float acc = bw2[o];
                #pragma unroll
                for (int g = 0; g < 8; ++g) acc = fmaf(h[g], ww2[g * 8 + o], acc);
                float m = acc;
                m = fmaxf(m, __shfl_xor(m, 1, 64));
                m = fmaxf(m, __shfl_xor(m, 2, 64));
                m = fmaxf(m, __shfl_xor(m, 4, 64));
                m = fmaxf(m, __shfl_xor(m, 8, 64));
                float e = __expf(acc - m);
                float s = e;
                s += __shfl_xor(s, 1, 64);
                s += __shfl_xor(s, 2, 64);
                s += __shfl_xor(s, 4, 64);
                s += __shfl_xor(s, 8, 64);
                wn[lane * 9 + o] = e / s * mask;
            }
        }
        // GEMM1: PEB = P1@wp2, in-place writeback per mt-tile
        #pragma unroll
        for (int mt = 0; mt < 4; ++mt) {
            int r = mt * 16 + (lane & 15);
            int c0 = (0 * 4 + (lane >> 4)) ^ (r & 7);
            int c1 = (1 * 4 + (lane >> 4)) ^ (r & 7);
            short8 a0 = *(const short8*)(P + r * 64 + (c0 << 3));
            short8 a1 = *(const short8*)(P + r * 64 + (c1 << 3));
            #pragma unroll
            for (int nt = 0; nt < 4; ++nt) {
                f32x4 acc = (f32x4){0.f, 0.f, 0.f, 0.f};
                acc = MFMA16(a0, b1[nt * 2 + 0], acc);
                acc = MFMA16(a1, b1[nt * 2 + 1], acc);
                int col = nt * 16 + (lane & 15);
                int pc = physK(col);
                #pragma unroll
                for (int rg = 0; rg < 4; ++rg) {
                    int row = mt * 16 + 4 * (lane >> 4) + rg;
                    P[aOff(row, pc)] = (short)f2bf(acc[rg]);
                }
            }
        }
        // phase C: lane = channel; out = sum_k (V + peb + bp2) * w
        #pragma unroll
        for (int p = 0; p < 4; ++p) {
            float accO = 0.f;
            #pragma unroll 8
            for (int k = 0; k < 16; ++k) {
                int r = p * 16 + k;
                int idx = idxs[r];
                float val = Vlin[idx * CCH + lane] + bf2f((unsigned short)P[aOff(r, pk)]) + bp2l;
                accO = fmaf(val, wn[r * 9 + (lane >> 3)], accO);
            }
            out[(p0 + p) * CCH + lane] = accO;
        }
    }
}

extern "C" void kernel_launch(void* const* d_in, const int* in_sizes, int n_in,
                              void* d_out, int out_size, void* d_ws, size_t ws_size,
                              hipStream_t stream)
{
    const float* feat  = (const float*)d_in[0];
    const float* coord = (const float*)d_in[1];
    const int*   ref   = (const int*)d_in[2];
    const float* wq    = (const float*)d_in[3];
    const float* bq    = (const float*)d_in[4];
    const float* gq    = (const float*)d_in[5];
    const float* betaq = (const float*)d_in[6];
    const float* wk    = (const float*)d_in[7];
    const float* bk    = (const float*)d_in[8];
    const float* gk    = (const float*)d_in[9];
    const float* betak = (const float*)d_in[10];
    const float* wv    = (const float*)d_in[11];
    const float* bv    = (const float*)d_in[12];
    const float* wp1   = (const float*)d_in[13];
    const float* bp1   = (const float*)d_in[14];
    const float* gp    = (const float*)d_in[15];
    const float* betap = (const float*)d_in[16];
    const float* wp2   = (const float*)d_in[17];
    const float* bp2   = (const float*)d_in[18];
    const float* ww1   = (const float*)d_in[19];
    const float* bw1   = (const float*)d_in[20];
    const float* gw_   = (const float*)d_in[21];
    const float* betaw = (const float*)d_in[22];
    const float* ww2   = (const float*)d_in[23];
    const float* bw2   = (const float*)d_in[24];

    float* ws   = (float*)d_ws;
    float* Qlin = ws + O_QLIN;
    float* Klin = ws + O_KLIN;
    float* Vlin = ws + O_VLIN;
    float* stat = ws + O_STAT;
    float* aff  = ws + O_AFF;
    float* w2w1 = ws + O_W2W1;
    float* QW1  = ws + O_QW1;
    float* KW1  = ws + O_KW1;
    float* out  = (float*)d_out;

    hipLaunchKernelGGL(k_prep, dim3(1), dim3(512), 0, stream, wp2, ww1, stat, w2w1);
    hipLaunchKernelGGL(k_qkv, dim3(QKV_BLOCKS + 128), dim3(256), 0, stream,
                       feat, wq, bq, wk, bk, wv, bv, coord, ref,
                       Qlin, Klin, Vlin, stat);
    hipLaunchKernelGGL(k_finA, dim3(1), dim3(192), 0, stream,
                       gq, betaq, gk, betak, gp, betap, wp1, bp1, stat, aff);
    hipLaunchKernelGGL(k_qkw, dim3(782), dim3(128), 0, stream,
                       Qlin, Klin, ww1, aff, QW1, KW1);
    hipLaunchKernelGGL(k_wstats, dim3(2500), dim3(128), 0, stream,
                       coord, ref, wp1, bp1, bw1, w2w1, QW1, KW1, aff, stat);
    hipLaunchKernelGGL(k_finB, dim3(1), dim3(64), 0, stream, gw_, betaw, stat, aff);
    hipLaunchKernelGGL(k_final, dim3(2500), dim3(128), 0, stream,
                       coord, ref, wp1, bp1, wp2, bp2, bw1, w2w1, ww2, bw2,
                       QW1, KW1, Vlin, aff, out);
}

// Round 5
// 344.688 us; speedup vs baseline: 11.8953x; 1.2238x over previous
//
#include <hip/hip_runtime.h>
#include <hip/hip_bf16.h>

#define NPTS 100000
#define KNBR 16
#define CCH  64
#define GRP  8
#define BN_EPS 1e-5f
#define NROW (NPTS * KNBR)        // 1,600,000
#define NBATCH (NROW / 64)        // 25,000 batches of 64 rows (4 points)
#define NPB   ((NPTS + 63) / 64)  // 1563 point-batches

// ---- workspace layout (float offsets) ----
#define O_QLINH 0                  // NPTS*64 bf16 = NPTS*32 floats
#define O_KLINH (NPTS * 32)
#define O_VLINH (NPTS * 64)
#define O_STAT  (NPTS * 96)        // 416 floats of stats
#define O_AFF   (O_STAT + 416)     // 416 floats of affines
#define O_W2W1  (O_AFF + 416)      // 512 floats: wp2@ww1 [64][8]
#define O_QW1   (O_W2W1 + 512)     // NPTS*8 fp32
#define O_KW1   (O_QW1 + NPTS * 8) // NPTS*8 fp32
// stat: qsum[0..64) qsq[64..128) ksum[128..192) ksq[192..256)
//       pmom[256..265), wsum[384..392) wsq[392..400)
// aff:  qa qb ka kb pa pb (64 each), wa[384..392) wb[392..400)

typedef __attribute__((ext_vector_type(8))) short short8;
typedef __attribute__((ext_vector_type(4))) float f32x4;
#define MFMA16(a, b, c) __builtin_amdgcn_mfma_f32_16x16x32_bf16(a, b, c, 0, 0, 0)

__device__ __forceinline__ int clip_idx(int r) {
    int i = r < 0 ? 0 : r;
    return i >= NPTS ? NPTS - 1 : i;
}
__device__ __forceinline__ unsigned short f2bf(float x) {
    union { float f; unsigned u; } v; v.f = x;
    unsigned r = v.u + 0x7fffu + ((v.u >> 16) & 1u);
    return (unsigned short)(r >> 16);
}
__device__ __forceinline__ float bf2f(unsigned short h) {
    union { unsigned u; float f; } v; v.u = ((unsigned)h) << 16;
    return v.f;
}
// K-slot s -> physical short offset within a row (A-fragment-linear order)
__device__ __forceinline__ int physK(int s) {
    return (s >> 5) * 32 + ((s >> 2) & 3) * 8 + ((s >> 4) & 1) * 4 + (s & 3);
}
// short index into a [64 rows][64 K-slots] A-buffer with 16B-chunk XOR swizzle
__device__ __forceinline__ int aOff(int r, int p) {
    return r * 64 + (((p >> 3) ^ (r & 7)) << 3) + (p & 7);
}
// element i of a B fragment for quarter q: K-in-block index
__device__ __forceinline__ int kib_of(int i, int q) {
    return (i < 4) ? (4 * q + i) : (16 + 4 * q + (i - 4));
}

// ---- prep: zero stats + w2w1 = wp2@ww1 ----
__global__ __launch_bounds__(512) void k_prep(
    const float* __restrict__ wp2, const float* __restrict__ ww1,
    float* __restrict__ stat, float* __restrict__ w2w1)
{
    int t = threadIdx.x;
    if (t < 416) stat[t] = 0.f;
    int j = t >> 3, g = t & 7;
    float acc = 0.f;
    #pragma unroll 16
    for (int c = 0; c < 64; ++c) acc = fmaf(wp2[j * 64 + c], ww1[c * 8 + g], acc);
    w2w1[t] = acc;
}

// ---- Q/K/V projection via MFMA + Q/K BN stats; pmom fused as extra blocks ----
#define QKV_BLOCKS 512
__global__ __launch_bounds__(256) void k_qkv(
    const float* __restrict__ feat,
    const float* __restrict__ wq, const float* __restrict__ bq,
    const float* __restrict__ wk, const float* __restrict__ bk,
    const float* __restrict__ wv, const float* __restrict__ bv,
    const float* __restrict__ coord, const int* __restrict__ ref,
    short* __restrict__ QlinH, short* __restrict__ KlinH, short* __restrict__ VlinH,
    float* __restrict__ stat)
{
    __shared__ short sA[4096];
    __shared__ float s_red[9];
    const int tid = threadIdx.x, lane = tid & 63, w = tid >> 6;
    const int q = lane >> 4, c15 = lane & 15;

    if (blockIdx.x >= QKV_BLOCKS) {
        // ---- pmom body ----
        float m[9];
        #pragma unroll
        for (int i = 0; i < 9; ++i) m[i] = 0.f;
        const int gid = (blockIdx.x - QKV_BLOCKS) * 256 + tid;
        const int stride = 128 * 256;
        for (int row = gid; row < NROW; row += stride) {
            int n = row >> 4;
            int idx = clip_idx(ref[row]);
            float px = coord[idx * 3 + 0] - coord[n * 3 + 0];
            float py = coord[idx * 3 + 1] - coord[n * 3 + 1];
            float pz = coord[idx * 3 + 2] - coord[n * 3 + 2];
            m[0] += px; m[1] += py; m[2] += pz;
            m[3] = fmaf(px, px, m[3]); m[4] = fmaf(py, py, m[4]); m[5] = fmaf(pz, pz, m[5]);
            m[6] = fmaf(px, py, m[6]); m[7] = fmaf(px, pz, m[7]); m[8] = fmaf(py, pz, m[8]);
        }
        if (tid < 9) s_red[tid] = 0.f;
        __syncthreads();
        #pragma unroll
        for (int off = 32; off >= 1; off >>= 1) {
            #pragma unroll
            for (int i = 0; i < 9; ++i) m[i] += __shfl_xor(m[i], off, 64);
        }
        if (lane == 0) {
            #pragma unroll
            for (int i = 0; i < 9; ++i) atomicAdd(&s_red[i], m[i]);
        }
        __syncthreads();
        if (tid < 9) atomicAdd(&stat[256 + tid], s_red[tid]);
        return;
    }

    // B fragments + bias: wave w owns global col-tiles 3w..3w+2 of [wq|wk|wv]
    short8 bfrag[3][2];
    float bias[3];
    #pragma unroll
    for (int t = 0; t < 3; ++t) {
        int gt = w * 3 + t;
        const float* W = (gt < 4) ? wq : (gt < 8) ? wk : wv;
        const float* B = (gt < 4) ? bq : (gt < 8) ? bk : bv;
        int col = (gt * 16 + c15) & 63;
        bias[t] = B[col];
        #pragma unroll
        for (int kt = 0; kt < 2; ++kt) {
            short8 bb;
            #pragma unroll
            for (int i = 0; i < 8; ++i) {
                int kk = kt * 32 + kib_of(i, q);
                bb[i] = (short)f2bf(W[kk * 64 + col]);
            }
            bfrag[t][kt] = bb;
        }
    }
    float st_s[3], st_q[3];
    #pragma unroll
    for (int t = 0; t < 3; ++t) { st_s[t] = 0.f; st_q[t] = 0.f; }
    const int pk = physK(lane);

    for (int b = blockIdx.x; b < NPB; b += QKV_BLOCKS) {
        const int pbase = b * 64;
        #pragma unroll 4
        for (int p = w * 16; p < w * 16 + 16; ++p) {
            int n = pbase + p;
            float v = (n < NPTS) ? feat[n * 64 + lane] : 0.f;
            sA[aOff(p, pk)] = (short)f2bf(v);
        }
        __syncthreads();
        #pragma unroll
        for (int mt = 0; mt < 4; ++mt) {
            int r = mt * 16 + c15;
            int ch0 = q ^ (r & 7);
            int ch1 = (4 + q) ^ (r & 7);
            short8 a0 = *(const short8*)(sA + r * 64 + (ch0 << 3));
            short8 a1 = *(const short8*)(sA + r * 64 + (ch1 << 3));
            #pragma unroll
            for (int t = 0; t < 3; ++t) {
                f32x4 acc = (f32x4){0.f, 0.f, 0.f, 0.f};
                acc = MFMA16(a0, bfrag[t][0], acc);
                acc = MFMA16(a1, bfrag[t][1], acc);
                int gt = w * 3 + t;
                #pragma unroll
                for (int rg = 0; rg < 4; ++rg) {
                    int row = mt * 16 + 4 * q + rg;
                    int n = pbase + row;
                    if (n < NPTS) {
                        unsigned short h = f2bf(acc[rg] + bias[t]);
                        float vr = bf2f(h);
                        if (gt < 4)      QlinH[n * 64 + gt * 16 + c15] = (short)h;
                        else if (gt < 8) KlinH[n * 64 + (gt - 4) * 16 + c15] = (short)h;
                        else             VlinH[n * 64 + (gt - 8) * 16 + c15] = (short)h;
                        if (gt < 8) { st_s[t] += vr; st_q[t] = fmaf(vr, vr, st_q[t]); }
                    }
                }
            }
        }
        __syncthreads();
    }
    #pragma unroll
    for (int t = 0; t < 3; ++t) {
        st_s[t] += __shfl_xor(st_s[t], 16, 64); st_s[t] += __shfl_xor(st_s[t], 32, 64);
        st_q[t] += __shfl_xor(st_q[t], 16, 64); st_q[t] += __shfl_xor(st_q[t], 32, 64);
    }
    if (q == 0) {
        #pragma unroll
        for (int t = 0; t < 3; ++t) {
            int gt = w * 3 + t;
            if (gt < 4) {
                atomicAdd(&stat[gt * 16 + c15], st_s[t]);
                atomicAdd(&stat[64 + gt * 16 + c15], st_q[t]);
            } else if (gt < 8) {
                atomicAdd(&stat[128 + (gt - 4) * 16 + c15], st_s[t]);
                atomicAdd(&stat[192 + (gt - 4) * 16 + c15], st_q[t]);
            }
        }
    }
}

// ---- finalize q/k/p BN affines ----
__global__ __launch_bounds__(192) void k_finA(
    const float* __restrict__ gq, const float* __restrict__ betaq,
    const float* __restrict__ gk, const float* __restrict__ betak,
    const float* __restrict__ gp, const float* __restrict__ betap,
    const float* __restrict__ wp1, const float* __restrict__ bp1,
    const float* __restrict__ stat, float* __restrict__ aff)
{
    int t = threadIdx.x;
    if (t < 64) {
        float m = stat[t] / (float)NPTS;
        float v = stat[64 + t] / (float)NPTS - m * m;
        float a = gq[t] * rsqrtf(v + BN_EPS);
        aff[t] = a;
        aff[64 + t] = betaq[t] - m * a;
    } else if (t < 128) {
        int c = t - 64;
        float m = stat[128 + c] / (float)NPTS;
        float v = stat[192 + c] / (float)NPTS - m * m;
        float a = gk[c] * rsqrtf(v + BN_EPS);
        aff[128 + c] = a;
        aff[192 + c] = betak[c] - m * a;
    } else {
        int c = t - 128;
        const float R = (float)NROW;
        float Ex = stat[256] / R, Ey = stat[257] / R, Ez = stat[258] / R;
        float Exx = stat[259] / R, Eyy = stat[260] / R, Ezz = stat[261] / R;
        float Exy = stat[262] / R, Exz = stat[263] / R, Eyz = stat[264] / R;
        float Cxx = Exx - Ex * Ex, Cyy = Eyy - Ey * Ey, Czz = Ezz - Ez * Ez;
        float Cxy = Exy - Ex * Ey, Cxz = Exz - Ex * Ez, Cyz = Eyz - Ey * Ez;
        float a0 = wp1[c], a1 = wp1[64 + c], a2 = wp1[128 + c];
        float mean = a0 * Ex + a1 * Ey + a2 * Ez + bp1[c];
        float var = a0 * a0 * Cxx + a1 * a1 * Cyy + a2 * a2 * Czz
                  + 2.f * (a0 * a1 * Cxy + a0 * a2 * Cxz + a1 * a2 * Cyz);
        float a = gp[c] * rsqrtf(var + BN_EPS);
        aff[256 + c] = a;
        aff[320 + c] = betap[c] - mean * a;
    }
}

// ---- per-point QW1/KW1 = relu_bn(Q/K) @ ww1 via MFMA ----
__global__ __launch_bounds__(128) void k_qkw(
    const short* __restrict__ QlinH, const short* __restrict__ KlinH,
    const float* __restrict__ ww1, const float* __restrict__ aff,
    float* __restrict__ QW1, float* __restrict__ KW1)
{
    __shared__ short sA[2][8192];
    const int tid = threadIdx.x, lane = tid & 63, w = tid >> 6;
    const int q = lane >> 4, g = lane & 15;
    short8 bimg[2];
    #pragma unroll
    for (int kt = 0; kt < 2; ++kt) {
        short8 bb;
        #pragma unroll
        for (int i = 0; i < 8; ++i) {
            int s = kt * 32 + kib_of(i, q);
            bb[i] = (short)f2bf(g < 8 ? ww1[s * 8 + g] : 0.f);
        }
        bimg[kt] = bb;
    }
    const float qa = aff[lane], qb = aff[64 + lane];
    const float ka = aff[128 + lane], kb = aff[192 + lane];
    short* AQ = sA[w];
    short* AK = sA[w] + 4096;
    const int pk = physK(lane);

    for (int b = blockIdx.x * 2 + w; b < NPB; b += gridDim.x * 2) {
        const int pbase = b * 64;
        #pragma unroll 8
        for (int p = 0; p < 64; ++p) {
            int n = pbase + p;
            float qv = 0.f, kv = 0.f;
            if (n < NPTS) {
                qv = fmaxf(fmaf(bf2f((unsigned short)QlinH[n * 64 + lane]), qa, qb), 0.f);
                kv = fmaxf(fmaf(bf2f((unsigned short)KlinH[n * 64 + lane]), ka, kb), 0.f);
            }
            AQ[aOff(p, pk)] = (short)f2bf(qv);
            AK[aOff(p, pk)] = (short)f2bf(kv);
        }
        #pragma unroll
        for (int mt = 0; mt < 4; ++mt) {
            f32x4 aq = (f32x4){0.f, 0.f, 0.f, 0.f};
            f32x4 ak = (f32x4){0.f, 0.f, 0.f, 0.f};
            int r = mt * 16 + g;
            #pragma unroll
            for (int kt = 0; kt < 2; ++kt) {
                int chunk = (kt * 4 + q) ^ (r & 7);
                aq = MFMA16(*(const short8*)(AQ + r * 64 + (chunk << 3)), bimg[kt], aq);
                ak = MFMA16(*(const short8*)(AK + r * 64 + (chunk << 3)), bimg[kt], ak);
            }
            if (g < 8) {
                #pragma unroll
                for (int rg = 0; rg < 4; ++rg) {
                    int n = pbase + mt * 16 + 4 * q + rg;
                    if (n < NPTS) {
                        QW1[n * 8 + g] = aq[rg];
                        KW1[n * 8 + g] = ak[rg];
                    }
                }
            }
        }
    }
}

// ---- W-branch BN stats: W1 = P1@w2w1 (MFMA) + KW1[idx] - QW1[n] + bw1 ----
__global__ __launch_bounds__(128) void k_wstats(
    const float* __restrict__ coord, const int* __restrict__ ref,
    const float* __restrict__ wp1, const float* __restrict__ bp1,
    const float* __restrict__ bw1, const float* __restrict__ w2w1,
    const float* __restrict__ QW1, const float* __restrict__ KW1,
    const float* __restrict__ aff, float* __restrict__ stat)
{
    __shared__ short sP[2][4096];
    __shared__ float sPos[2][256];
    __shared__ int   sIdx[2][64];
    __shared__ float sRed[16];
    const int tid = threadIdx.x, lane = tid & 63, w = tid >> 6;
    const int q = lane >> 4, g = lane & 15;
    short8 bimg[2];
    #pragma unroll
    for (int kt = 0; kt < 2; ++kt) {
        short8 bb;
        #pragma unroll
        for (int i = 0; i < 8; ++i) {
            int s = kt * 32 + kib_of(i, q);
            bb[i] = (short)f2bf(g < 8 ? w2w1[s * 8 + g] : 0.f);
        }
        bimg[kt] = bb;
    }
    if (tid < 16) sRed[tid] = 0.f;
    __syncthreads();

    const float pa = aff[256 + lane];
    const float A0 = pa * wp1[lane], A1 = pa * wp1[64 + lane], A2 = pa * wp1[128 + lane];
    const float B0 = fmaf(pa, bp1[lane], aff[320 + lane]);
    const float bwg = (g < 8) ? bw1[g] : 0.f;
    const int pk = physK(lane);

    short* P = sP[w];
    float* pos = sPos[w];
    int* idxs = sIdx[w];
    float accS = 0.f, accQ = 0.f;

    for (int b = blockIdx.x * 2 + w; b < NBATCH; b += gridDim.x * 2) {
        const int rbase = b * 64;
        const int p0 = b * 4;
        {
            int r = ref[rbase + lane];
            int idx = clip_idx(r);
            idxs[lane] = idx;
            int n = p0 + (lane >> 4);
            pos[lane * 4 + 0] = coord[idx * 3 + 0] - coord[n * 3 + 0];
            pos[lane * 4 + 1] = coord[idx * 3 + 1] - coord[n * 3 + 1];
            pos[lane * 4 + 2] = coord[idx * 3 + 2] - coord[n * 3 + 2];
        }
        #pragma unroll 8
        for (int rr = 0; rr < 64; ++rr) {
            f32x4 pp = *(const f32x4*)(pos + rr * 4);
            float p1v = fmaxf(fmaf(pp.x, A0, fmaf(pp.y, A1, fmaf(pp.z, A2, B0))), 0.f);
            P[aOff(rr, pk)] = (short)f2bf(p1v);
        }
        #pragma unroll
        for (int mt = 0; mt < 4; ++mt) {
            f32x4 acc = (f32x4){0.f, 0.f, 0.f, 0.f};
            int r = mt * 16 + g;
            #pragma unroll
            for (int kt = 0; kt < 2; ++kt) {
                int chunk = (kt * 4 + q) ^ (r & 7);
                acc = MFMA16(*(const short8*)(P + r * 64 + (chunk << 3)), bimg[kt], acc);
            }
            if (g < 8) {
                #pragma unroll
                for (int rg = 0; rg < 4; ++rg) {
                    int row = mt * 16 + 4 * q + rg;
                    float W = acc[rg] + KW1[idxs[row] * 8 + g]
                            - QW1[(p0 + (row >> 4)) * 8 + g] + bwg;
                    accS += W;
                    accQ = fmaf(W, W, accQ);
                }
            }
        }
    }
    accS += __shfl_xor(accS, 16, 64); accS += __shfl_xor(accS, 32, 64);
    accQ += __shfl_xor(accQ, 16, 64); accQ += __shfl_xor(accQ, 32, 64);
    if (lane < 8) {
        atomicAdd(&sRed[lane], accS);
        atomicAdd(&sRed[8 + lane], accQ);
    }
    __syncthreads();
    if (tid < 16) atomicAdd(&stat[384 + tid], sRed[tid]);
}

__global__ __launch_bounds__(64) void k_finB(
    const float* __restrict__ gw_, const float* __restrict__ betaw,
    const float* __restrict__ stat, float* __restrict__ aff)
{
    int t = threadIdx.x;
    if (t < 8) {
        const float M = (float)NROW;
        float m = stat[384 + t] / M;
        float v = stat[392 + t] / M - m * m;
        float a = gw_[t] * rsqrtf(v + BN_EPS);
        aff[384 + t] = a;
        aff[392 + t] = betaw[t] - m * a;
    }
}

// ---- final: W1 -> bn/relu -> w2 -> softmax; PEB (MFMA); einsum ----
__global__ __launch_bounds__(128) void k_final(
    const float* __restrict__ coord, const int* __restrict__ ref,
    const float* __restrict__ wp1, const float* __restrict__ bp1,
    const float* __restrict__ wp2, const float* __restrict__ bp2,
    const float* __restrict__ bw1, const float* __restrict__ w2w1,
    const float* __restrict__ ww2, const float* __restrict__ bw2,
    const float* __restrict__ QW1, const float* __restrict__ KW1,
    const short* __restrict__ VlinH,
    const float* __restrict__ aff, float* __restrict__ out)
{
    __shared__ short sP[2][4096];      // P1, overwritten by PEB per mt-tile
    __shared__ float sPos[2][256];
    __shared__ int   sIdx[2][64];
    __shared__ float sWn[2][576];
    const int tid = threadIdx.x, lane = tid & 63, w = tid >> 6;
    const int q = lane >> 4, g15 = lane & 15;

    short8 bw_img[2];
    #pragma unroll
    for (int kt = 0; kt < 2; ++kt) {
        short8 bb;
        #pragma unroll
        for (int i = 0; i < 8; ++i) {
            int s = kt * 32 + kib_of(i, q);
            bb[i] = (short)f2bf(g15 < 8 ? w2w1[s * 8 + g15] : 0.f);
        }
        bw_img[kt] = bb;
    }
    short8 b1[8];
    #pragma unroll
    for (int tt = 0; tt < 8; ++tt) {
        int kt = tt & 1, nt = tt >> 1;
        short8 bb;
        #pragma unroll
        for (int i = 0; i < 8; ++i) {
            int kk = kt * 32 + kib_of(i, q);
            bb[i] = (short)f2bf(wp2[kk * 64 + nt * 16 + g15]);
        }
        b1[tt] = bb;
    }

    const float pa = aff[256 + lane];
    const float A0 = pa * wp1[lane], A1 = pa * wp1[64 + lane], A2 = pa * wp1[128 + lane];
    const float B0 = fmaf(pa, bp1[lane], aff[320 + lane]);
    const float bp2l = bp2[lane];
    const float bwg = (g15 < 8) ? bw1[g15] : 0.f;
    const float wag = aff[384 + (g15 & 7)], wbg = aff[392 + (g15 & 7)];
    const int pk = physK(lane);

    short* P = sP[w];
    float* pos = sPos[w];
    int* idxs = sIdx[w];
    float* wn = sWn[w];

    for (int b = blockIdx.x * 2 + w; b < NBATCH; b += gridDim.x * 2) {
        const int rbase = b * 64;
        const int p0 = b * 4;
        {
            int r = ref[rbase + lane];
            int idx = clip_idx(r);
            idxs[lane] = idx;
            int n = p0 + (lane >> 4);
            pos[lane * 4 + 0] = coord[idx * 3 + 0] - coord[n * 3 + 0];
            pos[lane * 4 + 1] = coord[idx * 3 + 1] - coord[n * 3 + 1];
            pos[lane * 4 + 2] = coord[idx * 3 + 2] - coord[n * 3 + 2];
            pos[lane * 4 + 3] = (r >= 0) ? 1.f : 0.f;
        }
        // stage P1
        #pragma unroll 8
        for (int rr = 0; rr < 64; ++rr) {
            f32x4 pp = *(const f32x4*)(pos + rr * 4);
            float p1v = fmaxf(fmaf(pp.x, A0, fmaf(pp.y, A1, fmaf(pp.z, A2, B0))), 0.f);
            P[aOff(rr, pk)] = (short)f2bf(p1v);
        }
        // GEMM2: P1@w2w1 + per-point terms -> bn/relu -> wn
        #pragma unroll
        for (int mt = 0; mt < 4; ++mt) {
            f32x4 acc = (f32x4){0.f, 0.f, 0.f, 0.f};
            int r = mt * 16 + g15;
            #pragma unroll
            for (int kt = 0; kt < 2; ++kt) {
                int chunk = (kt * 4 + q) ^ (r & 7);
                acc = MFMA16(*(const short8*)(P + r * 64 + (chunk << 3)), bw_img[kt], acc);
            }
            if (g15 < 8) {
                #pragma unroll
                for (int rg = 0; rg < 4; ++rg) {
                    int row = mt * 16 + 4 * q + rg;
                    float W = acc[rg] + KW1[idxs[row] * 8 + g15]
                            - QW1[(p0 + (row >> 4)) * 8 + g15] + bwg;
                    wn[row * 9 + g15] = fmaxf(fmaf(wag, W, wbg), 0.f);
                }
            }
        }
        // lane = row: w2 + grouped masked softmax (16-lane point groups)
        {
            float h[8];
            #pragma unroll
            for (int gg = 0; gg < 8; ++gg) h[gg] = wn[lane * 9 + gg];
            float mask = pos[lane * 4 + 3];
            #pragma unroll
            for (int o = 0; o < 8; ++o) {
                float acc = bw2[o];
                #pragma unroll
                for (int gg = 0; gg < 8; ++gg) acc = fmaf(h[gg], ww2[gg * 8 + o], acc);
                float m = acc;
                m = fmaxf(m, __shfl_xor(m, 1, 64));
                m = fmaxf(m, __shfl_xor(m, 2, 64));
                m = fmaxf(m, __shfl_xor(m, 4, 64));
                m = fmaxf(m, __shfl_xor(m, 8, 64));
                float e = __expf(acc - m);
                float s = e;
                s += __shfl_xor(s, 1, 64);
                s += __shfl_xor(s, 2, 64);
                s += __shfl_xor(s, 4, 64);
                s += __shfl_xor(s, 8, 64);
                wn[lane * 9 + o] = e / s * mask;
            }
        }
        // GEMM1: PEB = P1@wp2, in-place writeback per mt-tile
        #pragma unroll
        for (int mt = 0; mt < 4; ++mt) {
            int r = mt * 16 + g15;
            int c0 = (0 * 4 + q) ^ (r & 7);
            int c1 = (1 * 4 + q) ^ (r & 7);
            short8 a0 = *(const short8*)(P + r * 64 + (c0 << 3));
            short8 a1 = *(const short8*)(P + r * 64 + (c1 << 3));
            #pragma unroll
            for (int nt = 0; nt < 4; ++nt) {
                f32x4 acc = (f32x4){0.f, 0.f, 0.f, 0.f};
                acc = MFMA16(a0, b1[nt * 2 + 0], acc);
                acc = MFMA16(a1, b1[nt * 2 + 1], acc);
                int pc = physK(nt * 16 + g15);
                #pragma unroll
                for (int rg = 0; rg < 4; ++rg) {
                    int row = mt * 16 + 4 * q + rg;
                    P[aOff(row, pc)] = (short)f2bf(acc[rg]);
                }
            }
        }
        // phase C: lane = channel; out = sum_k (V + peb + bp2) * w
        #pragma unroll
        for (int p = 0; p < 4; ++p) {
            float accO = 0.f;
            #pragma unroll 8
            for (int k = 0; k < 16; ++k) {
                int r = p * 16 + k;
                int idx = idxs[r];
                float val = bf2f((unsigned short)VlinH[idx * 64 + lane])
                          + bf2f((unsigned short)P[aOff(r, pk)]) + bp2l;
                accO = fmaf(val, wn[r * 9 + (lane >> 3)], accO);
            }
            out[(p0 + p) * 64 + lane] = accO;
        }
    }
}

extern "C" void kernel_launch(void* const* d_in, const int* in_sizes, int n_in,
                              void* d_out, int out_size, void* d_ws, size_t ws_size,
                              hipStream_t stream)
{
    const float* feat  = (const float*)d_in[0];
    const float* coord = (const float*)d_in[1];
    const int*   ref   = (const int*)d_in[2];
    const float* wq    = (const float*)d_in[3];
    const float* bq    = (const float*)d_in[4];
    const float* gq    = (const float*)d_in[5];
    const float* betaq = (const float*)d_in[6];
    const float* wk    = (const float*)d_in[7];
    const float* bk    = (const float*)d_in[8];
    const float* gk    = (const float*)d_in[9];
    const float* betak = (const float*)d_in[10];
    const float* wv    = (const float*)d_in[11];
    const float* bv    = (const float*)d_in[12];
    const float* wp1   = (const float*)d_in[13];
    const float* bp1   = (const float*)d_in[14];
    const float* gp    = (const float*)d_in[15];
    const float* betap = (const float*)d_in[16];
    const float* wp2   = (const float*)d_in[17];
    const float* bp2   = (const float*)d_in[18];
    const float* ww1   = (const float*)d_in[19];
    const float* bw1   = (const float*)d_in[20];
    const float* gw_   = (const float*)d_in[21];
    const float* betaw = (const float*)d_in[22];
    const float* ww2   = (const float*)d_in[23];
    const float* bw2   = (const float*)d_in[24];

    float* ws    = (float*)d_ws;
    short* QlinH = (short*)(ws + O_QLINH);
    short* KlinH = (short*)(ws + O_KLINH);
    short* VlinH = (short*)(ws + O_VLINH);
    float* stat  = ws + O_STAT;
    float* aff   = ws + O_AFF;
    float* w2w1  = ws + O_W2W1;
    float* QW1   = ws + O_QW1;
    float* KW1   = ws + O_KW1;
    float* out   = (float*)d_out;

    hipLaunchKernelGGL(k_prep, dim3(1), dim3(512), 0, stream, wp2, ww1, stat, w2w1);
    hipLaunchKernelGGL(k_qkv, dim3(QKV_BLOCKS + 128), dim3(256), 0, stream,
                       feat, wq, bq, wk, bk, wv, bv, coord, ref,
                       QlinH, KlinH, VlinH, stat);
    hipLaunchKernelGGL(k_finA, dim3(1), dim3(192), 0, stream,
                       gq, betaq, gk, betak, gp, betap, wp1, bp1, stat, aff);
    hipLaunchKernelGGL(k_qkw, dim3(782), dim3(128), 0, stream,
                       QlinH, KlinH, ww1, aff, QW1, KW1);
    hipLaunchKernelGGL(k_wstats, dim3(2500), dim3(128), 0, stream,
                       coord, ref, wp1, bp1, bw1, w2w1, QW1, KW1, aff, stat);
    hipLaunchKernelGGL(k_finB, dim3(1), dim3(64), 0, stream, gw_, betaw, stat, aff);
    hipLaunchKernelGGL(k_final, dim3(2500), dim3(128), 0, stream,
                       coord, ref, wp1, bp1, wp2, bp2, bw1, w2w1, ww2, bw2,
                       QW1, KW1, VlinH, aff, out);
}

// Round 6
// 318.184 us; speedup vs baseline: 12.8861x; 1.0833x over previous
//
#include <hip/hip_runtime.h>
#include <hip/hip_bf16.h>

#define NPTS 100000
#define KNBR 16
#define CCH  64
#define GRP  8
#define BN_EPS 1e-5f
#define NROW (NPTS * KNBR)        // 1,600,000
#define NBATCH (NROW / 64)        // 25,000 batches of 64 rows (4 points)
#define NPB   ((NPTS + 63) / 64)  // 1563 point-batches

// ---- workspace layout (float offsets) ----
#define O_QLINH 0                  // NPTS*64 bf16 = NPTS*32 floats
#define O_KLINH (NPTS * 32)
#define O_VLINH (NPTS * 64)
#define O_STAT  (NPTS * 96)        // 416 floats of stats
#define O_AFF   (O_STAT + 416)     // 416 floats of affines
#define O_W2W1  (O_AFF + 416)      // 512 floats: wp2@ww1 [64][8]
#define O_QW1   (O_W2W1 + 512)     // NPTS*8 fp32
#define O_KW1   (O_QW1 + NPTS * 8) // NPTS*8 fp32

typedef __attribute__((ext_vector_type(8))) short short8;
typedef __attribute__((ext_vector_type(4))) short short4v;
typedef __attribute__((ext_vector_type(4))) float f32x4;
#define MFMA16(a, b, c) __builtin_amdgcn_mfma_f32_16x16x32_bf16(a, b, c, 0, 0, 0)

__device__ __forceinline__ int clip_idx(int r) {
    int i = r < 0 ? 0 : r;
    return i >= NPTS ? NPTS - 1 : i;
}
__device__ __forceinline__ unsigned short f2bf(float x) {
    union { float f; unsigned u; } v; v.f = x;
    unsigned r = v.u + 0x7fffu + ((v.u >> 16) & 1u);
    return (unsigned short)(r >> 16);
}
__device__ __forceinline__ float bf2f(unsigned short h) {
    union { unsigned u; float f; } v; v.u = ((unsigned)h) << 16;
    return v.f;
}
// K-slot s -> physical short offset within a row (A-fragment-linear order)
__device__ __forceinline__ int physK(int s) {
    return (s >> 5) * 32 + ((s >> 2) & 3) * 8 + ((s >> 4) & 1) * 4 + (s & 3);
}
// short index into a [64 rows][64 K-slots] A-buffer with 16B-chunk XOR swizzle
__device__ __forceinline__ int aOff(int r, int p) {
    return r * 64 + (((p >> 3) ^ (r & 7)) << 3) + (p & 7);
}
// element i of a B fragment for quarter q: K-in-block index
__device__ __forceinline__ int kib_of(int i, int q) {
    return (i < 4) ? (4 * q + i) : (16 + 4 * q + (i - 4));
}

// ---- prep: zero stats + w2w1 = wp2@ww1 ----
__global__ __launch_bounds__(512) void k_prep(
    const float* __restrict__ wp2, const float* __restrict__ ww1,
    float* __restrict__ stat, float* __restrict__ w2w1)
{
    int t = threadIdx.x;
    if (t < 416) stat[t] = 0.f;
    int j = t >> 3, g = t & 7;
    float acc = 0.f;
    #pragma unroll 16
    for (int c = 0; c < 64; ++c) acc = fmaf(wp2[j * 64 + c], ww1[c * 8 + g], acc);
    w2w1[t] = acc;
}

// ---- Q/K/V projection via MFMA + Q/K BN stats; pmom fused as extra blocks ----
#define QKV_BLOCKS 512
__global__ __launch_bounds__(256) void k_qkv(
    const float* __restrict__ feat,
    const float* __restrict__ wq, const float* __restrict__ bq,
    const float* __restrict__ wk, const float* __restrict__ bk,
    const float* __restrict__ wv, const float* __restrict__ bv,
    const float* __restrict__ coord, const int* __restrict__ ref,
    short* __restrict__ QlinH, short* __restrict__ KlinH, short* __restrict__ VlinH,
    float* __restrict__ stat)
{
    __shared__ short sA[4096];
    __shared__ float s_red[9];
    const int tid = threadIdx.x, lane = tid & 63, w = tid >> 6;
    const int q = lane >> 4, c15 = lane & 15;

    if (blockIdx.x >= QKV_BLOCKS) {
        // ---- pmom body ----
        float m[9];
        #pragma unroll
        for (int i = 0; i < 9; ++i) m[i] = 0.f;
        const int gid = (blockIdx.x - QKV_BLOCKS) * 256 + tid;
        const int stride = 128 * 256;
        for (int row = gid; row < NROW; row += stride) {
            int n = row >> 4;
            int idx = clip_idx(ref[row]);
            float px = coord[idx * 3 + 0] - coord[n * 3 + 0];
            float py = coord[idx * 3 + 1] - coord[n * 3 + 1];
            float pz = coord[idx * 3 + 2] - coord[n * 3 + 2];
            m[0] += px; m[1] += py; m[2] += pz;
            m[3] = fmaf(px, px, m[3]); m[4] = fmaf(py, py, m[4]); m[5] = fmaf(pz, pz, m[5]);
            m[6] = fmaf(px, py, m[6]); m[7] = fmaf(px, pz, m[7]); m[8] = fmaf(py, pz, m[8]);
        }
        if (tid < 9) s_red[tid] = 0.f;
        __syncthreads();
        #pragma unroll
        for (int off = 32; off >= 1; off >>= 1) {
            #pragma unroll
            for (int i = 0; i < 9; ++i) m[i] += __shfl_xor(m[i], off, 64);
        }
        if (lane == 0) {
            #pragma unroll
            for (int i = 0; i < 9; ++i) atomicAdd(&s_red[i], m[i]);
        }
        __syncthreads();
        if (tid < 9) atomicAdd(&stat[256 + tid], s_red[tid]);
        return;
    }

    // B fragments + bias: wave w owns global col-tiles 3w..3w+2 of [wq|wk|wv]
    short8 bfrag[3][2];
    float bias[3];
    #pragma unroll
    for (int t = 0; t < 3; ++t) {
        int gt = w * 3 + t;
        const float* W = (gt < 4) ? wq : (gt < 8) ? wk : wv;
        const float* B = (gt < 4) ? bq : (gt < 8) ? bk : bv;
        int col = (gt * 16 + c15) & 63;
        bias[t] = B[col];
        #pragma unroll
        for (int kt = 0; kt < 2; ++kt) {
            short8 bb;
            #pragma unroll
            for (int i = 0; i < 8; ++i) {
                int kk = kt * 32 + kib_of(i, q);
                bb[i] = (short)f2bf(W[kk * 64 + col]);
            }
            bfrag[t][kt] = bb;
        }
    }
    float st_s[3], st_q[3];
    #pragma unroll
    for (int t = 0; t < 3; ++t) { st_s[t] = 0.f; st_q[t] = 0.f; }

    const int c4 = c15 * 4;              // 4-channel group
    const int pk4 = physK(c4);           // contiguous 4 slots

    for (int b = blockIdx.x; b < NPB; b += QKV_BLOCKS) {
        const int pbase = b * 64;
        // staging: float4 loads, 4 rows per instr
        #pragma unroll
        for (int i = 0; i < 4; ++i) {
            int p = w * 16 + i * 4 + q;
            int n = pbase + p;
            float4 v = make_float4(0.f, 0.f, 0.f, 0.f);
            if (n < NPTS) v = *(const float4*)(feat + n * 64 + c4);
            short4v h;
            h[0] = (short)f2bf(v.x); h[1] = (short)f2bf(v.y);
            h[2] = (short)f2bf(v.z); h[3] = (short)f2bf(v.w);
            *(short4v*)(sA + aOff(p, pk4)) = h;
        }
        __syncthreads();
        #pragma unroll
        for (int mt = 0; mt < 4; ++mt) {
            int r = mt * 16 + c15;
            int ch0 = q ^ (r & 7);
            int ch1 = (4 + q) ^ (r & 7);
            short8 a0 = *(const short8*)(sA + r * 64 + (ch0 << 3));
            short8 a1 = *(const short8*)(sA + r * 64 + (ch1 << 3));
            #pragma unroll
            for (int t = 0; t < 3; ++t) {
                f32x4 acc = (f32x4){0.f, 0.f, 0.f, 0.f};
                acc = MFMA16(a0, bfrag[t][0], acc);
                acc = MFMA16(a1, bfrag[t][1], acc);
                int gt = w * 3 + t;
                #pragma unroll
                for (int rg = 0; rg < 4; ++rg) {
                    int row = mt * 16 + 4 * q + rg;
                    int n = pbase + row;
                    if (n < NPTS) {
                        unsigned short h = f2bf(acc[rg] + bias[t]);
                        float vr = bf2f(h);
                        if (gt < 4)      QlinH[n * 64 + gt * 16 + c15] = (short)h;
                        else if (gt < 8) KlinH[n * 64 + (gt - 4) * 16 + c15] = (short)h;
                        else             VlinH[n * 64 + (gt - 8) * 16 + c15] = (short)h;
                        if (gt < 8) { st_s[t] += vr; st_q[t] = fmaf(vr, vr, st_q[t]); }
                    }
                }
            }
        }
        __syncthreads();
    }
    #pragma unroll
    for (int t = 0; t < 3; ++t) {
        st_s[t] += __shfl_xor(st_s[t], 16, 64); st_s[t] += __shfl_xor(st_s[t], 32, 64);
        st_q[t] += __shfl_xor(st_q[t], 16, 64); st_q[t] += __shfl_xor(st_q[t], 32, 64);
    }
    if (q == 0) {
        #pragma unroll
        for (int t = 0; t < 3; ++t) {
            int gt = w * 3 + t;
            if (gt < 4) {
                atomicAdd(&stat[gt * 16 + c15], st_s[t]);
                atomicAdd(&stat[64 + gt * 16 + c15], st_q[t]);
            } else if (gt < 8) {
                atomicAdd(&stat[128 + (gt - 4) * 16 + c15], st_s[t]);
                atomicAdd(&stat[192 + (gt - 4) * 16 + c15], st_q[t]);
            }
        }
    }
}

// ---- finalize q/k/p BN affines ----
__global__ __launch_bounds__(192) void k_finA(
    const float* __restrict__ gq, const float* __restrict__ betaq,
    const float* __restrict__ gk, const float* __restrict__ betak,
    const float* __restrict__ gp, const float* __restrict__ betap,
    const float* __restrict__ wp1, const float* __restrict__ bp1,
    const float* __restrict__ stat, float* __restrict__ aff)
{
    int t = threadIdx.x;
    if (t < 64) {
        float m = stat[t] / (float)NPTS;
        float v = stat[64 + t] / (float)NPTS - m * m;
        float a = gq[t] * rsqrtf(v + BN_EPS);
        aff[t] = a;
        aff[64 + t] = betaq[t] - m * a;
    } else if (t < 128) {
        int c = t - 64;
        float m = stat[128 + c] / (float)NPTS;
        float v = stat[192 + c] / (float)NPTS - m * m;
        float a = gk[c] * rsqrtf(v + BN_EPS);
        aff[128 + c] = a;
        aff[192 + c] = betak[c] - m * a;
    } else {
        int c = t - 128;
        const float R = (float)NROW;
        float Ex = stat[256] / R, Ey = stat[257] / R, Ez = stat[258] / R;
        float Exx = stat[259] / R, Eyy = stat[260] / R, Ezz = stat[261] / R;
        float Exy = stat[262] / R, Exz = stat[263] / R, Eyz = stat[264] / R;
        float Cxx = Exx - Ex * Ex, Cyy = Eyy - Ey * Ey, Czz = Ezz - Ez * Ez;
        float Cxy = Exy - Ex * Ey, Cxz = Exz - Ex * Ez, Cyz = Eyz - Ey * Ez;
        float a0 = wp1[c], a1 = wp1[64 + c], a2 = wp1[128 + c];
        float mean = a0 * Ex + a1 * Ey + a2 * Ez + bp1[c];
        float var = a0 * a0 * Cxx + a1 * a1 * Cyy + a2 * a2 * Czz
                  + 2.f * (a0 * a1 * Cxy + a0 * a2 * Cxz + a1 * a2 * Cyz);
        float a = gp[c] * rsqrtf(var + BN_EPS);
        aff[256 + c] = a;
        aff[320 + c] = betap[c] - mean * a;
    }
}

// ---- per-point QW1/KW1 = relu_bn(Q/K) @ ww1 via MFMA ----
__global__ __launch_bounds__(128) void k_qkw(
    const short* __restrict__ QlinH, const short* __restrict__ KlinH,
    const float* __restrict__ ww1, const float* __restrict__ aff,
    float* __restrict__ QW1, float* __restrict__ KW1)
{
    __shared__ short sA[2][8192];
    const int tid = threadIdx.x, lane = tid & 63, w = tid >> 6;
    const int q = lane >> 4, g = lane & 15;
    short8 bimg[2];
    #pragma unroll
    for (int kt = 0; kt < 2; ++kt) {
        short8 bb;
        #pragma unroll
        for (int i = 0; i < 8; ++i) {
            int s = kt * 32 + kib_of(i, q);
            bb[i] = (short)f2bf(g < 8 ? ww1[s * 8 + g] : 0.f);
        }
        bimg[kt] = bb;
    }
    // staging coeffs: lane handles 8 channels c8..c8+7 of 8 rows
    const int r8 = lane >> 3, c8 = (lane & 7) * 8;
    f32x4 qa0 = *(const f32x4*)(aff + c8),       qa1 = *(const f32x4*)(aff + c8 + 4);
    f32x4 qb0 = *(const f32x4*)(aff + 64 + c8),  qb1 = *(const f32x4*)(aff + 64 + c8 + 4);
    f32x4 ka0 = *(const f32x4*)(aff + 128 + c8), ka1 = *(const f32x4*)(aff + 128 + c8 + 4);
    f32x4 kb0 = *(const f32x4*)(aff + 192 + c8), kb1 = *(const f32x4*)(aff + 192 + c8 + 4);
    const int pkA = physK(c8), pkB = physK(c8 + 4);
    short* AQ = sA[w];
    short* AK = sA[w] + 4096;

    for (int b = blockIdx.x * 2 + w; b < NPB; b += gridDim.x * 2) {
        const int pbase = b * 64;
        #pragma unroll
        for (int it = 0; it < 8; ++it) {
            int p = it * 8 + r8;
            int n = pbase + p;
            short8 qraw = {0,0,0,0,0,0,0,0}, kraw = {0,0,0,0,0,0,0,0};
            if (n < NPTS) {
                qraw = *(const short8*)(QlinH + n * 64 + c8);
                kraw = *(const short8*)(KlinH + n * 64 + c8);
            }
            short4v qlo, qhi, klo, khi;
            #pragma unroll
            for (int e = 0; e < 4; ++e) {
                qlo[e] = (short)f2bf(fmaxf(fmaf(bf2f((unsigned short)qraw[e]), qa0[e], qb0[e]), 0.f));
                qhi[e] = (short)f2bf(fmaxf(fmaf(bf2f((unsigned short)qraw[e + 4]), qa1[e], qb1[e]), 0.f));
                klo[e] = (short)f2bf(fmaxf(fmaf(bf2f((unsigned short)kraw[e]), ka0[e], kb0[e]), 0.f));
                khi[e] = (short)f2bf(fmaxf(fmaf(bf2f((unsigned short)kraw[e + 4]), ka1[e], kb1[e]), 0.f));
            }
            *(short4v*)(AQ + aOff(p, pkA)) = qlo;
            *(short4v*)(AQ + aOff(p, pkB)) = qhi;
            *(short4v*)(AK + aOff(p, pkA)) = klo;
            *(short4v*)(AK + aOff(p, pkB)) = khi;
        }
        #pragma unroll
        for (int mt = 0; mt < 4; ++mt) {
            f32x4 aq = (f32x4){0.f, 0.f, 0.f, 0.f};
            f32x4 ak = (f32x4){0.f, 0.f, 0.f, 0.f};
            int r = mt * 16 + g;
            #pragma unroll
            for (int kt = 0; kt < 2; ++kt) {
                int chunk = (kt * 4 + q) ^ (r & 7);
                aq = MFMA16(*(const short8*)(AQ + r * 64 + (chunk << 3)), bimg[kt], aq);
                ak = MFMA16(*(const short8*)(AK + r * 64 + (chunk << 3)), bimg[kt], ak);
            }
            if (g < 8) {
                #pragma unroll
                for (int rg = 0; rg < 4; ++rg) {
                    int n = pbase + mt * 16 + 4 * q + rg;
                    if (n < NPTS) {
                        QW1[n * 8 + g] = aq[rg];
                        KW1[n * 8 + g] = ak[rg];
                    }
                }
            }
        }
    }
}

// ---- W-branch BN stats: W1 = P1@w2w1 (MFMA) + KW1[idx] - QW1[n] + bw1 ----
__global__ __launch_bounds__(128) void k_wstats(
    const float* __restrict__ coord, const int* __restrict__ ref,
    const float* __restrict__ wp1, const float* __restrict__ bp1,
    const float* __restrict__ bw1, const float* __restrict__ w2w1,
    const float* __restrict__ QW1, const float* __restrict__ KW1,
    const float* __restrict__ aff, float* __restrict__ stat)
{
    __shared__ short sP[2][4096];
    __shared__ float sPos[2][256];
    __shared__ int   sIdx[2][64];
    __shared__ float sRed[16];
    const int tid = threadIdx.x, lane = tid & 63, w = tid >> 6;
    const int q = lane >> 4, g = lane & 15;
    short8 bimg[2];
    #pragma unroll
    for (int kt = 0; kt < 2; ++kt) {
        short8 bb;
        #pragma unroll
        for (int i = 0; i < 8; ++i) {
            int s = kt * 32 + kib_of(i, q);
            bb[i] = (short)f2bf(g < 8 ? w2w1[s * 8 + g] : 0.f);
        }
        bimg[kt] = bb;
    }
    if (tid < 16) sRed[tid] = 0.f;
    __syncthreads();

    const float pa = aff[256 + lane];
    const float A0 = pa * wp1[lane], A1 = pa * wp1[64 + lane], A2 = pa * wp1[128 + lane];
    const float B0 = fmaf(pa, bp1[lane], aff[320 + lane]);
    const float bwg = (g < 8) ? bw1[g] : 0.f;
    const int pk = physK(lane);

    short* P = sP[w];
    float* pos = sPos[w];
    int* idxs = sIdx[w];
    float accS = 0.f, accQ = 0.f;

    for (int b = blockIdx.x * 2 + w; b < NBATCH; b += gridDim.x * 2) {
        const int rbase = b * 64;
        const int p0 = b * 4;
        {
            int r = ref[rbase + lane];
            int idx = clip_idx(r);
            idxs[lane] = idx;
            int n = p0 + (lane >> 4);
            pos[lane * 4 + 0] = coord[idx * 3 + 0] - coord[n * 3 + 0];
            pos[lane * 4 + 1] = coord[idx * 3 + 1] - coord[n * 3 + 1];
            pos[lane * 4 + 2] = coord[idx * 3 + 2] - coord[n * 3 + 2];
        }
        #pragma unroll 8
        for (int rr = 0; rr < 64; ++rr) {
            f32x4 pp = *(const f32x4*)(pos + rr * 4);
            float p1v = fmaxf(fmaf(pp.x, A0, fmaf(pp.y, A1, fmaf(pp.z, A2, B0))), 0.f);
            P[aOff(rr, pk)] = (short)f2bf(p1v);
        }
        #pragma unroll
        for (int mt = 0; mt < 4; ++mt) {
            f32x4 acc = (f32x4){0.f, 0.f, 0.f, 0.f};
            int r = mt * 16 + g;
            #pragma unroll
            for (int kt = 0; kt < 2; ++kt) {
                int chunk = (kt * 4 + q) ^ (r & 7);
                acc = MFMA16(*(const short8*)(P + r * 64 + (chunk << 3)), bimg[kt], acc);
            }
            if (g < 8) {
                int4 idx4 = *(const int4*)(idxs + mt * 16 + 4 * q);
                int ia[4] = {idx4.x, idx4.y, idx4.z, idx4.w};
                float dq = bwg - QW1[(p0 + mt) * 8 + g];
                #pragma unroll
                for (int rg = 0; rg < 4; ++rg) {
                    float W = acc[rg] + KW1[ia[rg] * 8 + g] + dq;
                    accS += W;
                    accQ = fmaf(W, W, accQ);
                }
            }
        }
    }
    accS += __shfl_xor(accS, 16, 64); accS += __shfl_xor(accS, 32, 64);
    accQ += __shfl_xor(accQ, 16, 64); accQ += __shfl_xor(accQ, 32, 64);
    if (lane < 8) {
        atomicAdd(&sRed[lane], accS);
        atomicAdd(&sRed[8 + lane], accQ);
    }
    __syncthreads();
    if (tid < 16) atomicAdd(&stat[384 + tid], sRed[tid]);
}

__global__ __launch_bounds__(64) void k_finB(
    const float* __restrict__ gw_, const float* __restrict__ betaw,
    const float* __restrict__ stat, float* __restrict__ aff)
{
    int t = threadIdx.x;
    if (t < 8) {
        const float M = (float)NROW;
        float m = stat[384 + t] / M;
        float v = stat[392 + t] / M - m * m;
        float a = gw_[t] * rsqrtf(v + BN_EPS);
        aff[384 + t] = a;
        aff[392 + t] = betaw[t] - m * a;
    }
}

// ---- final: W1 -> bn/relu -> w2 -> softmax; PEB GEMM fused with einsum ----
__global__ __launch_bounds__(128) void k_final(
    const float* __restrict__ coord, const int* __restrict__ ref,
    const float* __restrict__ wp1, const float* __restrict__ bp1,
    const float* __restrict__ wp2, const float* __restrict__ bp2,
    const float* __restrict__ bw1, const float* __restrict__ w2w1,
    const float* __restrict__ ww2, const float* __restrict__ bw2,
    const float* __restrict__ QW1, const float* __restrict__ KW1,
    const short* __restrict__ VlinH,
    const float* __restrict__ aff, float* __restrict__ out)
{
    __shared__ short sP[2][4096];      // P1 (stays intact)
    __shared__ float sPos[2][256];
    __shared__ int   sIdx[2][64];
    __shared__ float sWn[2][576];
    __shared__ float sW2[72];          // ww2[64] + bw2[8], block-shared
    const int tid = threadIdx.x, lane = tid & 63, w = tid >> 6;
    const int q = lane >> 4, g15 = lane & 15;

    if (tid < 64) sW2[tid] = ww2[tid];
    else if (tid < 72) sW2[tid] = bw2[tid - 64];
    __syncthreads();

    short8 bw_img[2];
    #pragma unroll
    for (int kt = 0; kt < 2; ++kt) {
        short8 bb;
        #pragma unroll
        for (int i = 0; i < 8; ++i) {
            int s = kt * 32 + kib_of(i, q);
            bb[i] = (short)f2bf(g15 < 8 ? w2w1[s * 8 + g15] : 0.f);
        }
        bw_img[kt] = bb;
    }
    short8 b1[8];
    #pragma unroll
    for (int tt = 0; tt < 8; ++tt) {
        int kt = tt & 1, nt = tt >> 1;
        short8 bb;
        #pragma unroll
        for (int i = 0; i < 8; ++i) {
            int kk = kt * 32 + kib_of(i, q);
            bb[i] = (short)f2bf(wp2[kk * 64 + nt * 16 + g15]);
        }
        b1[tt] = bb;
    }

    const float pa = aff[256 + lane];
    const float A0 = pa * wp1[lane], A1 = pa * wp1[64 + lane], A2 = pa * wp1[128 + lane];
    const float B0 = fmaf(pa, bp1[lane], aff[320 + lane]);
    const float bwg = (g15 < 8) ? bw1[g15] : 0.f;
    const float wag = aff[384 + (g15 & 7)], wbg = aff[392 + (g15 & 7)];
    const int pk = physK(lane);
    float bp2v[4];
    #pragma unroll
    for (int nt = 0; nt < 4; ++nt) bp2v[nt] = bp2[nt * 16 + g15];

    short* P = sP[w];
    float* pos = sPos[w];
    int* idxs = sIdx[w];
    float* wn = sWn[w];

    for (int b = blockIdx.x * 2 + w; b < NBATCH; b += gridDim.x * 2) {
        const int rbase = b * 64;
        const int p0 = b * 4;
        {
            int r = ref[rbase + lane];
            int idx = clip_idx(r);
            idxs[lane] = idx;
            int n = p0 + (lane >> 4);
            pos[lane * 4 + 0] = coord[idx * 3 + 0] - coord[n * 3 + 0];
            pos[lane * 4 + 1] = coord[idx * 3 + 1] - coord[n * 3 + 1];
            pos[lane * 4 + 2] = coord[idx * 3 + 2] - coord[n * 3 + 2];
            pos[lane * 4 + 3] = (r >= 0) ? 1.f : 0.f;
        }
        // stage P1
        #pragma unroll 8
        for (int rr = 0; rr < 64; ++rr) {
            f32x4 pp = *(const f32x4*)(pos + rr * 4);
            float p1v = fmaxf(fmaf(pp.x, A0, fmaf(pp.y, A1, fmaf(pp.z, A2, B0))), 0.f);
            P[aOff(rr, pk)] = (short)f2bf(p1v);
        }
        // GEMM2: P1@w2w1 + per-point terms -> bn/relu -> wn
        #pragma unroll
        for (int mt = 0; mt < 4; ++mt) {
            f32x4 acc = (f32x4){0.f, 0.f, 0.f, 0.f};
            int r = mt * 16 + g15;
            #pragma unroll
            for (int kt = 0; kt < 2; ++kt) {
                int chunk = (kt * 4 + q) ^ (r & 7);
                acc = MFMA16(*(const short8*)(P + r * 64 + (chunk << 3)), bw_img[kt], acc);
            }
            if (g15 < 8) {
                int4 idx4 = *(const int4*)(idxs + mt * 16 + 4 * q);
                int ia[4] = {idx4.x, idx4.y, idx4.z, idx4.w};
                float dq = bwg - QW1[(p0 + mt) * 8 + g15];
                #pragma unroll
                for (int rg = 0; rg < 4; ++rg) {
                    int row = mt * 16 + 4 * q + rg;
                    float W = acc[rg] + KW1[ia[rg] * 8 + g15] + dq;
                    wn[row * 9 + g15] = fmaxf(fmaf(wag, W, wbg), 0.f);
                }
            }
        }
        // lane = row: w2 + grouped masked softmax (no max-sub: BN-bounded logits)
        {
            float h[8];
            #pragma unroll
            for (int gg = 0; gg < 8; ++gg) h[gg] = wn[lane * 9 + gg];
            float mask = pos[lane * 4 + 3];
            #pragma unroll
            for (int o = 0; o < 8; ++o) {
                float acc = sW2[64 + o];
                #pragma unroll
                for (int gg = 0; gg < 8; ++gg) acc = fmaf(h[gg], sW2[gg * 8 + o], acc);
                float e = __expf(acc);
                float s = e;
                s += __shfl_xor(s, 1, 64);
                s += __shfl_xor(s, 2, 64);
                s += __shfl_xor(s, 4, 64);
                s += __shfl_xor(s, 8, 64);
                wn[lane * 9 + o] = e * __builtin_amdgcn_rcpf(s) * mask;
            }
        }
        // GEMM1 (PEB) fused with einsum: no writeback, direct output
        #pragma unroll
        for (int mt = 0; mt < 4; ++mt) {
            int r = mt * 16 + g15;
            int c0 = q ^ (r & 7);
            int c1 = (4 + q) ^ (r & 7);
            short8 a0 = *(const short8*)(P + r * 64 + (c0 << 3));
            short8 a1 = *(const short8*)(P + r * 64 + (c1 << 3));
            int4 idx4 = *(const int4*)(idxs + mt * 16 + 4 * q);
            int ia[4] = {idx4.x, idx4.y, idx4.z, idx4.w};
            const int ro0 = (mt * 16 + 4 * q) * 9;
            #pragma unroll
            for (int nt = 0; nt < 4; ++nt) {
                f32x4 acc = (f32x4){0.f, 0.f, 0.f, 0.f};
                acc = MFMA16(a0, b1[nt * 2 + 0], acc);
                acc = MFMA16(a1, b1[nt * 2 + 1], acc);
                int col = nt * 16 + g15;
                int o = nt * 2 + (g15 >> 3);
                float part = 0.f;
                #pragma unroll
                for (int rg = 0; rg < 4; ++rg) {
                    float v = bf2f((unsigned short)VlinH[ia[rg] * 64 + col]);
                    float t = acc[rg] + bp2v[nt];
                    part = fmaf(v + t, wn[ro0 + rg * 9 + o], part);
                }
                part += __shfl_xor(part, 16, 64);
                part += __shfl_xor(part, 32, 64);
                if (q == 0) out[(p0 + mt) * 64 + col] = part;
            }
        }
    }
}

extern "C" void kernel_launch(void* const* d_in, const int* in_sizes, int n_in,
                              void* d_out, int out_size, void* d_ws, size_t ws_size,
                              hipStream_t stream)
{
    const float* feat  = (const float*)d_in[0];
    const float* coord = (const float*)d_in[1];
    const int*   ref   = (const int*)d_in[2];
    const float* wq    = (const float*)d_in[3];
    const float* bq    = (const float*)d_in[4];
    const float* gq    = (const float*)d_in[5];
    const float* betaq = (const float*)d_in[6];
    const float* wk    = (const float*)d_in[7];
    const float* bk    = (const float*)d_in[8];
    const float* gk    = (const float*)d_in[9];
    const float* betak = (const float*)d_in[10];
    const float* wv    = (const float*)d_in[11];
    const float* bv    = (const float*)d_in[12];
    const float* wp1   = (const float*)d_in[13];
    const float* bp1   = (const float*)d_in[14];
    const float* gp    = (const float*)d_in[15];
    const float* betap = (const float*)d_in[16];
    const float* wp2   = (const float*)d_in[17];
    const float* bp2   = (const float*)d_in[18];
    const float* ww1   = (const float*)d_in[19];
    const float* bw1   = (const float*)d_in[20];
    const float* gw_   = (const float*)d_in[21];
    const float* betaw = (const float*)d_in[22];
    const float* ww2   = (const float*)d_in[23];
    const float* bw2   = (const float*)d_in[24];

    float* ws    = (float*)d_ws;
    short* QlinH = (short*)(ws + O_QLINH);
    short* KlinH = (short*)(ws + O_KLINH);
    short* VlinH = (short*)(ws + O_VLINH);
    float* stat  = ws + O_STAT;
    float* aff   = ws + O_AFF;
    float* w2w1  = ws + O_W2W1;
    float* QW1   = ws + O_QW1;
    float* KW1   = ws + O_KW1;
    float* out   = (float*)d_out;

    hipLaunchKernelGGL(k_prep, dim3(1), dim3(512), 0, stream, wp2, ww1, stat, w2w1);
    hipLaunchKernelGGL(k_qkv, dim3(QKV_BLOCKS + 128), dim3(256), 0, stream,
                       feat, wq, bq, wk, bk, wv, bv, coord, ref,
                       QlinH, KlinH, VlinH, stat);
    hipLaunchKernelGGL(k_finA, dim3(1), dim3(192), 0, stream,
                       gq, betaq, gk, betak, gp, betap, wp1, bp1, stat, aff);
    hipLaunchKernelGGL(k_qkw, dim3(782), dim3(128), 0, stream,
                       QlinH, KlinH, ww1, aff, QW1, KW1);
    hipLaunchKernelGGL(k_wstats, dim3(2500), dim3(128), 0, stream,
                       coord, ref, wp1, bp1, bw1, w2w1, QW1, KW1, aff, stat);
    hipLaunchKernelGGL(k_finB, dim3(1), dim3(64), 0, stream, gw_, betaw, stat, aff);
    hipLaunchKernelGGL(k_final, dim3(2500), dim3(128), 0, stream,
                       coord, ref, wp1, bp1, wp2, bp2, bw1, w2w1, ww2, bw2,
                       QW1, KW1, VlinH, aff, out);
}

// Round 7
// 263.646 us; speedup vs baseline: 15.5518x; 1.2069x over previous
//
#include <hip/hip_runtime.h>
#include <hip/hip_bf16.h>

#define NPTS 100000
#define KNBR 16
#define CCH  64
#define GRP  8
#define BN_EPS 1e-5f
#define NROW (NPTS * KNBR)        // 1,600,000
#define NBATCH (NROW / 64)        // 25,000 batches of 64 rows (4 points)
#define NPB   ((NPTS + 63) / 64)  // 1563 point-batches

// ---- workspace layout (float offsets) ----
#define O_QLINH 0                  // NPTS*64 bf16 = NPTS*32 floats
#define O_KLINH (NPTS * 32)
#define O_VLINH (NPTS * 64)
#define O_STAT  (NPTS * 96)        // 416 floats of stats
#define O_AFF   (O_STAT + 416)     // 416 floats of affines
#define O_W2W1  (O_AFF + 416)      // 512 floats: wp2@ww1 [64][8]
#define O_BW1E  (O_W2W1 + 512)     // 8 floats: bw1 + bp2@ww1
#define O_QW1   (O_BW1E + 8)       // NPTS*8 fp32
#define O_KW1   (O_QW1 + NPTS * 8) // NPTS*8 fp32

typedef __attribute__((ext_vector_type(8))) short short8;
typedef __attribute__((ext_vector_type(4))) short short4v;
typedef __attribute__((ext_vector_type(4))) float f32x4;
#define MFMA16(a, b, c) __builtin_amdgcn_mfma_f32_16x16x32_bf16(a, b, c, 0, 0, 0)

__device__ __forceinline__ int clip_idx(int r) {
    int i = r < 0 ? 0 : r;
    return i >= NPTS ? NPTS - 1 : i;
}
__device__ __forceinline__ unsigned short f2bf(float x) {
    union { float f; unsigned u; } v; v.f = x;
    unsigned r = v.u + 0x7fffu + ((v.u >> 16) & 1u);
    return (unsigned short)(r >> 16);
}
__device__ __forceinline__ float bf2f(unsigned short h) {
    union { unsigned u; float f; } v; v.u = ((unsigned)h) << 16;
    return v.f;
}
// K-slot s -> physical short offset within a row (A-fragment-linear order)
__device__ __forceinline__ int physK(int s) {
    return (s >> 5) * 32 + ((s >> 2) & 3) * 8 + ((s >> 4) & 1) * 4 + (s & 3);
}
// short index into a [64 rows][64 K-slots] A-buffer with 16B-chunk XOR swizzle
__device__ __forceinline__ int aOff(int r, int p) {
    return r * 64 + (((p >> 3) ^ (r & 7)) << 3) + (p & 7);
}
// element i of a B fragment for quarter q: K-in-block index
__device__ __forceinline__ int kib_of(int i, int q) {
    return (i < 4) ? (4 * q + i) : (16 + 4 * q + (i - 4));
}

// ---- prep: zero stats + w2w1 = wp2@ww1 + bw1e = bw1 + bp2@ww1 ----
__global__ __launch_bounds__(512) void k_prep(
    const float* __restrict__ wp2, const float* __restrict__ ww1,
    const float* __restrict__ bw1, const float* __restrict__ bp2,
    float* __restrict__ stat, float* __restrict__ w2w1, float* __restrict__ bw1e)
{
    int t = threadIdx.x;
    if (t < 416) stat[t] = 0.f;
    int j = t >> 3, g = t & 7;
    float acc = 0.f;
    #pragma unroll 16
    for (int c = 0; c < 64; ++c) acc = fmaf(wp2[j * 64 + c], ww1[c * 8 + g], acc);
    w2w1[t] = acc;
    if (t < 8) {
        float b = bw1[t];
        #pragma unroll 16
        for (int c = 0; c < 64; ++c) b = fmaf(bp2[c], ww1[c * 8 + t], b);
        bw1e[t] = b;
    }
}

// ---- Q/K/V projection via MFMA + Q/K BN stats; pmom fused as extra blocks ----
// V gets bp2 folded in (einsum adds V+PEB+bp2; bp2 is per-channel constant).
#define QKV_BLOCKS 512
__global__ __launch_bounds__(256) void k_qkv(
    const float* __restrict__ feat,
    const float* __restrict__ wq, const float* __restrict__ bq,
    const float* __restrict__ wk, const float* __restrict__ bk,
    const float* __restrict__ wv, const float* __restrict__ bv,
    const float* __restrict__ bp2,
    const float* __restrict__ coord, const int* __restrict__ ref,
    short* __restrict__ QlinH, short* __restrict__ KlinH, short* __restrict__ VlinH,
    float* __restrict__ stat)
{
    __shared__ short sA[4096];
    __shared__ float s_red[9];
    const int tid = threadIdx.x, lane = tid & 63, w = tid >> 6;
    const int q = lane >> 4, c15 = lane & 15;

    if (blockIdx.x >= QKV_BLOCKS) {
        // ---- pmom body ----
        float m[9];
        #pragma unroll
        for (int i = 0; i < 9; ++i) m[i] = 0.f;
        const int gid = (blockIdx.x - QKV_BLOCKS) * 256 + tid;
        const int stride = 128 * 256;
        for (int row = gid; row < NROW; row += stride) {
            int n = row >> 4;
            int idx = clip_idx(ref[row]);
            float px = coord[idx * 3 + 0] - coord[n * 3 + 0];
            float py = coord[idx * 3 + 1] - coord[n * 3 + 1];
            float pz = coord[idx * 3 + 2] - coord[n * 3 + 2];
            m[0] += px; m[1] += py; m[2] += pz;
            m[3] = fmaf(px, px, m[3]); m[4] = fmaf(py, py, m[4]); m[5] = fmaf(pz, pz, m[5]);
            m[6] = fmaf(px, py, m[6]); m[7] = fmaf(px, pz, m[7]); m[8] = fmaf(py, pz, m[8]);
        }
        if (tid < 9) s_red[tid] = 0.f;
        __syncthreads();
        #pragma unroll
        for (int off = 32; off >= 1; off >>= 1) {
            #pragma unroll
            for (int i = 0; i < 9; ++i) m[i] += __shfl_xor(m[i], off, 64);
        }
        if (lane == 0) {
            #pragma unroll
            for (int i = 0; i < 9; ++i) atomicAdd(&s_red[i], m[i]);
        }
        __syncthreads();
        if (tid < 9) atomicAdd(&stat[256 + tid], s_red[tid]);
        return;
    }

    // B fragments + bias: wave w owns global col-tiles 3w..3w+2 of [wq|wk|wv]
    short8 bfrag[3][2];
    float bias[3];
    #pragma unroll
    for (int t = 0; t < 3; ++t) {
        int gt = w * 3 + t;
        const float* W = (gt < 4) ? wq : (gt < 8) ? wk : wv;
        const float* B = (gt < 4) ? bq : (gt < 8) ? bk : bv;
        int col = (gt * 16 + c15) & 63;
        bias[t] = B[col] + (gt >= 8 ? bp2[col] : 0.f);
        #pragma unroll
        for (int kt = 0; kt < 2; ++kt) {
            short8 bb;
            #pragma unroll
            for (int i = 0; i < 8; ++i) {
                int kk = kt * 32 + kib_of(i, q);
                bb[i] = (short)f2bf(W[kk * 64 + col]);
            }
            bfrag[t][kt] = bb;
        }
    }
    float st_s[3], st_q[3];
    #pragma unroll
    for (int t = 0; t < 3; ++t) { st_s[t] = 0.f; st_q[t] = 0.f; }

    const int c4 = c15 * 4;              // 4-channel group
    const int pk4 = physK(c4);           // contiguous 4 slots

    for (int b = blockIdx.x; b < NPB; b += QKV_BLOCKS) {
        const int pbase = b * 64;
        // staging: float4 loads, 4 rows per instr
        #pragma unroll
        for (int i = 0; i < 4; ++i) {
            int p = w * 16 + i * 4 + q;
            int n = pbase + p;
            float4 v = make_float4(0.f, 0.f, 0.f, 0.f);
            if (n < NPTS) v = *(const float4*)(feat + n * 64 + c4);
            short4v h;
            h[0] = (short)f2bf(v.x); h[1] = (short)f2bf(v.y);
            h[2] = (short)f2bf(v.z); h[3] = (short)f2bf(v.w);
            *(short4v*)(sA + aOff(p, pk4)) = h;
        }
        __syncthreads();
        #pragma unroll
        for (int mt = 0; mt < 4; ++mt) {
            int r = mt * 16 + c15;
            int ch0 = q ^ (r & 7);
            int ch1 = (4 + q) ^ (r & 7);
            short8 a0 = *(const short8*)(sA + r * 64 + (ch0 << 3));
            short8 a1 = *(const short8*)(sA + r * 64 + (ch1 << 3));
            #pragma unroll
            for (int t = 0; t < 3; ++t) {
                f32x4 acc = (f32x4){0.f, 0.f, 0.f, 0.f};
                acc = MFMA16(a0, bfrag[t][0], acc);
                acc = MFMA16(a1, bfrag[t][1], acc);
                int gt = w * 3 + t;
                #pragma unroll
                for (int rg = 0; rg < 4; ++rg) {
                    int row = mt * 16 + 4 * q + rg;
                    int n = pbase + row;
                    if (n < NPTS) {
                        unsigned short h = f2bf(acc[rg] + bias[t]);
                        float vr = bf2f(h);
                        if (gt < 4)      QlinH[n * 64 + gt * 16 + c15] = (short)h;
                        else if (gt < 8) KlinH[n * 64 + (gt - 4) * 16 + c15] = (short)h;
                        else             VlinH[n * 64 + (gt - 8) * 16 + c15] = (short)h;
                        if (gt < 8) { st_s[t] += vr; st_q[t] = fmaf(vr, vr, st_q[t]); }
                    }
                }
            }
        }
        __syncthreads();
    }
    #pragma unroll
    for (int t = 0; t < 3; ++t) {
        st_s[t] += __shfl_xor(st_s[t], 16, 64); st_s[t] += __shfl_xor(st_s[t], 32, 64);
        st_q[t] += __shfl_xor(st_q[t], 16, 64); st_q[t] += __shfl_xor(st_q[t], 32, 64);
    }
    if (q == 0) {
        #pragma unroll
        for (int t = 0; t < 3; ++t) {
            int gt = w * 3 + t;
            if (gt < 4) {
                atomicAdd(&stat[gt * 16 + c15], st_s[t]);
                atomicAdd(&stat[64 + gt * 16 + c15], st_q[t]);
            } else if (gt < 8) {
                atomicAdd(&stat[128 + (gt - 4) * 16 + c15], st_s[t]);
                atomicAdd(&stat[192 + (gt - 4) * 16 + c15], st_q[t]);
            }
        }
    }
}

// ---- finalize q/k/p BN affines ----
__global__ __launch_bounds__(192) void k_finA(
    const float* __restrict__ gq, const float* __restrict__ betaq,
    const float* __restrict__ gk, const float* __restrict__ betak,
    const float* __restrict__ gp, const float* __restrict__ betap,
    const float* __restrict__ wp1, const float* __restrict__ bp1,
    const float* __restrict__ stat, float* __restrict__ aff)
{
    int t = threadIdx.x;
    if (t < 64) {
        float m = stat[t] / (float)NPTS;
        float v = stat[64 + t] / (float)NPTS - m * m;
        float a = gq[t] * rsqrtf(v + BN_EPS);
        aff[t] = a;
        aff[64 + t] = betaq[t] - m * a;
    } else if (t < 128) {
        int c = t - 64;
        float m = stat[128 + c] / (float)NPTS;
        float v = stat[192 + c] / (float)NPTS - m * m;
        float a = gk[c] * rsqrtf(v + BN_EPS);
        aff[128 + c] = a;
        aff[192 + c] = betak[c] - m * a;
    } else {
        int c = t - 128;
        const float R = (float)NROW;
        float Ex = stat[256] / R, Ey = stat[257] / R, Ez = stat[258] / R;
        float Exx = stat[259] / R, Eyy = stat[260] / R, Ezz = stat[261] / R;
        float Exy = stat[262] / R, Exz = stat[263] / R, Eyz = stat[264] / R;
        float Cxx = Exx - Ex * Ex, Cyy = Eyy - Ey * Ey, Czz = Ezz - Ez * Ez;
        float Cxy = Exy - Ex * Ey, Cxz = Exz - Ex * Ez, Cyz = Eyz - Ey * Ez;
        float a0 = wp1[c], a1 = wp1[64 + c], a2 = wp1[128 + c];
        float mean = a0 * Ex + a1 * Ey + a2 * Ez + bp1[c];
        float var = a0 * a0 * Cxx + a1 * a1 * Cyy + a2 * a2 * Czz
                  + 2.f * (a0 * a1 * Cxy + a0 * a2 * Cxz + a1 * a2 * Cyz);
        float a = gp[c] * rsqrtf(var + BN_EPS);
        aff[256 + c] = a;
        aff[320 + c] = betap[c] - mean * a;
    }
}

// ---- per-point QW1/KW1 = relu_bn(Q/K) @ ww1 via MFMA ----
__global__ __launch_bounds__(128) void k_qkw(
    const short* __restrict__ QlinH, const short* __restrict__ KlinH,
    const float* __restrict__ ww1, const float* __restrict__ aff,
    float* __restrict__ QW1, float* __restrict__ KW1)
{
    __shared__ short sA[2][8192];
    const int tid = threadIdx.x, lane = tid & 63, w = tid >> 6;
    const int q = lane >> 4, g = lane & 15;
    short8 bimg[2];
    #pragma unroll
    for (int kt = 0; kt < 2; ++kt) {
        short8 bb;
        #pragma unroll
        for (int i = 0; i < 8; ++i) {
            int s = kt * 32 + kib_of(i, q);
            bb[i] = (short)f2bf(g < 8 ? ww1[s * 8 + g] : 0.f);
        }
        bimg[kt] = bb;
    }
    // staging coeffs: lane handles 8 channels c8..c8+7 of 8 rows
    const int r8 = lane >> 3, c8 = (lane & 7) * 8;
    f32x4 qa0 = *(const f32x4*)(aff + c8),       qa1 = *(const f32x4*)(aff + c8 + 4);
    f32x4 qb0 = *(const f32x4*)(aff + 64 + c8),  qb1 = *(const f32x4*)(aff + 64 + c8 + 4);
    f32x4 ka0 = *(const f32x4*)(aff + 128 + c8), ka1 = *(const f32x4*)(aff + 128 + c8 + 4);
    f32x4 kb0 = *(const f32x4*)(aff + 192 + c8), kb1 = *(const f32x4*)(aff + 192 + c8 + 4);
    const int pkA = physK(c8), pkB = physK(c8 + 4);
    short* AQ = sA[w];
    short* AK = sA[w] + 4096;

    for (int b = blockIdx.x * 2 + w; b < NPB; b += gridDim.x * 2) {
        const int pbase = b * 64;
        #pragma unroll
        for (int it = 0; it < 8; ++it) {
            int p = it * 8 + r8;
            int n = pbase + p;
            short8 qraw = {0,0,0,0,0,0,0,0}, kraw = {0,0,0,0,0,0,0,0};
            if (n < NPTS) {
                qraw = *(const short8*)(QlinH + n * 64 + c8);
                kraw = *(const short8*)(KlinH + n * 64 + c8);
            }
            short4v qlo, qhi, klo, khi;
            #pragma unroll
            for (int e = 0; e < 4; ++e) {
                qlo[e] = (short)f2bf(fmaxf(fmaf(bf2f((unsigned short)qraw[e]), qa0[e], qb0[e]), 0.f));
                qhi[e] = (short)f2bf(fmaxf(fmaf(bf2f((unsigned short)qraw[e + 4]), qa1[e], qb1[e]), 0.f));
                klo[e] = (short)f2bf(fmaxf(fmaf(bf2f((unsigned short)kraw[e]), ka0[e], kb0[e]), 0.f));
                khi[e] = (short)f2bf(fmaxf(fmaf(bf2f((unsigned short)kraw[e + 4]), ka1[e], kb1[e]), 0.f));
            }
            *(short4v*)(AQ + aOff(p, pkA)) = qlo;
            *(short4v*)(AQ + aOff(p, pkB)) = qhi;
            *(short4v*)(AK + aOff(p, pkA)) = klo;
            *(short4v*)(AK + aOff(p, pkB)) = khi;
        }
        #pragma unroll
        for (int mt = 0; mt < 4; ++mt) {
            f32x4 aq = (f32x4){0.f, 0.f, 0.f, 0.f};
            f32x4 ak = (f32x4){0.f, 0.f, 0.f, 0.f};
            int r = mt * 16 + g;
            #pragma unroll
            for (int kt = 0; kt < 2; ++kt) {
                int chunk = (kt * 4 + q) ^ (r & 7);
                aq = MFMA16(*(const short8*)(AQ + r * 64 + (chunk << 3)), bimg[kt], aq);
                ak = MFMA16(*(const short8*)(AK + r * 64 + (chunk << 3)), bimg[kt], ak);
            }
            if (g < 8) {
                #pragma unroll
                for (int rg = 0; rg < 4; ++rg) {
                    int n = pbase + mt * 16 + 4 * q + rg;
                    if (n < NPTS) {
                        QW1[n * 8 + g] = aq[rg];
                        KW1[n * 8 + g] = ak[rg];
                    }
                }
            }
        }
    }
}

// ---- W-branch BN stats: W1 = P1@w2w1 (MFMA) + KW1[idx] - QW1[n] + bw1e ----
__global__ __launch_bounds__(128) void k_wstats(
    const float* __restrict__ coord, const int* __restrict__ ref,
    const float* __restrict__ wp1, const float* __restrict__ bp1,
    const float* __restrict__ bw1e, const float* __restrict__ w2w1,
    const float* __restrict__ QW1, const float* __restrict__ KW1,
    const float* __restrict__ aff, float* __restrict__ stat)
{
    __shared__ short sP[2][4096];
    __shared__ float sPos[2][256];
    __shared__ int   sIdx[2][64];
    __shared__ float sRed[16];
    const int tid = threadIdx.x, lane = tid & 63, w = tid >> 6;
    const int q = lane >> 4, g = lane & 15, g7 = lane & 7;
    short8 bimg[2];
    #pragma unroll
    for (int kt = 0; kt < 2; ++kt) {
        short8 bb;
        #pragma unroll
        for (int i = 0; i < 8; ++i) {
            int s = kt * 32 + kib_of(i, q);
            bb[i] = (short)f2bf(g < 8 ? w2w1[s * 8 + g] : 0.f);
        }
        bimg[kt] = bb;
    }
    if (tid < 16) sRed[tid] = 0.f;
    __syncthreads();

    const float pa = aff[256 + lane];
    const float A0 = pa * wp1[lane], A1 = pa * wp1[64 + lane], A2 = pa * wp1[128 + lane];
    const float B0 = fmaf(pa, bp1[lane], aff[320 + lane]);
    const float bwg = bw1e[g7];
    const int pk = physK(lane);

    short* P = sP[w];
    float* pos = sPos[w];
    int* idxs = sIdx[w];
    float accS = 0.f, accQ = 0.f;

    for (int b = blockIdx.x * 2 + w; b < NBATCH; b += gridDim.x * 2) {
        const int rbase = b * 64;
        const int p0 = b * 4;
        {
            int r = ref[rbase + lane];
            int idx = clip_idx(r);
            idxs[lane] = idx;
            int n = p0 + (lane >> 4);
            pos[lane * 4 + 0] = coord[idx * 3 + 0] - coord[n * 3 + 0];
            pos[lane * 4 + 1] = coord[idx * 3 + 1] - coord[n * 3 + 1];
            pos[lane * 4 + 2] = coord[idx * 3 + 2] - coord[n * 3 + 2];
        }
        // prefetch KW1/QW1 for this batch (latency hides under staging)
        float kwc[16], qwc[4];
        #pragma unroll
        for (int mt = 0; mt < 4; ++mt) {
            int4 i4 = *(const int4*)(idxs + mt * 16 + 4 * q);
            kwc[mt * 4 + 0] = KW1[i4.x * 8 + g7];
            kwc[mt * 4 + 1] = KW1[i4.y * 8 + g7];
            kwc[mt * 4 + 2] = KW1[i4.z * 8 + g7];
            kwc[mt * 4 + 3] = KW1[i4.w * 8 + g7];
            qwc[mt] = QW1[(p0 + mt) * 8 + g7];
        }
        // stage P1
        #pragma unroll 8
        for (int rr = 0; rr < 64; ++rr) {
            f32x4 pp = *(const f32x4*)(pos + rr * 4);
            float p1v = fmaxf(fmaf(pp.x, A0, fmaf(pp.y, A1, fmaf(pp.z, A2, B0))), 0.f);
            P[aOff(rr, pk)] = (short)f2bf(p1v);
        }
        #pragma unroll
        for (int mt = 0; mt < 4; ++mt) {
            f32x4 acc = (f32x4){0.f, 0.f, 0.f, 0.f};
            int r = mt * 16 + g;
            #pragma unroll
            for (int kt = 0; kt < 2; ++kt) {
                int chunk = (kt * 4 + q) ^ (r & 7);
                acc = MFMA16(*(const short8*)(P + r * 64 + (chunk << 3)), bimg[kt], acc);
            }
            if (g < 8) {
                float dq = bwg - qwc[mt];
                #pragma unroll
                for (int rg = 0; rg < 4; ++rg) {
                    float W = acc[rg] + kwc[mt * 4 + rg] + dq;
                    accS += W;
                    accQ = fmaf(W, W, accQ);
                }
            }
        }
    }
    accS += __shfl_xor(accS, 16, 64); accS += __shfl_xor(accS, 32, 64);
    accQ += __shfl_xor(accQ, 16, 64); accQ += __shfl_xor(accQ, 32, 64);
    if (lane < 8) {
        atomicAdd(&sRed[lane], accS);
        atomicAdd(&sRed[8 + lane], accQ);
    }
    __syncthreads();
    if (tid < 16) atomicAdd(&stat[384 + tid], sRed[tid]);
}

__global__ __launch_bounds__(64) void k_finB(
    const float* __restrict__ gw_, const float* __restrict__ betaw,
    const float* __restrict__ stat, float* __restrict__ aff)
{
    int t = threadIdx.x;
    if (t < 8) {
        const float M = (float)NROW;
        float m = stat[384 + t] / M;
        float v = stat[392 + t] / M - m * m;
        float a = gw_[t] * rsqrtf(v + BN_EPS);
        aff[384 + t] = a;
        aff[392 + t] = betaw[t] - m * a;
    }
}

// ---- final: W1 -> bn/relu -> w2 -> softmax; PEB GEMM fused with einsum ----
__global__ __launch_bounds__(128) void k_final(
    const float* __restrict__ coord, const int* __restrict__ ref,
    const float* __restrict__ wp1, const float* __restrict__ bp1,
    const float* __restrict__ wp2,
    const float* __restrict__ bw1e, const float* __restrict__ w2w1,
    const float* __restrict__ ww2, const float* __restrict__ bw2,
    const float* __restrict__ QW1, const float* __restrict__ KW1,
    const short* __restrict__ VlinH,
    const float* __restrict__ aff, float* __restrict__ out)
{
    __shared__ short sP[2][4096];      // P1 (stays intact)
    __shared__ float sPos[2][256];
    __shared__ int   sIdx[2][64];
    __shared__ float sWn[2][576];
    __shared__ float sW2[72];          // ww2[64] + bw2[8], block-shared
    const int tid = threadIdx.x, lane = tid & 63, w = tid >> 6;
    const int q = lane >> 4, g15 = lane & 15, g7 = lane & 7;

    if (tid < 64) sW2[tid] = ww2[tid];
    else if (tid < 72) sW2[tid] = bw2[tid - 64];
    __syncthreads();

    short8 bw_img[2];
    #pragma unroll
    for (int kt = 0; kt < 2; ++kt) {
        short8 bb;
        #pragma unroll
        for (int i = 0; i < 8; ++i) {
            int s = kt * 32 + kib_of(i, q);
            bb[i] = (short)f2bf(g15 < 8 ? w2w1[s * 8 + g15] : 0.f);
        }
        bw_img[kt] = bb;
    }
    short8 b1[8];
    #pragma unroll
    for (int tt = 0; tt < 8; ++tt) {
        int kt = tt & 1, nt = tt >> 1;
        short8 bb;
        #pragma unroll
        for (int i = 0; i < 8; ++i) {
            int kk = kt * 32 + kib_of(i, q);
            bb[i] = (short)f2bf(wp2[kk * 64 + nt * 16 + g15]);
        }
        b1[tt] = bb;
    }

    const float pa = aff[256 + lane];
    const float A0 = pa * wp1[lane], A1 = pa * wp1[64 + lane], A2 = pa * wp1[128 + lane];
    const float B0 = fmaf(pa, bp1[lane], aff[320 + lane]);
    const float bwg = bw1e[g7];
    const float wag = aff[384 + g7], wbg = aff[392 + g7];
    const int pk = physK(lane);

    short* P = sP[w];
    float* pos = sPos[w];
    int* idxs = sIdx[w];
    float* wn = sWn[w];

    for (int b = blockIdx.x * 2 + w; b < NBATCH; b += gridDim.x * 2) {
        const int rbase = b * 64;
        const int p0 = b * 4;
        {
            int r = ref[rbase + lane];
            int idx = clip_idx(r);
            idxs[lane] = idx;
            int n = p0 + (lane >> 4);
            pos[lane * 4 + 0] = coord[idx * 3 + 0] - coord[n * 3 + 0];
            pos[lane * 4 + 1] = coord[idx * 3 + 1] - coord[n * 3 + 1];
            pos[lane * 4 + 2] = coord[idx * 3 + 2] - coord[n * 3 + 2];
            pos[lane * 4 + 3] = (r >= 0) ? 1.f : 0.f;
        }
        // prefetch KW1/QW1 for this batch (latency hides under staging)
        float kwc[16], qwc[4];
        #pragma unroll
        for (int mt = 0; mt < 4; ++mt) {
            int4 i4 = *(const int4*)(idxs + mt * 16 + 4 * q);
            kwc[mt * 4 + 0] = KW1[i4.x * 8 + g7];
            kwc[mt * 4 + 1] = KW1[i4.y * 8 + g7];
            kwc[mt * 4 + 2] = KW1[i4.z * 8 + g7];
            kwc[mt * 4 + 3] = KW1[i4.w * 8 + g7];
            qwc[mt] = QW1[(p0 + mt) * 8 + g7];
        }
        // stage P1
        #pragma unroll 8
        for (int rr = 0; rr < 64; ++rr) {
            f32x4 pp = *(const f32x4*)(pos + rr * 4);
            float p1v = fmaxf(fmaf(pp.x, A0, fmaf(pp.y, A1, fmaf(pp.z, A2, B0))), 0.f);
            P[aOff(rr, pk)] = (short)f2bf(p1v);
        }
        // GEMM2: P1@w2w1 + per-point terms -> bn/relu -> wn
        #pragma unroll
        for (int mt = 0; mt < 4; ++mt) {
            f32x4 acc = (f32x4){0.f, 0.f, 0.f, 0.f};
            int r = mt * 16 + g15;
            #pragma unroll
            for (int kt = 0; kt < 2; ++kt) {
                int chunk = (kt * 4 + q) ^ (r & 7);
                acc = MFMA16(*(const short8*)(P + r * 64 + (chunk << 3)), bw_img[kt], acc);
            }
            if (g15 < 8) {
                float dq = bwg - qwc[mt];
                #pragma unroll
                for (int rg = 0; rg < 4; ++rg) {
                    int row = mt * 16 + 4 * q + rg;
                    float W = acc[rg] + kwc[mt * 4 + rg] + dq;
                    wn[row * 9 + g15] = fmaxf(fmaf(wag, W, wbg), 0.f);
                }
            }
        }
        // lane = row: w2 + grouped masked softmax (no max-sub: BN-bounded logits)
        {
            float h[8];
            #pragma unroll
            for (int gg = 0; gg < 8; ++gg) h[gg] = wn[lane * 9 + gg];
            float mask = pos[lane * 4 + 3];
            #pragma unroll
            for (int o = 0; o < 8; ++o) {
                float acc = sW2[64 + o];
                #pragma unroll
                for (int gg = 0; gg < 8; ++gg) acc = fmaf(h[gg], sW2[gg * 8 + o], acc);
                float e = __expf(acc);
                float s = e;
                s += __shfl_xor(s, 1, 64);
                s += __shfl_xor(s, 2, 64);
                s += __shfl_xor(s, 4, 64);
                s += __shfl_xor(s, 8, 64);
                wn[lane * 9 + o] = e * __builtin_amdgcn_rcpf(s) * mask;
            }
        }
        // GEMM1 (PEB) fused with einsum; V prefetched per-mt into registers
        #pragma unroll
        for (int mt = 0; mt < 4; ++mt) {
            int4 i4 = *(const int4*)(idxs + mt * 16 + 4 * q);
            int ia[4] = {i4.x, i4.y, i4.z, i4.w};
            unsigned short vc[16];
            #pragma unroll
            for (int rg = 0; rg < 4; ++rg) {
                const short* vb = VlinH + ia[rg] * 64 + g15;
                #pragma unroll
                for (int nt = 0; nt < 4; ++nt)
                    vc[rg * 4 + nt] = (unsigned short)vb[nt * 16];
            }
            int r = mt * 16 + g15;
            int c0 = q ^ (r & 7);
            int c1 = (4 + q) ^ (r & 7);
            short8 a0 = *(const short8*)(P + r * 64 + (c0 << 3));
            short8 a1 = *(const short8*)(P + r * 64 + (c1 << 3));
            const int ro0 = (mt * 16 + 4 * q) * 9;
            #pragma unroll
            for (int nt = 0; nt < 4; ++nt) {
                f32x4 acc = (f32x4){0.f, 0.f, 0.f, 0.f};
                acc = MFMA16(a0, b1[nt * 2 + 0], acc);
                acc = MFMA16(a1, b1[nt * 2 + 1], acc);
                int col = nt * 16 + g15;
                int o = nt * 2 + (g15 >> 3);
                float part = 0.f;
                #pragma unroll
                for (int rg = 0; rg < 4; ++rg) {
                    float v = bf2f(vc[rg * 4 + nt]);
                    part = fmaf(v + acc[rg], wn[ro0 + rg * 9 + o], part);
                }
                part += __shfl_xor(part, 16, 64);
                part += __shfl_xor(part, 32, 64);
                if (q == 0) out[(p0 + mt) * 64 + col] = part;
            }
        }
    }
}

extern "C" void kernel_launch(void* const* d_in, const int* in_sizes, int n_in,
                              void* d_out, int out_size, void* d_ws, size_t ws_size,
                              hipStream_t stream)
{
    const float* feat  = (const float*)d_in[0];
    const float* coord = (const float*)d_in[1];
    const int*   ref   = (const int*)d_in[2];
    const float* wq    = (const float*)d_in[3];
    const float* bq    = (const float*)d_in[4];
    const float* gq    = (const float*)d_in[5];
    const float* betaq = (const float*)d_in[6];
    const float* wk    = (const float*)d_in[7];
    const float* bk    = (const float*)d_in[8];
    const float* gk    = (const float*)d_in[9];
    const float* betak = (const float*)d_in[10];
    const float* wv    = (const float*)d_in[11];
    const float* bv    = (const float*)d_in[12];
    const float* wp1   = (const float*)d_in[13];
    const float* bp1   = (const float*)d_in[14];
    const float* gp    = (const float*)d_in[15];
    const float* betap = (const float*)d_in[16];
    const float* wp2   = (const float*)d_in[17];
    const float* bp2   = (const float*)d_in[18];
    const float* ww1   = (const float*)d_in[19];
    const float* bw1   = (const float*)d_in[20];
    const float* gw_   = (const float*)d_in[21];
    const float* betaw = (const float*)d_in[22];
    const float* ww2   = (const float*)d_in[23];
    const float* bw2   = (const float*)d_in[24];

    float* ws    = (float*)d_ws;
    short* QlinH = (short*)(ws + O_QLINH);
    short* KlinH = (short*)(ws + O_KLINH);
    short* VlinH = (short*)(ws + O_VLINH);
    float* stat  = ws + O_STAT;
    float* aff   = ws + O_AFF;
    float* w2w1  = ws + O_W2W1;
    float* bw1e  = ws + O_BW1E;
    float* QW1   = ws + O_QW1;
    float* KW1   = ws + O_KW1;
    float* out   = (float*)d_out;

    hipLaunchKernelGGL(k_prep, dim3(1), dim3(512), 0, stream,
                       wp2, ww1, bw1, bp2, stat, w2w1, bw1e);
    hipLaunchKernelGGL(k_qkv, dim3(QKV_BLOCKS + 128), dim3(256), 0, stream,
                       feat, wq, bq, wk, bk, wv, bv, bp2, coord, ref,
                       QlinH, KlinH, VlinH, stat);
    hipLaunchKernelGGL(k_finA, dim3(1), dim3(192), 0, stream,
                       gq, betaq, gk, betak, gp, betap, wp1, bp1, stat, aff);
    hipLaunchKernelGGL(k_qkw, dim3(782), dim3(128), 0, stream,
                       QlinH, KlinH, ww1, aff, QW1, KW1);
    hipLaunchKernelGGL(k_wstats, dim3(2500), dim3(128), 0, stream,
                       coord, ref, wp1, bp1, bw1e, w2w1, QW1, KW1, aff, stat);
    hipLaunchKernelGGL(k_finB, dim3(1), dim3(64), 0, stream, gw_, betaw, stat, aff);
    hipLaunchKernelGGL(k_final, dim3(2500), dim3(128), 0, stream,
                       coord, ref, wp1, bp1, wp2, bw1e, w2w1, ww2, bw2,
                       QW1, KW1, VlinH, aff, out);
}

// Round 8
// 220.717 us; speedup vs baseline: 18.5766x; 1.1945x over previous
//
#include <hip/hip_runtime.h>
#include <hip/hip_bf16.h>

#define NPTS 100000
#define KNBR 16
#define CCH  64
#define GRP  8
#define BN_EPS 1e-5f
#define NROW (NPTS * KNBR)        // 1,600,000
#define NBATCH (NROW / 64)        // 25,000 batches of 64 rows (4 points)
#define NPB   ((NPTS + 63) / 64)  // 1563 point-batches

// ---- workspace layout (float offsets) ----
#define O_QLINH 0                  // NPTS*64 bf16 = NPTS*32 floats
#define O_KLINH (NPTS * 32)
#define O_VLINH (NPTS * 64)
#define O_STAT  (NPTS * 96)        // 416 floats of stats
#define O_AFF   (O_STAT + 416)     // 416 floats of affines
#define O_W2W1  (O_AFF + 416)      // 512 floats: wp2@ww1 [64][8]
#define O_BW1E  (O_W2W1 + 512)     // 8 floats: bw1 + bp2@ww1
#define O_QW1   (O_BW1E + 8)       // NPTS*8 fp32
#define O_KW1   (O_QW1 + NPTS * 8) // NPTS*8 fp32

typedef __attribute__((ext_vector_type(8))) short short8;
typedef __attribute__((ext_vector_type(4))) short short4v;
typedef __attribute__((ext_vector_type(4))) float f32x4;
#define MFMA16(a, b, c) __builtin_amdgcn_mfma_f32_16x16x32_bf16(a, b, c, 0, 0, 0)

__device__ __forceinline__ int clip_idx(int r) {
    int i = r < 0 ? 0 : r;
    return i >= NPTS ? NPTS - 1 : i;
}
__device__ __forceinline__ unsigned short f2bf(float x) {
    union { float f; unsigned u; } v; v.f = x;
    unsigned r = v.u + 0x7fffu + ((v.u >> 16) & 1u);
    return (unsigned short)(r >> 16);
}
__device__ __forceinline__ float bf2f(unsigned short h) {
    union { unsigned u; float f; } v; v.u = ((unsigned)h) << 16;
    return v.f;
}
// packed f32x2 -> bf16x2 (single HW instruction; no builtin on gfx950)
__device__ __forceinline__ unsigned pk_bf16(float lo, float hi) {
    unsigned r;
    asm("v_cvt_pk_bf16_f32 %0, %1, %2" : "=v"(r) : "v"(lo), "v"(hi));
    return r;
}
// K-slot s -> physical short offset within a row (A-fragment-linear order)
__device__ __forceinline__ int physK(int s) {
    return (s >> 5) * 32 + ((s >> 2) & 3) * 8 + ((s >> 4) & 1) * 4 + (s & 3);
}
// short index into a [64 rows][64 K-slots] A-buffer with 16B-chunk XOR swizzle
__device__ __forceinline__ int aOff(int r, int p) {
    return r * 64 + (((p >> 3) ^ (r & 7)) << 3) + (p & 7);
}
// element i of a B fragment for quarter q: K-in-block index
__device__ __forceinline__ int kib_of(int i, int q) {
    return (i < 4) ? (4 * q + i) : (16 + 4 * q + (i - 4));
}

// ---- prep: zero stats + w2w1 = wp2@ww1 + bw1e = bw1 + bp2@ww1 ----
__global__ __launch_bounds__(512) void k_prep(
    const float* __restrict__ wp2, const float* __restrict__ ww1,
    const float* __restrict__ bw1, const float* __restrict__ bp2,
    float* __restrict__ stat, float* __restrict__ w2w1, float* __restrict__ bw1e)
{
    int t = threadIdx.x;
    if (t < 416) stat[t] = 0.f;
    int j = t >> 3, g = t & 7;
    float acc = 0.f;
    #pragma unroll 16
    for (int c = 0; c < 64; ++c) acc = fmaf(wp2[j * 64 + c], ww1[c * 8 + g], acc);
    w2w1[t] = acc;
    if (t < 8) {
        float b = bw1[t];
        #pragma unroll 16
        for (int c = 0; c < 64; ++c) b = fmaf(bp2[c], ww1[c * 8 + t], b);
        bw1e[t] = b;
    }
}

// ---- Q/K/V projection via MFMA + Q/K BN stats; pmom fused as extra blocks ----
// V gets bp2 folded in (einsum adds V+PEB+bp2; bp2 is per-channel constant).
#define QKV_BLOCKS 512
__global__ __launch_bounds__(256) void k_qkv(
    const float* __restrict__ feat,
    const float* __restrict__ wq, const float* __restrict__ bq,
    const float* __restrict__ wk, const float* __restrict__ bk,
    const float* __restrict__ wv, const float* __restrict__ bv,
    const float* __restrict__ bp2,
    const float* __restrict__ coord, const int* __restrict__ ref,
    short* __restrict__ QlinH, short* __restrict__ KlinH, short* __restrict__ VlinH,
    float* __restrict__ stat)
{
    __shared__ short sA[4096];
    __shared__ float s_red[9];
    const int tid = threadIdx.x, lane = tid & 63, w = tid >> 6;
    const int q = lane >> 4, c15 = lane & 15;

    if (blockIdx.x >= QKV_BLOCKS) {
        // ---- pmom body ----
        float m[9];
        #pragma unroll
        for (int i = 0; i < 9; ++i) m[i] = 0.f;
        const int gid = (blockIdx.x - QKV_BLOCKS) * 256 + tid;
        const int stride = 128 * 256;
        for (int row = gid; row < NROW; row += stride) {
            int n = row >> 4;
            int idx = clip_idx(ref[row]);
            float px = coord[idx * 3 + 0] - coord[n * 3 + 0];
            float py = coord[idx * 3 + 1] - coord[n * 3 + 1];
            float pz = coord[idx * 3 + 2] - coord[n * 3 + 2];
            m[0] += px; m[1] += py; m[2] += pz;
            m[3] = fmaf(px, px, m[3]); m[4] = fmaf(py, py, m[4]); m[5] = fmaf(pz, pz, m[5]);
            m[6] = fmaf(px, py, m[6]); m[7] = fmaf(px, pz, m[7]); m[8] = fmaf(py, pz, m[8]);
        }
        if (tid < 9) s_red[tid] = 0.f;
        __syncthreads();
        #pragma unroll
        for (int off = 32; off >= 1; off >>= 1) {
            #pragma unroll
            for (int i = 0; i < 9; ++i) m[i] += __shfl_xor(m[i], off, 64);
        }
        if (lane == 0) {
            #pragma unroll
            for (int i = 0; i < 9; ++i) atomicAdd(&s_red[i], m[i]);
        }
        __syncthreads();
        if (tid < 9) atomicAdd(&stat[256 + tid], s_red[tid]);
        return;
    }

    // B fragments + bias: wave w owns global col-tiles 3w..3w+2 of [wq|wk|wv]
    short8 bfrag[3][2];
    float bias[3];
    #pragma unroll
    for (int t = 0; t < 3; ++t) {
        int gt = w * 3 + t;
        const float* W = (gt < 4) ? wq : (gt < 8) ? wk : wv;
        const float* B = (gt < 4) ? bq : (gt < 8) ? bk : bv;
        int col = (gt * 16 + c15) & 63;
        bias[t] = B[col] + (gt >= 8 ? bp2[col] : 0.f);
        #pragma unroll
        for (int kt = 0; kt < 2; ++kt) {
            short8 bb;
            #pragma unroll
            for (int i = 0; i < 8; ++i) {
                int kk = kt * 32 + kib_of(i, q);
                bb[i] = (short)f2bf(W[kk * 64 + col]);
            }
            bfrag[t][kt] = bb;
        }
    }
    float st_s[3], st_q[3];
    #pragma unroll
    for (int t = 0; t < 3; ++t) { st_s[t] = 0.f; st_q[t] = 0.f; }

    const int c4 = c15 * 4;              // 4-channel group
    const int pk4 = physK(c4);           // contiguous 4 slots

    for (int b = blockIdx.x; b < NPB; b += QKV_BLOCKS) {
        const int pbase = b * 64;
        // staging: float4 loads, 4 rows per instr
        #pragma unroll
        for (int i = 0; i < 4; ++i) {
            int p = w * 16 + i * 4 + q;
            int n = pbase + p;
            float4 v = make_float4(0.f, 0.f, 0.f, 0.f);
            if (n < NPTS) v = *(const float4*)(feat + n * 64 + c4);
            short4v h;
            h[0] = (short)f2bf(v.x); h[1] = (short)f2bf(v.y);
            h[2] = (short)f2bf(v.z); h[3] = (short)f2bf(v.w);
            *(short4v*)(sA + aOff(p, pk4)) = h;
        }
        __syncthreads();
        #pragma unroll
        for (int mt = 0; mt < 4; ++mt) {
            int r = mt * 16 + c15;
            int ch0 = q ^ (r & 7);
            int ch1 = (4 + q) ^ (r & 7);
            short8 a0 = *(const short8*)(sA + r * 64 + (ch0 << 3));
            short8 a1 = *(const short8*)(sA + r * 64 + (ch1 << 3));
            #pragma unroll
            for (int t = 0; t < 3; ++t) {
                f32x4 acc = (f32x4){0.f, 0.f, 0.f, 0.f};
                acc = MFMA16(a0, bfrag[t][0], acc);
                acc = MFMA16(a1, bfrag[t][1], acc);
                int gt = w * 3 + t;
                #pragma unroll
                for (int rg = 0; rg < 4; ++rg) {
                    int row = mt * 16 + 4 * q + rg;
                    int n = pbase + row;
                    if (n < NPTS) {
                        unsigned short h = f2bf(acc[rg] + bias[t]);
                        float vr = bf2f(h);
                        if (gt < 4)      QlinH[n * 64 + gt * 16 + c15] = (short)h;
                        else if (gt < 8) KlinH[n * 64 + (gt - 4) * 16 + c15] = (short)h;
                        else             VlinH[n * 64 + (gt - 8) * 16 + c15] = (short)h;
                        if (gt < 8) { st_s[t] += vr; st_q[t] = fmaf(vr, vr, st_q[t]); }
                    }
                }
            }
        }
        __syncthreads();
    }
    #pragma unroll
    for (int t = 0; t < 3; ++t) {
        st_s[t] += __shfl_xor(st_s[t], 16, 64); st_s[t] += __shfl_xor(st_s[t], 32, 64);
        st_q[t] += __shfl_xor(st_q[t], 16, 64); st_q[t] += __shfl_xor(st_q[t], 32, 64);
    }
    if (q == 0) {
        #pragma unroll
        for (int t = 0; t < 3; ++t) {
            int gt = w * 3 + t;
            if (gt < 4) {
                atomicAdd(&stat[gt * 16 + c15], st_s[t]);
                atomicAdd(&stat[64 + gt * 16 + c15], st_q[t]);
            } else if (gt < 8) {
                atomicAdd(&stat[128 + (gt - 4) * 16 + c15], st_s[t]);
                atomicAdd(&stat[192 + (gt - 4) * 16 + c15], st_q[t]);
            }
        }
    }
}

// ---- finalize q/k/p BN affines ----
__global__ __launch_bounds__(192) void k_finA(
    const float* __restrict__ gq, const float* __restrict__ betaq,
    const float* __restrict__ gk, const float* __restrict__ betak,
    const float* __restrict__ gp, const float* __restrict__ betap,
    const float* __restrict__ wp1, const float* __restrict__ bp1,
    const float* __restrict__ stat, float* __restrict__ aff)
{
    int t = threadIdx.x;
    if (t < 64) {
        float m = stat[t] / (float)NPTS;
        float v = stat[64 + t] / (float)NPTS - m * m;
        float a = gq[t] * rsqrtf(v + BN_EPS);
        aff[t] = a;
        aff[64 + t] = betaq[t] - m * a;
    } else if (t < 128) {
        int c = t - 64;
        float m = stat[128 + c] / (float)NPTS;
        float v = stat[192 + c] / (float)NPTS - m * m;
        float a = gk[c] * rsqrtf(v + BN_EPS);
        aff[128 + c] = a;
        aff[192 + c] = betak[c] - m * a;
    } else {
        int c = t - 128;
        const float R = (float)NROW;
        float Ex = stat[256] / R, Ey = stat[257] / R, Ez = stat[258] / R;
        float Exx = stat[259] / R, Eyy = stat[260] / R, Ezz = stat[261] / R;
        float Exy = stat[262] / R, Exz = stat[263] / R, Eyz = stat[264] / R;
        float Cxx = Exx - Ex * Ex, Cyy = Eyy - Ey * Ey, Czz = Ezz - Ez * Ez;
        float Cxy = Exy - Ex * Ey, Cxz = Exz - Ex * Ez, Cyz = Eyz - Ey * Ez;
        float a0 = wp1[c], a1 = wp1[64 + c], a2 = wp1[128 + c];
        float mean = a0 * Ex + a1 * Ey + a2 * Ez + bp1[c];
        float var = a0 * a0 * Cxx + a1 * a1 * Cyy + a2 * a2 * Czz
                  + 2.f * (a0 * a1 * Cxy + a0 * a2 * Cxz + a1 * a2 * Cyz);
        float a = gp[c] * rsqrtf(var + BN_EPS);
        aff[256 + c] = a;
        aff[320 + c] = betap[c] - mean * a;
    }
}

// ---- per-point QW1/KW1 = relu_bn(Q/K) @ ww1 via MFMA ----
__global__ __launch_bounds__(128) void k_qkw(
    const short* __restrict__ QlinH, const short* __restrict__ KlinH,
    const float* __restrict__ ww1, const float* __restrict__ aff,
    float* __restrict__ QW1, float* __restrict__ KW1)
{
    __shared__ short sA[2][8192];
    const int tid = threadIdx.x, lane = tid & 63, w = tid >> 6;
    const int q = lane >> 4, g = lane & 15;
    short8 bimg[2];
    #pragma unroll
    for (int kt = 0; kt < 2; ++kt) {
        short8 bb;
        #pragma unroll
        for (int i = 0; i < 8; ++i) {
            int s = kt * 32 + kib_of(i, q);
            bb[i] = (short)f2bf(g < 8 ? ww1[s * 8 + g] : 0.f);
        }
        bimg[kt] = bb;
    }
    // staging coeffs: lane handles 8 channels c8..c8+7 of 8 rows
    const int r8 = lane >> 3, c8 = (lane & 7) * 8;
    f32x4 qa0 = *(const f32x4*)(aff + c8),       qa1 = *(const f32x4*)(aff + c8 + 4);
    f32x4 qb0 = *(const f32x4*)(aff + 64 + c8),  qb1 = *(const f32x4*)(aff + 64 + c8 + 4);
    f32x4 ka0 = *(const f32x4*)(aff + 128 + c8), ka1 = *(const f32x4*)(aff + 128 + c8 + 4);
    f32x4 kb0 = *(const f32x4*)(aff + 192 + c8), kb1 = *(const f32x4*)(aff + 192 + c8 + 4);
    const int pkA = physK(c8), pkB = physK(c8 + 4);
    short* AQ = sA[w];
    short* AK = sA[w] + 4096;

    for (int b = blockIdx.x * 2 + w; b < NPB; b += gridDim.x * 2) {
        const int pbase = b * 64;
        #pragma unroll
        for (int it = 0; it < 8; ++it) {
            int p = it * 8 + r8;
            int n = pbase + p;
            short8 qraw = {0,0,0,0,0,0,0,0}, kraw = {0,0,0,0,0,0,0,0};
            if (n < NPTS) {
                qraw = *(const short8*)(QlinH + n * 64 + c8);
                kraw = *(const short8*)(KlinH + n * 64 + c8);
            }
            float qf[8], kf[8];
            #pragma unroll
            for (int e = 0; e < 4; ++e) {
                qf[e]     = fmaxf(fmaf(bf2f((unsigned short)qraw[e]), qa0[e], qb0[e]), 0.f);
                qf[e + 4] = fmaxf(fmaf(bf2f((unsigned short)qraw[e + 4]), qa1[e], qb1[e]), 0.f);
                kf[e]     = fmaxf(fmaf(bf2f((unsigned short)kraw[e]), ka0[e], kb0[e]), 0.f);
                kf[e + 4] = fmaxf(fmaf(bf2f((unsigned short)kraw[e + 4]), ka1[e], kb1[e]), 0.f);
            }
            uint2 qv0 = make_uint2(pk_bf16(qf[0], qf[1]), pk_bf16(qf[2], qf[3]));
            uint2 qv1 = make_uint2(pk_bf16(qf[4], qf[5]), pk_bf16(qf[6], qf[7]));
            uint2 kv0 = make_uint2(pk_bf16(kf[0], kf[1]), pk_bf16(kf[2], kf[3]));
            uint2 kv1 = make_uint2(pk_bf16(kf[4], kf[5]), pk_bf16(kf[6], kf[7]));
            *(uint2*)(AQ + aOff(p, pkA)) = qv0;
            *(uint2*)(AQ + aOff(p, pkB)) = qv1;
            *(uint2*)(AK + aOff(p, pkA)) = kv0;
            *(uint2*)(AK + aOff(p, pkB)) = kv1;
        }
        #pragma unroll
        for (int mt = 0; mt < 4; ++mt) {
            f32x4 aq = (f32x4){0.f, 0.f, 0.f, 0.f};
            f32x4 ak = (f32x4){0.f, 0.f, 0.f, 0.f};
            int r = mt * 16 + g;
            #pragma unroll
            for (int kt = 0; kt < 2; ++kt) {
                int chunk = (kt * 4 + q) ^ (r & 7);
                aq = MFMA16(*(const short8*)(AQ + r * 64 + (chunk << 3)), bimg[kt], aq);
                ak = MFMA16(*(const short8*)(AK + r * 64 + (chunk << 3)), bimg[kt], ak);
            }
            if (g < 8) {
                #pragma unroll
                for (int rg = 0; rg < 4; ++rg) {
                    int n = pbase + mt * 16 + 4 * q + rg;
                    if (n < NPTS) {
                        QW1[n * 8 + g] = aq[rg];
                        KW1[n * 8 + g] = ak[rg];
                    }
                }
            }
        }
    }
}

// ---- W-branch BN stats: W1 = P1@w2w1 (MFMA) + KW1[idx] - QW1[n] + bw1e ----
__global__ __launch_bounds__(128) void k_wstats(
    const float* __restrict__ coord, const int* __restrict__ ref,
    const float* __restrict__ wp1, const float* __restrict__ bp1,
    const float* __restrict__ bw1e, const float* __restrict__ w2w1,
    const float* __restrict__ QW1, const float* __restrict__ KW1,
    const float* __restrict__ aff, float* __restrict__ stat)
{
    __shared__ short sP[2][4096];
    __shared__ float sPos[2][256];
    __shared__ int   sIdx[2][64];
    __shared__ float sRed[16];
    const int tid = threadIdx.x, lane = tid & 63, w = tid >> 6;
    const int q = lane >> 4, g = lane & 15, g7 = lane & 7;
    short8 bimg[2];
    #pragma unroll
    for (int kt = 0; kt < 2; ++kt) {
        short8 bb;
        #pragma unroll
        for (int i = 0; i < 8; ++i) {
            int s = kt * 32 + kib_of(i, q);
            bb[i] = (short)f2bf(g < 8 ? w2w1[s * 8 + g] : 0.f);
        }
        bimg[kt] = bb;
    }
    if (tid < 16) sRed[tid] = 0.f;
    __syncthreads();

    // P1 pair-staging constants: lane owns channels (c2, c2+1), rows rh5..rh5+31
    const int c2 = (lane & 31) * 2, rh5 = (lane >> 5) * 32;
    const float paL = aff[256 + c2],     paH = aff[256 + c2 + 1];
    const float A0L = paL * wp1[c2],       A0H = paH * wp1[c2 + 1];
    const float A1L = paL * wp1[64 + c2],  A1H = paH * wp1[64 + c2 + 1];
    const float A2L = paL * wp1[128 + c2], A2H = paH * wp1[128 + c2 + 1];
    const float B0L = fmaf(paL, bp1[c2], aff[320 + c2]);
    const float B0H = fmaf(paH, bp1[c2 + 1], aff[320 + c2 + 1]);
    const int pOff = physK(c2);
    const float bwg = bw1e[g7];

    short* P = sP[w];
    float* pos = sPos[w];
    int* idxs = sIdx[w];
    float accS = 0.f, accQ = 0.f;

    for (int b = blockIdx.x * 2 + w; b < NBATCH; b += gridDim.x * 2) {
        const int rbase = b * 64;
        const int p0 = b * 4;
        {
            int r = ref[rbase + lane];
            int idx = clip_idx(r);
            idxs[lane] = idx;
            int n = p0 + (lane >> 4);
            pos[lane * 4 + 0] = coord[idx * 3 + 0] - coord[n * 3 + 0];
            pos[lane * 4 + 1] = coord[idx * 3 + 1] - coord[n * 3 + 1];
            pos[lane * 4 + 2] = coord[idx * 3 + 2] - coord[n * 3 + 2];
        }
        // prefetch KW1/QW1 for this batch (latency hides under staging)
        float kwc[16], qwc[4];
        #pragma unroll
        for (int mt = 0; mt < 4; ++mt) {
            int4 i4 = *(const int4*)(idxs + mt * 16 + 4 * q);
            kwc[mt * 4 + 0] = KW1[i4.x * 8 + g7];
            kwc[mt * 4 + 1] = KW1[i4.y * 8 + g7];
            kwc[mt * 4 + 2] = KW1[i4.z * 8 + g7];
            kwc[mt * 4 + 3] = KW1[i4.w * 8 + g7];
            qwc[mt] = QW1[(p0 + mt) * 8 + g7];
        }
        // stage P1 (channel-pair, packed bf16x2 writes)
        #pragma unroll 8
        for (int rr = 0; rr < 32; ++rr) {
            int row = rh5 + rr;
            f32x4 pp = *(const f32x4*)(pos + row * 4);
            float lo = fmaxf(fmaf(pp.x, A0L, fmaf(pp.y, A1L, fmaf(pp.z, A2L, B0L))), 0.f);
            float hi = fmaxf(fmaf(pp.x, A0H, fmaf(pp.y, A1H, fmaf(pp.z, A2H, B0H))), 0.f);
            *(unsigned*)(P + aOff(row, pOff)) = pk_bf16(lo, hi);
        }
        #pragma unroll
        for (int mt = 0; mt < 4; ++mt) {
            f32x4 acc = (f32x4){0.f, 0.f, 0.f, 0.f};
            int r = mt * 16 + g;
            #pragma unroll
            for (int kt = 0; kt < 2; ++kt) {
                int chunk = (kt * 4 + q) ^ (r & 7);
                acc = MFMA16(*(const short8*)(P + r * 64 + (chunk << 3)), bimg[kt], acc);
            }
            if (g < 8) {
                float dq = bwg - qwc[mt];
                #pragma unroll
                for (int rg = 0; rg < 4; ++rg) {
                    float W = acc[rg] + kwc[mt * 4 + rg] + dq;
                    accS += W;
                    accQ = fmaf(W, W, accQ);
                }
            }
        }
    }
    accS += __shfl_xor(accS, 16, 64); accS += __shfl_xor(accS, 32, 64);
    accQ += __shfl_xor(accQ, 16, 64); accQ += __shfl_xor(accQ, 32, 64);
    if (lane < 8) {
        atomicAdd(&sRed[lane], accS);
        atomicAdd(&sRed[8 + lane], accQ);
    }
    __syncthreads();
    if (tid < 16) atomicAdd(&stat[384 + tid], sRed[tid]);
}

__global__ __launch_bounds__(64) void k_finB(
    const float* __restrict__ gw_, const float* __restrict__ betaw,
    const float* __restrict__ stat, float* __restrict__ aff)
{
    int t = threadIdx.x;
    if (t < 8) {
        const float M = (float)NROW;
        float m = stat[384 + t] / M;
        float v = stat[392 + t] / M - m * m;
        float a = gw_[t] * rsqrtf(v + BN_EPS);
        aff[384 + t] = a;
        aff[392 + t] = betaw[t] - m * a;
    }
}

// ---- final: W1 -> bn/relu -> w2 -> softmax; PEB GEMM fused with einsum ----
__global__ __launch_bounds__(128) void k_final(
    const float* __restrict__ coord, const int* __restrict__ ref,
    const float* __restrict__ wp1, const float* __restrict__ bp1,
    const float* __restrict__ wp2,
    const float* __restrict__ bw1e, const float* __restrict__ w2w1,
    const float* __restrict__ ww2, const float* __restrict__ bw2,
    const float* __restrict__ QW1, const float* __restrict__ KW1,
    const short* __restrict__ VlinH,
    const float* __restrict__ aff, float* __restrict__ out)
{
    __shared__ short sP[2][4096];      // P1 (stays intact)
    __shared__ float sPos[2][256];
    __shared__ int   sIdx[2][64];
    __shared__ float sWn[2][576];
    __shared__ float sW2[72];          // ww2[64] + bw2[8], block-shared
    const int tid = threadIdx.x, lane = tid & 63, w = tid >> 6;
    const int q = lane >> 4, g15 = lane & 15, g7 = lane & 7;

    if (tid < 64) sW2[tid] = ww2[tid];
    else if (tid < 72) sW2[tid] = bw2[tid - 64];
    __syncthreads();

    short8 bw_img[2];
    #pragma unroll
    for (int kt = 0; kt < 2; ++kt) {
        short8 bb;
        #pragma unroll
        for (int i = 0; i < 8; ++i) {
            int s = kt * 32 + kib_of(i, q);
            bb[i] = (short)f2bf(g15 < 8 ? w2w1[s * 8 + g15] : 0.f);
        }
        bw_img[kt] = bb;
    }
    short8 b1[8];
    #pragma unroll
    for (int tt = 0; tt < 8; ++tt) {
        int kt = tt & 1, nt = tt >> 1;
        short8 bb;
        #pragma unroll
        for (int i = 0; i < 8; ++i) {
            int kk = kt * 32 + kib_of(i, q);
            bb[i] = (short)f2bf(wp2[kk * 64 + nt * 16 + g15]);
        }
        b1[tt] = bb;
    }

    // P1 pair-staging constants
    const int c2 = (lane & 31) * 2, rh5 = (lane >> 5) * 32;
    const float paL = aff[256 + c2],     paH = aff[256 + c2 + 1];
    const float A0L = paL * wp1[c2],       A0H = paH * wp1[c2 + 1];
    const float A1L = paL * wp1[64 + c2],  A1H = paH * wp1[64 + c2 + 1];
    const float A2L = paL * wp1[128 + c2], A2H = paH * wp1[128 + c2 + 1];
    const float B0L = fmaf(paL, bp1[c2], aff[320 + c2]);
    const float B0H = fmaf(paH, bp1[c2 + 1], aff[320 + c2 + 1]);
    const int pOff = physK(c2);
    const float bwg = bw1e[g7];
    const float wag = aff[384 + g7], wbg = aff[392 + g7];

    short* P = sP[w];
    float* pos = sPos[w];
    int* idxs = sIdx[w];
    float* wn = sWn[w];

#define LOADV(MT, VC) do {                                              \
        int4 i4_ = *(const int4*)(idxs + (MT) * 16 + 4 * q);            \
        int ia_[4] = {i4_.x, i4_.y, i4_.z, i4_.w};                      \
        _Pragma("unroll")                                               \
        for (int rg = 0; rg < 4; ++rg) {                                \
            const short* vb_ = VlinH + ia_[rg] * 64 + g15;              \
            _Pragma("unroll")                                           \
            for (int nt = 0; nt < 4; ++nt)                              \
                VC[rg * 4 + nt] = (unsigned short)vb_[nt * 16];         \
        }                                                               \
    } while (0)

#define EINSUM_MT(MT, VC) do {                                          \
        int r_ = (MT) * 16 + g15;                                       \
        int c0_ = q ^ (r_ & 7);                                         \
        int c1_ = (4 + q) ^ (r_ & 7);                                   \
        short8 a0_ = *(const short8*)(P + r_ * 64 + (c0_ << 3));        \
        short8 a1_ = *(const short8*)(P + r_ * 64 + (c1_ << 3));        \
        const int ro0_ = ((MT) * 16 + 4 * q) * 9;                       \
        _Pragma("unroll")                                               \
        for (int nt = 0; nt < 4; ++nt) {                                \
            f32x4 acc_ = (f32x4){0.f, 0.f, 0.f, 0.f};                   \
            acc_ = MFMA16(a0_, b1[nt * 2 + 0], acc_);                   \
            acc_ = MFMA16(a1_, b1[nt * 2 + 1], acc_);                   \
            int col_ = nt * 16 + g15;                                   \
            int o_ = nt * 2 + (g15 >> 3);                               \
            float part_ = 0.f;                                          \
            _Pragma("unroll")                                           \
            for (int rg = 0; rg < 4; ++rg) {                            \
                float v_ = bf2f(VC[rg * 4 + nt]);                       \
                part_ = fmaf(v_ + acc_[rg], wn[ro0_ + rg * 9 + o_], part_); \
            }                                                           \
            part_ += __shfl_xor(part_, 16, 64);                         \
            part_ += __shfl_xor(part_, 32, 64);                         \
            if (q == 0) out[(p0 + (MT)) * 64 + col_] = part_;           \
        }                                                               \
    } while (0)

    for (int b = blockIdx.x * 2 + w; b < NBATCH; b += gridDim.x * 2) {
        const int rbase = b * 64;
        const int p0 = b * 4;
        {
            int r = ref[rbase + lane];
            int idx = clip_idx(r);
            idxs[lane] = idx;
            int n = p0 + (lane >> 4);
            pos[lane * 4 + 0] = coord[idx * 3 + 0] - coord[n * 3 + 0];
            pos[lane * 4 + 1] = coord[idx * 3 + 1] - coord[n * 3 + 1];
            pos[lane * 4 + 2] = coord[idx * 3 + 2] - coord[n * 3 + 2];
            pos[lane * 4 + 3] = (r >= 0) ? 1.f : 0.f;
        }
        // prefetch KW1/QW1 (latency hides under P1 staging)
        float kwc[16], qwc[4];
        #pragma unroll
        for (int mt = 0; mt < 4; ++mt) {
            int4 i4 = *(const int4*)(idxs + mt * 16 + 4 * q);
            kwc[mt * 4 + 0] = KW1[i4.x * 8 + g7];
            kwc[mt * 4 + 1] = KW1[i4.y * 8 + g7];
            kwc[mt * 4 + 2] = KW1[i4.z * 8 + g7];
            kwc[mt * 4 + 3] = KW1[i4.w * 8 + g7];
            qwc[mt] = QW1[(p0 + mt) * 8 + g7];
        }
        // issue V gathers for mt 0/1 early (consumed only in einsum)
        unsigned short vcA[16], vcB[16], vcC[16], vcD[16];
        LOADV(0, vcA);
        LOADV(1, vcB);
        // stage P1 (channel-pair, packed bf16x2 writes)
        #pragma unroll 8
        for (int rr = 0; rr < 32; ++rr) {
            int row = rh5 + rr;
            f32x4 pp = *(const f32x4*)(pos + row * 4);
            float lo = fmaxf(fmaf(pp.x, A0L, fmaf(pp.y, A1L, fmaf(pp.z, A2L, B0L))), 0.f);
            float hi = fmaxf(fmaf(pp.x, A0H, fmaf(pp.y, A1H, fmaf(pp.z, A2H, B0H))), 0.f);
            *(unsigned*)(P + aOff(row, pOff)) = pk_bf16(lo, hi);
        }
        // GEMM2: P1@w2w1 + per-point terms -> bn/relu -> wn
        #pragma unroll
        for (int mt = 0; mt < 4; ++mt) {
            f32x4 acc = (f32x4){0.f, 0.f, 0.f, 0.f};
            int r = mt * 16 + g15;
            #pragma unroll
            for (int kt = 0; kt < 2; ++kt) {
                int chunk = (kt * 4 + q) ^ (r & 7);
                acc = MFMA16(*(const short8*)(P + r * 64 + (chunk << 3)), bw_img[kt], acc);
            }
            if (g15 < 8) {
                float dq = bwg - qwc[mt];
                #pragma unroll
                for (int rg = 0; rg < 4; ++rg) {
                    int row = mt * 16 + 4 * q + rg;
                    float W = acc[rg] + kwc[mt * 4 + rg] + dq;
                    wn[row * 9 + g15] = fmaxf(fmaf(wag, W, wbg), 0.f);
                }
            }
        }
        // issue V gathers for mt 2/3 (consumed after softmax)
        LOADV(2, vcC);
        LOADV(3, vcD);
        // lane = row: w2 + grouped masked softmax (no max-sub: BN-bounded logits)
        {
            float h[8];
            #pragma unroll
            for (int gg = 0; gg < 8; ++gg) h[gg] = wn[lane * 9 + gg];
            float mask = pos[lane * 4 + 3];
            #pragma unroll
            for (int o = 0; o < 8; ++o) {
                float acc = sW2[64 + o];
                #pragma unroll
                for (int gg = 0; gg < 8; ++gg) acc = fmaf(h[gg], sW2[gg * 8 + o], acc);
                float e = __expf(acc);
                float s = e;
                s += __shfl_xor(s, 1, 64);
                s += __shfl_xor(s, 2, 64);
                s += __shfl_xor(s, 4, 64);
                s += __shfl_xor(s, 8, 64);
                wn[lane * 9 + o] = e * __builtin_amdgcn_rcpf(s) * mask;
            }
        }
        // GEMM1 (PEB) fused with einsum; V fully in registers
        EINSUM_MT(0, vcA);
        EINSUM_MT(1, vcB);
        EINSUM_MT(2, vcC);
        EINSUM_MT(3, vcD);
    }
#undef LOADV
#undef EINSUM_MT
}

extern "C" void kernel_launch(void* const* d_in, const int* in_sizes, int n_in,
                              void* d_out, int out_size, void* d_ws, size_t ws_size,
                              hipStream_t stream)
{
    const float* feat  = (const float*)d_in[0];
    const float* coord = (const float*)d_in[1];
    const int*   ref   = (const int*)d_in[2];
    const float* wq    = (const float*)d_in[3];
    const float* bq    = (const float*)d_in[4];
    const float* gq    = (const float*)d_in[5];
    const float* betaq = (const float*)d_in[6];
    const float* wk    = (const float*)d_in[7];
    const float* bk    = (const float*)d_in[8];
    const float* gk    = (const float*)d_in[9];
    const float* betak = (const float*)d_in[10];
    const float* wv    = (const float*)d_in[11];
    const float* bv    = (const float*)d_in[12];
    const float* wp1   = (const float*)d_in[13];
    const float* bp1   = (const float*)d_in[14];
    const float* gp    = (const float*)d_in[15];
    const float* betap = (const float*)d_in[16];
    const float* wp2   = (const float*)d_in[17];
    const float* bp2   = (const float*)d_in[18];
    const float* ww1   = (const float*)d_in[19];
    const float* bw1   = (const float*)d_in[20];
    const float* gw_   = (const float*)d_in[21];
    const float* betaw = (const float*)d_in[22];
    const float* ww2   = (const float*)d_in[23];
    const float* bw2   = (const float*)d_in[24];

    float* ws    = (float*)d_ws;
    short* QlinH = (short*)(ws + O_QLINH);
    short* KlinH = (short*)(ws + O_KLINH);
    short* VlinH = (short*)(ws + O_VLINH);
    float* stat  = ws + O_STAT;
    float* aff   = ws + O_AFF;
    float* w2w1  = ws + O_W2W1;
    float* bw1e  = ws + O_BW1E;
    float* QW1   = ws + O_QW1;
    float* KW1   = ws + O_KW1;
    float* out   = (float*)d_out;

    hipLaunchKernelGGL(k_prep, dim3(1), dim3(512), 0, stream,
                       wp2, ww1, bw1, bp2, stat, w2w1, bw1e);
    hipLaunchKernelGGL(k_qkv, dim3(QKV_BLOCKS + 128), dim3(256), 0, stream,
                       feat, wq, bq, wk, bk, wv, bv, bp2, coord, ref,
                       QlinH, KlinH, VlinH, stat);
    hipLaunchKernelGGL(k_finA, dim3(1), dim3(192), 0, stream,
                       gq, betaq, gk, betak, gp, betap, wp1, bp1, stat, aff);
    hipLaunchKernelGGL(k_qkw, dim3(782), dim3(128), 0, stream,
                       QlinH, KlinH, ww1, aff, QW1, KW1);
    hipLaunchKernelGGL(k_wstats, dim3(2500), dim3(128), 0, stream,
                       coord, ref, wp1, bp1, bw1e, w2w1, QW1, KW1, aff, stat);
    hipLaunchKernelGGL(k_finB, dim3(1), dim3(64), 0, stream, gw_, betaw, stat, aff);
    hipLaunchKernelGGL(k_final, dim3(2500), dim3(128), 0, stream,
                       coord, ref, wp1, bp1, wp2, bw1e, w2w1, ww2, bw2,
                       QW1, KW1, VlinH, aff, out);
}

// Round 9
// 215.434 us; speedup vs baseline: 19.0321x; 1.0245x over previous
//
#include <hip/hip_runtime.h>
#include <hip/hip_bf16.h>

#define NPTS 100000
#define KNBR 16
#define CCH  64
#define GRP  8
#define BN_EPS 1e-5f
#define NROW (NPTS * KNBR)        // 1,600,000
#define NBATCH (NROW / 64)        // 25,000 batches of 64 rows (4 points)
#define NPB   ((NPTS + 63) / 64)  // 1563 point-batches

// ---- workspace layout (float offsets) ----
#define O_QLINH 0                  // NPTS*64 bf16 = NPTS*32 floats
#define O_KLINH (NPTS * 32)
#define O_VLINH (NPTS * 64)
#define O_STAT  (NPTS * 96)        // 416 floats of stats
#define O_AFF   (O_STAT + 416)     // 416 floats of affines
#define O_W2W1  (O_AFF + 416)      // 512 floats: wp2@ww1 [64][8]
#define O_BW1E  (O_W2W1 + 512)     // 8 floats: bw1 + bp2@ww1
#define O_QW1   (O_BW1E + 8)       // NPTS*8 fp32
#define O_KW1   (O_QW1 + NPTS * 8) // NPTS*8 fp32
#define O_W1H   (O_KW1 + NPTS * 8) // NROW*8 bf16 = NROW*4 floats (25.6 MB)

typedef __attribute__((ext_vector_type(8))) short short8;
typedef __attribute__((ext_vector_type(4))) short short4v;
typedef __attribute__((ext_vector_type(4))) float f32x4;
#define MFMA16(a, b, c) __builtin_amdgcn_mfma_f32_16x16x32_bf16(a, b, c, 0, 0, 0)

__device__ __forceinline__ int clip_idx(int r) {
    int i = r < 0 ? 0 : r;
    return i >= NPTS ? NPTS - 1 : i;
}
__device__ __forceinline__ unsigned short f2bf(float x) {
    union { float f; unsigned u; } v; v.f = x;
    unsigned r = v.u + 0x7fffu + ((v.u >> 16) & 1u);
    return (unsigned short)(r >> 16);
}
__device__ __forceinline__ float bf2f(unsigned short h) {
    union { unsigned u; float f; } v; v.u = ((unsigned)h) << 16;
    return v.f;
}
// packed f32x2 -> bf16x2 (single HW instruction; no builtin on gfx950)
__device__ __forceinline__ unsigned pk_bf16(float lo, float hi) {
    unsigned r;
    asm("v_cvt_pk_bf16_f32 %0, %1, %2" : "=v"(r) : "v"(lo), "v"(hi));
    return r;
}
// K-slot s -> physical short offset within a row (A-fragment-linear order)
__device__ __forceinline__ int physK(int s) {
    return (s >> 5) * 32 + ((s >> 2) & 3) * 8 + ((s >> 4) & 1) * 4 + (s & 3);
}
// short index into a [64 rows][64 K-slots] A-buffer with 16B-chunk XOR swizzle
__device__ __forceinline__ int aOff(int r, int p) {
    return r * 64 + (((p >> 3) ^ (r & 7)) << 3) + (p & 7);
}
// element i of a B fragment for quarter q: K-in-block index
__device__ __forceinline__ int kib_of(int i, int q) {
    return (i < 4) ? (4 * q + i) : (16 + 4 * q + (i - 4));
}

// ---- prep: zero stats + w2w1 = wp2@ww1 + bw1e = bw1 + bp2@ww1 ----
__global__ __launch_bounds__(512) void k_prep(
    const float* __restrict__ wp2, const float* __restrict__ ww1,
    const float* __restrict__ bw1, const float* __restrict__ bp2,
    float* __restrict__ stat, float* __restrict__ w2w1, float* __restrict__ bw1e)
{
    int t = threadIdx.x;
    if (t < 416) stat[t] = 0.f;
    int j = t >> 3, g = t & 7;
    float acc = 0.f;
    #pragma unroll 16
    for (int c = 0; c < 64; ++c) acc = fmaf(wp2[j * 64 + c], ww1[c * 8 + g], acc);
    w2w1[t] = acc;
    if (t < 8) {
        float b = bw1[t];
        #pragma unroll 16
        for (int c = 0; c < 64; ++c) b = fmaf(bp2[c], ww1[c * 8 + t], b);
        bw1e[t] = b;
    }
}

// ---- Q/K/V projection via MFMA + Q/K BN stats; pmom fused as extra blocks ----
// V gets bp2 folded in (einsum adds V+PEB+bp2; bp2 is per-channel constant).
#define QKV_BLOCKS 512
__global__ __launch_bounds__(256) void k_qkv(
    const float* __restrict__ feat,
    const float* __restrict__ wq, const float* __restrict__ bq,
    const float* __restrict__ wk, const float* __restrict__ bk,
    const float* __restrict__ wv, const float* __restrict__ bv,
    const float* __restrict__ bp2,
    const float* __restrict__ coord, const int* __restrict__ ref,
    short* __restrict__ QlinH, short* __restrict__ KlinH, short* __restrict__ VlinH,
    float* __restrict__ stat)
{
    __shared__ short sA[4096];
    __shared__ float s_red[9];
    const int tid = threadIdx.x, lane = tid & 63, w = tid >> 6;
    const int q = lane >> 4, c15 = lane & 15;

    if (blockIdx.x >= QKV_BLOCKS) {
        // ---- pmom body ----
        float m[9];
        #pragma unroll
        for (int i = 0; i < 9; ++i) m[i] = 0.f;
        const int gid = (blockIdx.x - QKV_BLOCKS) * 256 + tid;
        const int stride = 128 * 256;
        for (int row = gid; row < NROW; row += stride) {
            int n = row >> 4;
            int idx = clip_idx(ref[row]);
            float px = coord[idx * 3 + 0] - coord[n * 3 + 0];
            float py = coord[idx * 3 + 1] - coord[n * 3 + 1];
            float pz = coord[idx * 3 + 2] - coord[n * 3 + 2];
            m[0] += px; m[1] += py; m[2] += pz;
            m[3] = fmaf(px, px, m[3]); m[4] = fmaf(py, py, m[4]); m[5] = fmaf(pz, pz, m[5]);
            m[6] = fmaf(px, py, m[6]); m[7] = fmaf(px, pz, m[7]); m[8] = fmaf(py, pz, m[8]);
        }
        if (tid < 9) s_red[tid] = 0.f;
        __syncthreads();
        #pragma unroll
        for (int off = 32; off >= 1; off >>= 1) {
            #pragma unroll
            for (int i = 0; i < 9; ++i) m[i] += __shfl_xor(m[i], off, 64);
        }
        if (lane == 0) {
            #pragma unroll
            for (int i = 0; i < 9; ++i) atomicAdd(&s_red[i], m[i]);
        }
        __syncthreads();
        if (tid < 9) atomicAdd(&stat[256 + tid], s_red[tid]);
        return;
    }

    // B fragments + bias: wave w owns global col-tiles 3w..3w+2 of [wq|wk|wv]
    short8 bfrag[3][2];
    float bias[3];
    #pragma unroll
    for (int t = 0; t < 3; ++t) {
        int gt = w * 3 + t;
        const float* W = (gt < 4) ? wq : (gt < 8) ? wk : wv;
        const float* B = (gt < 4) ? bq : (gt < 8) ? bk : bv;
        int col = (gt * 16 + c15) & 63;
        bias[t] = B[col] + (gt >= 8 ? bp2[col] : 0.f);
        #pragma unroll
        for (int kt = 0; kt < 2; ++kt) {
            short8 bb;
            #pragma unroll
            for (int i = 0; i < 8; ++i) {
                int kk = kt * 32 + kib_of(i, q);
                bb[i] = (short)f2bf(W[kk * 64 + col]);
            }
            bfrag[t][kt] = bb;
        }
    }
    float st_s[3], st_q[3];
    #pragma unroll
    for (int t = 0; t < 3; ++t) { st_s[t] = 0.f; st_q[t] = 0.f; }

    const int c4 = c15 * 4;              // 4-channel group
    const int pk4 = physK(c4);           // contiguous 4 slots

    for (int b = blockIdx.x; b < NPB; b += QKV_BLOCKS) {
        const int pbase = b * 64;
        // staging: float4 loads, 4 rows per instr
        #pragma unroll
        for (int i = 0; i < 4; ++i) {
            int p = w * 16 + i * 4 + q;
            int n = pbase + p;
            float4 v = make_float4(0.f, 0.f, 0.f, 0.f);
            if (n < NPTS) v = *(const float4*)(feat + n * 64 + c4);
            short4v h;
            h[0] = (short)f2bf(v.x); h[1] = (short)f2bf(v.y);
            h[2] = (short)f2bf(v.z); h[3] = (short)f2bf(v.w);
            *(short4v*)(sA + aOff(p, pk4)) = h;
        }
        __syncthreads();
        #pragma unroll
        for (int mt = 0; mt < 4; ++mt) {
            int r = mt * 16 + c15;
            int ch0 = q ^ (r & 7);
            int ch1 = (4 + q) ^ (r & 7);
            short8 a0 = *(const short8*)(sA + r * 64 + (ch0 << 3));
            short8 a1 = *(const short8*)(sA + r * 64 + (ch1 << 3));
            #pragma unroll
            for (int t = 0; t < 3; ++t) {
                f32x4 acc = (f32x4){0.f, 0.f, 0.f, 0.f};
                acc = MFMA16(a0, bfrag[t][0], acc);
                acc = MFMA16(a1, bfrag[t][1], acc);
                int gt = w * 3 + t;
                #pragma unroll
                for (int rg = 0; rg < 4; ++rg) {
                    int row = mt * 16 + 4 * q + rg;
                    int n = pbase + row;
                    if (n < NPTS) {
                        unsigned short h = f2bf(acc[rg] + bias[t]);
                        float vr = bf2f(h);
                        if (gt < 4)      QlinH[n * 64 + gt * 16 + c15] = (short)h;
                        else if (gt < 8) KlinH[n * 64 + (gt - 4) * 16 + c15] = (short)h;
                        else             VlinH[n * 64 + (gt - 8) * 16 + c15] = (short)h;
                        if (gt < 8) { st_s[t] += vr; st_q[t] = fmaf(vr, vr, st_q[t]); }
                    }
                }
            }
        }
        __syncthreads();
    }
    #pragma unroll
    for (int t = 0; t < 3; ++t) {
        st_s[t] += __shfl_xor(st_s[t], 16, 64); st_s[t] += __shfl_xor(st_s[t], 32, 64);
        st_q[t] += __shfl_xor(st_q[t], 16, 64); st_q[t] += __shfl_xor(st_q[t], 32, 64);
    }
    if (q == 0) {
        #pragma unroll
        for (int t = 0; t < 3; ++t) {
            int gt = w * 3 + t;
            if (gt < 4) {
                atomicAdd(&stat[gt * 16 + c15], st_s[t]);
                atomicAdd(&stat[64 + gt * 16 + c15], st_q[t]);
            } else if (gt < 8) {
                atomicAdd(&stat[128 + (gt - 4) * 16 + c15], st_s[t]);
                atomicAdd(&stat[192 + (gt - 4) * 16 + c15], st_q[t]);
            }
        }
    }
}

// ---- finalize q/k/p BN affines ----
__global__ __launch_bounds__(192) void k_finA(
    const float* __restrict__ gq, const float* __restrict__ betaq,
    const float* __restrict__ gk, const float* __restrict__ betak,
    const float* __restrict__ gp, const float* __restrict__ betap,
    const float* __restrict__ wp1, const float* __restrict__ bp1,
    const float* __restrict__ stat, float* __restrict__ aff)
{
    int t = threadIdx.x;
    if (t < 64) {
        float m = stat[t] / (float)NPTS;
        float v = stat[64 + t] / (float)NPTS - m * m;
        float a = gq[t] * rsqrtf(v + BN_EPS);
        aff[t] = a;
        aff[64 + t] = betaq[t] - m * a;
    } else if (t < 128) {
        int c = t - 64;
        float m = stat[128 + c] / (float)NPTS;
        float v = stat[192 + c] / (float)NPTS - m * m;
        float a = gk[c] * rsqrtf(v + BN_EPS);
        aff[128 + c] = a;
        aff[192 + c] = betak[c] - m * a;
    } else {
        int c = t - 128;
        const float R = (float)NROW;
        float Ex = stat[256] / R, Ey = stat[257] / R, Ez = stat[258] / R;
        float Exx = stat[259] / R, Eyy = stat[260] / R, Ezz = stat[261] / R;
        float Exy = stat[262] / R, Exz = stat[263] / R, Eyz = stat[264] / R;
        float Cxx = Exx - Ex * Ex, Cyy = Eyy - Ey * Ey, Czz = Ezz - Ez * Ez;
        float Cxy = Exy - Ex * Ey, Cxz = Exz - Ex * Ez, Cyz = Eyz - Ey * Ez;
        float a0 = wp1[c], a1 = wp1[64 + c], a2 = wp1[128 + c];
        float mean = a0 * Ex + a1 * Ey + a2 * Ez + bp1[c];
        float var = a0 * a0 * Cxx + a1 * a1 * Cyy + a2 * a2 * Czz
                  + 2.f * (a0 * a1 * Cxy + a0 * a2 * Cxz + a1 * a2 * Cyz);
        float a = gp[c] * rsqrtf(var + BN_EPS);
        aff[256 + c] = a;
        aff[320 + c] = betap[c] - mean * a;
    }
}

// ---- per-point QW1/KW1 = relu_bn(Q/K) @ ww1 via MFMA ----
__global__ __launch_bounds__(128) void k_qkw(
    const short* __restrict__ QlinH, const short* __restrict__ KlinH,
    const float* __restrict__ ww1, const float* __restrict__ aff,
    float* __restrict__ QW1, float* __restrict__ KW1)
{
    __shared__ short sA[2][8192];
    const int tid = threadIdx.x, lane = tid & 63, w = tid >> 6;
    const int q = lane >> 4, g = lane & 15;
    short8 bimg[2];
    #pragma unroll
    for (int kt = 0; kt < 2; ++kt) {
        short8 bb;
        #pragma unroll
        for (int i = 0; i < 8; ++i) {
            int s = kt * 32 + kib_of(i, q);
            bb[i] = (short)f2bf(g < 8 ? ww1[s * 8 + g] : 0.f);
        }
        bimg[kt] = bb;
    }
    // staging coeffs: lane handles 8 channels c8..c8+7 of 8 rows
    const int r8 = lane >> 3, c8 = (lane & 7) * 8;
    f32x4 qa0 = *(const f32x4*)(aff + c8),       qa1 = *(const f32x4*)(aff + c8 + 4);
    f32x4 qb0 = *(const f32x4*)(aff + 64 + c8),  qb1 = *(const f32x4*)(aff + 64 + c8 + 4);
    f32x4 ka0 = *(const f32x4*)(aff + 128 + c8), ka1 = *(const f32x4*)(aff + 128 + c8 + 4);
    f32x4 kb0 = *(const f32x4*)(aff + 192 + c8), kb1 = *(const f32x4*)(aff + 192 + c8 + 4);
    const int pkA = physK(c8), pkB = physK(c8 + 4);
    short* AQ = sA[w];
    short* AK = sA[w] + 4096;

    for (int b = blockIdx.x * 2 + w; b < NPB; b += gridDim.x * 2) {
        const int pbase = b * 64;
        #pragma unroll
        for (int it = 0; it < 8; ++it) {
            int p = it * 8 + r8;
            int n = pbase + p;
            short8 qraw = {0,0,0,0,0,0,0,0}, kraw = {0,0,0,0,0,0,0,0};
            if (n < NPTS) {
                qraw = *(const short8*)(QlinH + n * 64 + c8);
                kraw = *(const short8*)(KlinH + n * 64 + c8);
            }
            float qf[8], kf[8];
            #pragma unroll
            for (int e = 0; e < 4; ++e) {
                qf[e]     = fmaxf(fmaf(bf2f((unsigned short)qraw[e]), qa0[e], qb0[e]), 0.f);
                qf[e + 4] = fmaxf(fmaf(bf2f((unsigned short)qraw[e + 4]), qa1[e], qb1[e]), 0.f);
                kf[e]     = fmaxf(fmaf(bf2f((unsigned short)kraw[e]), ka0[e], kb0[e]), 0.f);
                kf[e + 4] = fmaxf(fmaf(bf2f((unsigned short)kraw[e + 4]), ka1[e], kb1[e]), 0.f);
            }
            uint2 qv0 = make_uint2(pk_bf16(qf[0], qf[1]), pk_bf16(qf[2], qf[3]));
            uint2 qv1 = make_uint2(pk_bf16(qf[4], qf[5]), pk_bf16(qf[6], qf[7]));
            uint2 kv0 = make_uint2(pk_bf16(kf[0], kf[1]), pk_bf16(kf[2], kf[3]));
            uint2 kv1 = make_uint2(pk_bf16(kf[4], kf[5]), pk_bf16(kf[6], kf[7]));
            *(uint2*)(AQ + aOff(p, pkA)) = qv0;
            *(uint2*)(AQ + aOff(p, pkB)) = qv1;
            *(uint2*)(AK + aOff(p, pkA)) = kv0;
            *(uint2*)(AK + aOff(p, pkB)) = kv1;
        }
        #pragma unroll
        for (int mt = 0; mt < 4; ++mt) {
            f32x4 aq = (f32x4){0.f, 0.f, 0.f, 0.f};
            f32x4 ak = (f32x4){0.f, 0.f, 0.f, 0.f};
            int r = mt * 16 + g;
            #pragma unroll
            for (int kt = 0; kt < 2; ++kt) {
                int chunk = (kt * 4 + q) ^ (r & 7);
                aq = MFMA16(*(const short8*)(AQ + r * 64 + (chunk << 3)), bimg[kt], aq);
                ak = MFMA16(*(const short8*)(AK + r * 64 + (chunk << 3)), bimg[kt], ak);
            }
            if (g < 8) {
                #pragma unroll
                for (int rg = 0; rg < 4; ++rg) {
                    int n = pbase + mt * 16 + 4 * q + rg;
                    if (n < NPTS) {
                        QW1[n * 8 + g] = aq[rg];
                        KW1[n * 8 + g] = ak[rg];
                    }
                }
            }
        }
    }
}

// ---- W-branch BN stats + W1 materialization (bf16, stats from rounded) ----
__global__ __launch_bounds__(128) void k_wstats(
    const float* __restrict__ coord, const int* __restrict__ ref,
    const float* __restrict__ wp1, const float* __restrict__ bp1,
    const float* __restrict__ bw1e, const float* __restrict__ w2w1,
    const float* __restrict__ QW1, const float* __restrict__ KW1,
    const float* __restrict__ aff, float* __restrict__ stat,
    short* __restrict__ W1H)
{
    __shared__ short sP[2][4096];
    __shared__ float sPos[2][256];
    __shared__ int   sIdx[2][64];
    __shared__ float sRed[16];
    const int tid = threadIdx.x, lane = tid & 63, w = tid >> 6;
    const int q = lane >> 4, g = lane & 15, g7 = lane & 7;
    short8 bimg[2];
    #pragma unroll
    for (int kt = 0; kt < 2; ++kt) {
        short8 bb;
        #pragma unroll
        for (int i = 0; i < 8; ++i) {
            int s = kt * 32 + kib_of(i, q);
            bb[i] = (short)f2bf(g < 8 ? w2w1[s * 8 + g] : 0.f);
        }
        bimg[kt] = bb;
    }
    if (tid < 16) sRed[tid] = 0.f;
    __syncthreads();

    // P1 pair-staging constants: lane owns channels (c2, c2+1), rows rh5..rh5+31
    const int c2 = (lane & 31) * 2, rh5 = (lane >> 5) * 32;
    const float paL = aff[256 + c2],     paH = aff[256 + c2 + 1];
    const float A0L = paL * wp1[c2],       A0H = paH * wp1[c2 + 1];
    const float A1L = paL * wp1[64 + c2],  A1H = paH * wp1[64 + c2 + 1];
    const float A2L = paL * wp1[128 + c2], A2H = paH * wp1[128 + c2 + 1];
    const float B0L = fmaf(paL, bp1[c2], aff[320 + c2]);
    const float B0H = fmaf(paH, bp1[c2 + 1], aff[320 + c2 + 1]);
    const int pOff = physK(c2);
    const float bwg = bw1e[g7];

    short* P = sP[w];
    float* pos = sPos[w];
    int* idxs = sIdx[w];
    float accS = 0.f, accQ = 0.f;

    for (int b = blockIdx.x * 2 + w; b < NBATCH; b += gridDim.x * 2) {
        const int rbase = b * 64;
        const int p0 = b * 4;
        {
            int r = ref[rbase + lane];
            int idx = clip_idx(r);
            idxs[lane] = idx;
            int n = p0 + (lane >> 4);
            pos[lane * 4 + 0] = coord[idx * 3 + 0] - coord[n * 3 + 0];
            pos[lane * 4 + 1] = coord[idx * 3 + 1] - coord[n * 3 + 1];
            pos[lane * 4 + 2] = coord[idx * 3 + 2] - coord[n * 3 + 2];
        }
        // prefetch KW1/QW1 for this batch (latency hides under staging)
        float kwc[16], qwc[4];
        #pragma unroll
        for (int mt = 0; mt < 4; ++mt) {
            int4 i4 = *(const int4*)(idxs + mt * 16 + 4 * q);
            kwc[mt * 4 + 0] = KW1[i4.x * 8 + g7];
            kwc[mt * 4 + 1] = KW1[i4.y * 8 + g7];
            kwc[mt * 4 + 2] = KW1[i4.z * 8 + g7];
            kwc[mt * 4 + 3] = KW1[i4.w * 8 + g7];
            qwc[mt] = QW1[(p0 + mt) * 8 + g7];
        }
        // stage P1 (channel-pair, packed bf16x2 writes)
        #pragma unroll 8
        for (int rr = 0; rr < 32; ++rr) {
            int row = rh5 + rr;
            f32x4 pp = *(const f32x4*)(pos + row * 4);
            float lo = fmaxf(fmaf(pp.x, A0L, fmaf(pp.y, A1L, fmaf(pp.z, A2L, B0L))), 0.f);
            float hi = fmaxf(fmaf(pp.x, A0H, fmaf(pp.y, A1H, fmaf(pp.z, A2H, B0H))), 0.f);
            *(unsigned*)(P + aOff(row, pOff)) = pk_bf16(lo, hi);
        }
        #pragma unroll
        for (int mt = 0; mt < 4; ++mt) {
            f32x4 acc = (f32x4){0.f, 0.f, 0.f, 0.f};
            int r = mt * 16 + g;
            #pragma unroll
            for (int kt = 0; kt < 2; ++kt) {
                int chunk = (kt * 4 + q) ^ (r & 7);
                acc = MFMA16(*(const short8*)(P + r * 64 + (chunk << 3)), bimg[kt], acc);
            }
            if (g < 8) {
                float dq = bwg - qwc[mt];
                #pragma unroll
                for (int rg = 0; rg < 4; ++rg) {
                    float Wf = acc[rg] + kwc[mt * 4 + rg] + dq;
                    unsigned short wh = f2bf(Wf);
                    float Wr = bf2f(wh);
                    accS += Wr;
                    accQ = fmaf(Wr, Wr, accQ);
                    W1H[(rbase + mt * 16 + 4 * q + rg) * 8 + g7] = (short)wh;
                }
            }
        }
    }
    accS += __shfl_xor(accS, 16, 64); accS += __shfl_xor(accS, 32, 64);
    accQ += __shfl_xor(accQ, 16, 64); accQ += __shfl_xor(accQ, 32, 64);
    if (lane < 8) {
        atomicAdd(&sRed[lane], accS);
        atomicAdd(&sRed[8 + lane], accQ);
    }
    __syncthreads();
    if (tid < 16) atomicAdd(&stat[384 + tid], sRed[tid]);
}

__global__ __launch_bounds__(64) void k_finB(
    const float* __restrict__ gw_, const float* __restrict__ betaw,
    const float* __restrict__ stat, float* __restrict__ aff)
{
    int t = threadIdx.x;
    if (t < 8) {
        const float M = (float)NROW;
        float m = stat[384 + t] / M;
        float v = stat[392 + t] / M - m * m;
        float a = gw_[t] * rsqrtf(v + BN_EPS);
        aff[384 + t] = a;
        aff[392 + t] = betaw[t] - m * a;
    }
}

// ---- final: load W1 -> bn/relu (regs) -> w2 -> softmax; PEB GEMM + einsum ----
__global__ __launch_bounds__(128) void k_final(
    const float* __restrict__ coord, const int* __restrict__ ref,
    const float* __restrict__ wp1, const float* __restrict__ bp1,
    const float* __restrict__ wp2,
    const float* __restrict__ ww2, const float* __restrict__ bw2,
    const short* __restrict__ W1H, const short* __restrict__ VlinH,
    const float* __restrict__ aff, float* __restrict__ out)
{
    __shared__ short sP[2][4096];      // P1 (stays intact)
    __shared__ float sPos[2][256];
    __shared__ int   sIdx[2][64];
    __shared__ float sWn[2][576];
    __shared__ float sW2[72];          // ww2[64] + bw2[8], block-shared
    const int tid = threadIdx.x, lane = tid & 63, w = tid >> 6;
    const int q = lane >> 4, g15 = lane & 15;

    if (tid < 64) sW2[tid] = ww2[tid];
    else if (tid < 72) sW2[tid] = bw2[tid - 64];
    __syncthreads();

    short8 b1[8];
    #pragma unroll
    for (int tt = 0; tt < 8; ++tt) {
        int kt = tt & 1, nt = tt >> 1;
        short8 bb;
        #pragma unroll
        for (int i = 0; i < 8; ++i) {
            int kk = kt * 32 + kib_of(i, q);
            bb[i] = (short)f2bf(wp2[kk * 64 + nt * 16 + g15]);
        }
        b1[tt] = bb;
    }

    // P1 pair-staging constants
    const int c2 = (lane & 31) * 2, rh5 = (lane >> 5) * 32;
    const float paL = aff[256 + c2],     paH = aff[256 + c2 + 1];
    const float A0L = paL * wp1[c2],       A0H = paH * wp1[c2 + 1];
    const float A1L = paL * wp1[64 + c2],  A1H = paH * wp1[64 + c2 + 1];
    const float A2L = paL * wp1[128 + c2], A2H = paH * wp1[128 + c2 + 1];
    const float B0L = fmaf(paL, bp1[c2], aff[320 + c2]);
    const float B0H = fmaf(paH, bp1[c2 + 1], aff[320 + c2 + 1]);
    const int pOff = physK(c2);
    // full W-BN affine vectors (all 8 groups per lane)
    float wa8[8], wb8[8];
    #pragma unroll
    for (int gg = 0; gg < 8; ++gg) {
        wa8[gg] = aff[384 + gg];
        wb8[gg] = aff[392 + gg];
    }

    short* P = sP[w];
    float* pos = sPos[w];
    int* idxs = sIdx[w];
    float* wn = sWn[w];

#define LOADV(MT, VC) do {                                              \
        int4 i4_ = *(const int4*)(idxs + (MT) * 16 + 4 * q);            \
        int ia_[4] = {i4_.x, i4_.y, i4_.z, i4_.w};                      \
        _Pragma("unroll")                                               \
        for (int rg = 0; rg < 4; ++rg) {                                \
            const short* vb_ = VlinH + ia_[rg] * 64 + g15;              \
            _Pragma("unroll")                                           \
            for (int nt = 0; nt < 4; ++nt)                              \
                VC[rg * 4 + nt] = (unsigned short)vb_[nt * 16];         \
        }                                                               \
    } while (0)

#define EINSUM_MT(MT, VC) do {                                          \
        int r_ = (MT) * 16 + g15;                                       \
        int c0_ = q ^ (r_ & 7);                                         \
        int c1_ = (4 + q) ^ (r_ & 7);                                   \
        short8 a0_ = *(const short8*)(P + r_ * 64 + (c0_ << 3));        \
        short8 a1_ = *(const short8*)(P + r_ * 64 + (c1_ << 3));        \
        const int ro0_ = ((MT) * 16 + 4 * q) * 9;                       \
        _Pragma("unroll")                                               \
        for (int nt = 0; nt < 4; ++nt) {                                \
            f32x4 acc_ = (f32x4){0.f, 0.f, 0.f, 0.f};                   \
            acc_ = MFMA16(a0_, b1[nt * 2 + 0], acc_);                   \
            acc_ = MFMA16(a1_, b1[nt * 2 + 1], acc_);                   \
            int col_ = nt * 16 + g15;                                   \
            int o_ = nt * 2 + (g15 >> 3);                               \
            float part_ = 0.f;                                          \
            _Pragma("unroll")                                           \
            for (int rg = 0; rg < 4; ++rg) {                            \
                float v_ = bf2f(VC[rg * 4 + nt]);                       \
                part_ = fmaf(v_ + acc_[rg], wn[ro0_ + rg * 9 + o_], part_); \
            }                                                           \
            part_ += __shfl_xor(part_, 16, 64);                         \
            part_ += __shfl_xor(part_, 32, 64);                         \
            if (q == 0) out[(p0 + (MT)) * 64 + col_] = part_;           \
        }                                                               \
    } while (0)

    for (int b = blockIdx.x * 2 + w; b < NBATCH; b += gridDim.x * 2) {
        const int rbase = b * 64;
        const int p0 = b * 4;
        {
            int r = ref[rbase + lane];
            int idx = clip_idx(r);
            idxs[lane] = idx;
            int n = p0 + (lane >> 4);
            pos[lane * 4 + 0] = coord[idx * 3 + 0] - coord[n * 3 + 0];
            pos[lane * 4 + 1] = coord[idx * 3 + 1] - coord[n * 3 + 1];
            pos[lane * 4 + 2] = coord[idx * 3 + 2] - coord[n * 3 + 2];
            pos[lane * 4 + 3] = (r >= 0) ? 1.f : 0.f;
        }
        // issue W1 row load early (coalesced; consumed in softmax phase)
        short8 w8 = *(const short8*)(W1H + (rbase + lane) * 8);
        // issue V gathers for mt 0/1 early (consumed only in einsum)
        unsigned short vcA[16], vcB[16], vcC[16], vcD[16];
        LOADV(0, vcA);
        LOADV(1, vcB);
        // stage P1 (channel-pair, packed bf16x2 writes)
        #pragma unroll 8
        for (int rr = 0; rr < 32; ++rr) {
            int row = rh5 + rr;
            f32x4 pp = *(const f32x4*)(pos + row * 4);
            float lo = fmaxf(fmaf(pp.x, A0L, fmaf(pp.y, A1L, fmaf(pp.z, A2L, B0L))), 0.f);
            float hi = fmaxf(fmaf(pp.x, A0H, fmaf(pp.y, A1H, fmaf(pp.z, A2H, B0H))), 0.f);
            *(unsigned*)(P + aOff(row, pOff)) = pk_bf16(lo, hi);
        }
        // issue V gathers for mt 2/3
        LOADV(2, vcC);
        LOADV(3, vcD);
        // lane = row: BN+relu on W (regs) + w2 + grouped masked softmax
        {
            float h[8];
            #pragma unroll
            for (int gg = 0; gg < 8; ++gg) {
                float Wf = bf2f((unsigned short)w8[gg]);
                h[gg] = fmaxf(fmaf(wa8[gg], Wf, wb8[gg]), 0.f);
            }
            float mask = pos[lane * 4 + 3];
            #pragma unroll
            for (int o = 0; o < 8; ++o) {
                float acc = sW2[64 + o];
                #pragma unroll
                for (int gg = 0; gg < 8; ++gg) acc = fmaf(h[gg], sW2[gg * 8 + o], acc);
                float e = __expf(acc);
                float s = e;
                s += __shfl_xor(s, 1, 64);
                s += __shfl_xor(s, 2, 64);
                s += __shfl_xor(s, 4, 64);
                s += __shfl_xor(s, 8, 64);
                wn[lane * 9 + o] = e * __builtin_amdgcn_rcpf(s) * mask;
            }
        }
        // GEMM1 (PEB) fused with einsum; V fully in registers
        EINSUM_MT(0, vcA);
        EINSUM_MT(1, vcB);
        EINSUM_MT(2, vcC);
        EINSUM_MT(3, vcD);
    }
#undef LOADV
#undef EINSUM_MT
}

extern "C" void kernel_launch(void* const* d_in, const int* in_sizes, int n_in,
                              void* d_out, int out_size, void* d_ws, size_t ws_size,
                              hipStream_t stream)
{
    const float* feat  = (const float*)d_in[0];
    const float* coord = (const float*)d_in[1];
    const int*   ref   = (const int*)d_in[2];
    const float* wq    = (const float*)d_in[3];
    const float* bq    = (const float*)d_in[4];
    const float* gq    = (const float*)d_in[5];
    const float* betaq = (const float*)d_in[6];
    const float* wk    = (const float*)d_in[7];
    const float* bk    = (const float*)d_in[8];
    const float* gk    = (const float*)d_in[9];
    const float* betak = (const float*)d_in[10];
    const float* wv    = (const float*)d_in[11];
    const float* bv    = (const float*)d_in[12];
    const float* wp1   = (const float*)d_in[13];
    const float* bp1   = (const float*)d_in[14];
    const float* gp    = (const float*)d_in[15];
    const float* betap = (const float*)d_in[16];
    const float* wp2   = (const float*)d_in[17];
    const float* bp2   = (const float*)d_in[18];
    const float* ww1   = (const float*)d_in[19];
    const float* bw1   = (const float*)d_in[20];
    const float* gw_   = (const float*)d_in[21];
    const float* betaw = (const float*)d_in[22];
    const float* ww2   = (const float*)d_in[23];
    const float* bw2   = (const float*)d_in[24];

    float* ws    = (float*)d_ws;
    short* QlinH = (short*)(ws + O_QLINH);
    short* KlinH = (short*)(ws + O_KLINH);
    short* VlinH = (short*)(ws + O_VLINH);
    float* stat  = ws + O_STAT;
    float* aff   = ws + O_AFF;
    float* w2w1  = ws + O_W2W1;
    float* bw1e  = ws + O_BW1E;
    float* QW1   = ws + O_QW1;
    float* KW1   = ws + O_KW1;
    short* W1H   = (short*)(ws + O_W1H);
    float* out   = (float*)d_out;

    hipLaunchKernelGGL(k_prep, dim3(1), dim3(512), 0, stream,
                       wp2, ww1, bw1, bp2, stat, w2w1, bw1e);
    hipLaunchKernelGGL(k_qkv, dim3(QKV_BLOCKS + 128), dim3(256), 0, stream,
                       feat, wq, bq, wk, bk, wv, bv, bp2, coord, ref,
                       QlinH, KlinH, VlinH, stat);
    hipLaunchKernelGGL(k_finA, dim3(1), dim3(192), 0, stream,
                       gq, betaq, gk, betak, gp, betap, wp1, bp1, stat, aff);
    hipLaunchKernelGGL(k_qkw, dim3(782), dim3(128), 0, stream,
                       QlinH, KlinH, ww1, aff, QW1, KW1);
    hipLaunchKernelGGL(k_wstats, dim3(2500), dim3(128), 0, stream,
                       coord, ref, wp1, bp1, bw1e, w2w1, QW1, KW1, aff, stat, W1H);
    hipLaunchKernelGGL(k_finB, dim3(1), dim3(64), 0, stream, gw_, betaw, stat, aff);
    hipLaunchKernelGGL(k_final, dim3(2500), dim3(128), 0, stream,
                       coord, ref, wp1, bp1, wp2, ww2, bw2,
                       W1H, VlinH, aff, out);
}